// Round 8
// baseline (1809.499 us; speedup 1.0000x reference)
//
#include <hip/hip_runtime.h>
#include <hip/hip_bf16.h>
#include <math.h>

using u16 = unsigned short;
using u32 = unsigned int;

// Problem constants
constexpr int B   = 64;
constexpr int S   = 128;
constexpr int D   = 512;
constexpr int H   = 8;
constexpr int DK  = 64;
constexpr int L   = 6;
constexpr int DFF = 2048;
constexpr int AH  = 2;
constexpr int BS  = B * S;          // 8192
constexpr int BS2 = 2 * BS;         // 16384 (both passes batched)

// Output layout (fp32 elements)
constexpr long OUT_TOK    = 0;
constexpr long OUT_OUT1   = 8192;
constexpr long OUT_MTOK   = 16384;
constexpr long OUT_OUTM   = 24576;
constexpr long OUT_SCORES = 32768;

// Workspace layout (float units). ~206 MB of ~1 GiB ws
constexpr long OFF_PE   = 0;            // 65536
constexpr long OFF_ASC  = 65536;        // 2*B*H*S = 131072
constexpr long OFF_COLP = 196608;       // B*AH*S = 16384
constexpr long OFF_MTOK = 212992;       // 8192 ints
constexpr long OFF_X    = 221184;       // BS2*D fp32 = 8,388,608
constexpr long OFF_XB   = 8609792;      // BS2*D bf16 = 4,194,304 fl
constexpr long OFF_QB   = 12804096;     // BS2*D bf16
constexpr long OFF_KB   = 16998400;     // BS2*D bf16
constexpr long OFF_VB   = 21192704;     // BS2*D bf16
constexpr long OFF_TB   = 25387008;     // BS2*DFF bf16 = 16,777,216 fl (alias: mask q/k, pre-head parts)
constexpr long OFF_W    = 42164224;     // 6 layers x 3,145,728 bf16 = 9,437,184 fl
constexpr long WSTRIDE  = 3145728;      // bf16 elems per layer

typedef __attribute__((ext_vector_type(8))) short bf16x8;
typedef __attribute__((ext_vector_type(4))) float f32x4;

__device__ __forceinline__ float b2f(u16 u) {
    union { u32 i; float f; } v; v.i = ((u32)u) << 16; return v.f;
}
__device__ __forceinline__ u16 f2b(float f) {      // RNE f32 -> bf16
    union { float f; u32 i; } v; v.f = f;
    u32 r = v.i + 0x7fffu + ((v.i >> 16) & 1u);
    return (u16)(r >> 16);
}

#define GLOAD_LDS16(g, l) __builtin_amdgcn_global_load_lds(                        \
    (const __attribute__((address_space(1))) u32*)(const void*)(g),               \
    (__attribute__((address_space(3))) u32*)(void*)(l), 16, 0, 0)

// ---------------------------------------------------------------- pos enc
__global__ void pe_kernel(float* __restrict__ pe) {
    int idx = blockIdx.x * 256 + threadIdx.x;
    if (idx >= S * (D / 2)) return;
    int s = idx >> 8;
    int i = idx & 255;
    const float CPE = (float)(-9.210340371976184 / 512.0);
    float div = expf((float)(2 * i) * CPE);
    float ang = (float)s * div;
    pe[(long)s * D + 2 * i]     = sinf(ang);
    pe[(long)s * D + 2 * i + 1] = cosf(ang);
}

// ---------------------------------------------------------------- embed + pe (fp32 + bf16 out)
__global__ void embed_dual(const int* __restrict__ toks, const float* __restrict__ emb,
                           const float* __restrict__ pe, float* __restrict__ x,
                           u16* __restrict__ xb) {
    int i8 = blockIdx.x * 256 + threadIdx.x;      // over BS*D/8 = 524288
    if (i8 >= BS * D / 8) return;
    int row = i8 >> 6;
    int c8  = i8 & 63;
    int s   = row & (S - 1);
    int t   = toks[row];
    float4 e0 = *(const float4*)(emb + (long)t * D + c8 * 8);
    float4 e1 = *(const float4*)(emb + (long)t * D + c8 * 8 + 4);
    float4 p0 = *(const float4*)(pe + (long)s * D + c8 * 8);
    float4 p1 = *(const float4*)(pe + (long)s * D + c8 * 8 + 4);
    float4 o0, o1;
    o0.x = e0.x + p0.x; o0.y = e0.y + p0.y; o0.z = e0.z + p0.z; o0.w = e0.w + p0.w;
    o1.x = e1.x + p1.x; o1.y = e1.y + p1.y; o1.z = e1.z + p1.z; o1.w = e1.w + p1.w;
    *(float4*)(x + (long)i8 * 8)     = o0;
    *(float4*)(x + (long)i8 * 8 + 4) = o1;
    u16 u[8] = {f2b(o0.x), f2b(o0.y), f2b(o0.z), f2b(o0.w), f2b(o1.x), f2b(o1.y), f2b(o1.z), f2b(o1.w)};
    *(uint4*)(xb + (long)i8 * 8) = *(uint4*)u;
}

// ---------------------------------------------------------------- all-layer weight transpose+convert
__global__ __launch_bounds__(256)
void wconv_all(const float* __restrict__ tWQ, const float* __restrict__ tWK,
               const float* __restrict__ tWV, const float* __restrict__ tFC,
               const float* __restrict__ tF1, const float* __restrict__ tF2,
               u16* __restrict__ wAll) {
    __shared__ float t[32][33];
    const int lyr = blockIdx.x / 3072;
    const int bid = blockIdx.x % 3072;
    u16* base = wAll + (long)lyr * WSTRIDE;
    const float* src; u16* dst; int KK, NN, tk, tn;
    if (bid < 1024) {
        int which = bid >> 8, tt = bid & 255;
        src = (which == 0 ? tWQ : which == 1 ? tWK : which == 2 ? tWV : tFC) + (long)lyr * D * D;
        dst = base + (long)which * 262144;
        KK = 512; NN = 512; tk = tt >> 4; tn = tt & 15;
    } else if (bid < 2048) {
        int tt = bid - 1024;
        src = tF1 + (long)lyr * D * DFF; dst = base + 1048576;
        KK = 512; NN = 2048; tk = tt >> 6; tn = tt & 63;
    } else {
        int tt = bid - 2048;
        src = tF2 + (long)lyr * DFF * D; dst = base + 2097152;
        KK = 2048; NN = 512; tk = tt >> 4; tn = tt & 15;
    }
    int ty = threadIdx.x >> 5, tx = threadIdx.x & 31;
    #pragma unroll
    for (int i = 0; i < 4; i++)
        t[ty + i * 8][tx] = src[(long)(tk * 32 + ty + i * 8) * NN + tn * 32 + tx];
    __syncthreads();
    #pragma unroll
    for (int i = 0; i < 4; i++)
        dst[(long)(tn * 32 + ty + i * 8) * KK + tk * 32 + tx] = f2b(t[tx][ty + i * 8]);
}

// ---------------------------------------------------------------- bf16 MFMA GEMM core (128x128, 4 waves)
template<int EPI, int OUTB>
__device__ __forceinline__ void gemm_core(
        const u16* __restrict__ A, const u16* __restrict__ Wt,
        float* C, u16* Cb, const float* __restrict__ X,
        int M, int N, int K, int m0, int n0) {
    __shared__ u16 As[128 * 32];
    __shared__ u16 Bs[128 * 32];
    const int tid = threadIdx.x;
    const int w = tid >> 6, l = tid & 63;
    const int wr = (w >> 1) * 64, wc = (w & 1) * 64;
    f32x4 acc[4][4];
    #pragma unroll
    for (int i = 0; i < 4; i++)
        #pragma unroll
        for (int j = 0; j < 4; j++) { f32x4 z = {0.f, 0.f, 0.f, 0.f}; acc[i][j] = z; }

    const int srow = w * 32 + (l >> 2);
    const int scol = (l & 3) * 8;
    const u16* gA = A + (long)(m0 + srow) * K + scol;
    const u16* gB = Wt + (long)(n0 + srow) * K + scol;
    u16* lA0 = As + w * 1024;
    u16* lA1 = As + w * 1024 + 512;
    u16* lB0 = Bs + w * 1024;
    u16* lB1 = Bs + w * 1024 + 512;

    for (int k0 = 0; k0 < K; k0 += 32) {
        GLOAD_LDS16(gA + k0,               lA0);
        GLOAD_LDS16(gA + (long)16 * K + k0, lA1);
        GLOAD_LDS16(gB + k0,               lB0);
        GLOAD_LDS16(gB + (long)16 * K + k0, lB1);
        __syncthreads();
        bf16x8 aF[4], bF[4];
        #pragma unroll
        for (int mi = 0; mi < 4; mi++)
            aF[mi] = *(const bf16x8*)(As + (wr + mi * 16 + (l & 15)) * 32 + (l >> 4) * 8);
        #pragma unroll
        for (int ni = 0; ni < 4; ni++)
            bF[ni] = *(const bf16x8*)(Bs + (wc + ni * 16 + (l & 15)) * 32 + (l >> 4) * 8);
        #pragma unroll
        for (int mi = 0; mi < 4; mi++)
            #pragma unroll
            for (int ni = 0; ni < 4; ni++)
                acc[mi][ni] = __builtin_amdgcn_mfma_f32_16x16x32_bf16(aF[mi], bF[ni], acc[mi][ni], 0, 0, 0);
        __syncthreads();
    }

    #pragma unroll
    for (int mi = 0; mi < 4; mi++) {
        #pragma unroll
        for (int ni = 0; ni < 4; ni++) {
            const int col = n0 + wc + ni * 16 + (l & 15);
            #pragma unroll
            for (int r = 0; r < 4; r++) {
                const int row = m0 + wr + mi * 16 + (l >> 4) * 4 + r;
                const long idx = (long)row * N + col;
                float v = acc[mi][ni][r];
                if (EPI == 1) v += X[idx];
                if (EPI == 2) v = fmaxf(v, 0.0f);
                if (OUTB) Cb[idx] = f2b(v);
                else      C[idx]  = v;
            }
        }
    }
}

__global__ __launch_bounds__(256)
void gemm_qkv_b(const u16* __restrict__ A, const u16* wq, const u16* wk, const u16* wv,
                u16* qb, u16* kb, u16* vb, int M, int N, int K) {
    const u16* Wt = blockIdx.z == 0 ? wq : blockIdx.z == 1 ? wk : wv;
    u16* Cb       = blockIdx.z == 0 ? qb : blockIdx.z == 1 ? kb : vb;
    gemm_core<0, 1>(A, Wt, nullptr, Cb, nullptr, M, N, K, blockIdx.x * 128, blockIdx.y * 128);
}
__global__ __launch_bounds__(256)
void gemm_relu_b(const u16* __restrict__ A, const u16* __restrict__ Wt,
                 u16* Cb, int M, int N, int K) {
    gemm_core<2, 1>(A, Wt, nullptr, Cb, nullptr, M, N, K, blockIdx.x * 128, blockIdx.y * 128);
}

// ---------------------------------------------------------------- GEMM + residual + LayerNorm fused
// One block = 64 rows x full width 512. 512 threads = 8 waves; wave w owns cols [w*64, w*64+64).
// out = LN(A @ Wt + x); writes x (fp32) and xb (bf16) in place.
__global__ __launch_bounds__(512)
void gemm_ln(const u16* __restrict__ A, const u16* __restrict__ Wt,
             float* x, u16* __restrict__ xb, int K) {
    __shared__ u16 As[64 * 32];
    __shared__ u16 Bs[512 * 32];
    __shared__ float redS[64][9];
    __shared__ float redQ[64][9];
    __shared__ float meanS[64], invS[64];
    const int m0 = blockIdx.x * 64;
    const int tid = threadIdx.x;
    const int w = tid >> 6, l = tid & 63;
    const int wc = w * 64;

    f32x4 acc[4][4];
    #pragma unroll
    for (int i = 0; i < 4; i++)
        #pragma unroll
        for (int j = 0; j < 4; j++) { f32x4 z = {0.f, 0.f, 0.f, 0.f}; acc[i][j] = z; }

    const int scol = (l & 3) * 8;
    const u16* gA = A + (long)(m0 + w * 16 + (l >> 2)) * K + scol;     // waves 0-3 only
    const u16* gB = Wt + (long)(w * 64 + (l >> 2)) * K + scol;
    u16* lA = As + (w * 16) * 32;
    u16* lB = Bs + (w * 64) * 32;

    for (int k0 = 0; k0 < K; k0 += 32) {
        if (w < 4) GLOAD_LDS16(gA + k0, lA);
        #pragma unroll
        for (int j = 0; j < 4; j++)
            GLOAD_LDS16(gB + (long)j * 16 * K + k0, lB + j * 16 * 32);
        __syncthreads();
        bf16x8 aF[4], bF[4];
        #pragma unroll
        for (int mi = 0; mi < 4; mi++)
            aF[mi] = *(const bf16x8*)(As + (mi * 16 + (l & 15)) * 32 + (l >> 4) * 8);
        #pragma unroll
        for (int ni = 0; ni < 4; ni++)
            bF[ni] = *(const bf16x8*)(Bs + (wc + ni * 16 + (l & 15)) * 32 + (l >> 4) * 8);
        #pragma unroll
        for (int mi = 0; mi < 4; mi++)
            #pragma unroll
            for (int ni = 0; ni < 4; ni++)
                acc[mi][ni] = __builtin_amdgcn_mfma_f32_16x16x32_bf16(aF[mi], bF[ni], acc[mi][ni], 0, 0, 0);
        __syncthreads();
    }

    // v = acc + residual; per-row sum / sumsq partials (16-lane group covers this wave's 64 cols)
    #pragma unroll
    for (int mi = 0; mi < 4; mi++)
        #pragma unroll
        for (int r = 0; r < 4; r++) {
            const int row = mi * 16 + (l >> 4) * 4 + r;
            float s = 0.0f, q = 0.0f;
            #pragma unroll
            for (int ni = 0; ni < 4; ni++) {
                const int col = wc + ni * 16 + (l & 15);
                float v = acc[mi][ni][r] + x[(long)(m0 + row) * D + col];
                acc[mi][ni][r] = v;
                s += v; q += v * v;
            }
            s += __shfl_xor(s, 1); s += __shfl_xor(s, 2); s += __shfl_xor(s, 4); s += __shfl_xor(s, 8);
            q += __shfl_xor(q, 1); q += __shfl_xor(q, 2); q += __shfl_xor(q, 4); q += __shfl_xor(q, 8);
            if ((l & 15) == 0) { redS[row][w] = s; redQ[row][w] = q; }
        }
    __syncthreads();
    if (tid < 64) {
        float s = 0.0f, q = 0.0f;
        #pragma unroll
        for (int ww = 0; ww < 8; ww++) { s += redS[tid][ww]; q += redQ[tid][ww]; }
        float mean = s * (1.0f / 512.0f);
        float var  = q * (1.0f / 512.0f) - mean * mean;
        meanS[tid] = mean;
        invS[tid]  = 1.0f / sqrtf(var + 1e-5f);
    }
    __syncthreads();
    #pragma unroll
    for (int mi = 0; mi < 4; mi++)
        #pragma unroll
        for (int r = 0; r < 4; r++) {
            const int row = mi * 16 + (l >> 4) * 4 + r;
            const float mn = meanS[row], iv = invS[row];
            #pragma unroll
            for (int ni = 0; ni < 4; ni++) {
                const int col = wc + ni * 16 + (l & 15);
                const long idx = (long)(m0 + row) * D + col;
                float o = (acc[mi][ni][r] - mn) * iv;
                x[idx]  = o;
                xb[idx] = f2b(o);
            }
        }
}

// ---------------------------------------------------------------- fp32 GEMM (pre-head tail)
template<int EPI>
__global__ __launch_bounds__(256)
void gemm64(const float* __restrict__ A, const float* __restrict__ W,
            float* C, const float* X, int M, int N, int K) {
    __shared__ float As[32][68];
    __shared__ float Ws[32][64];
    const int m0 = blockIdx.x * 64, n0 = blockIdx.y * 64;
    const int tid  = threadIdx.x;
    const int tr   = tid >> 4, tc = tid & 15;
    const int arow = tid >> 3, acg = tid & 7;
    const int wrow = tid >> 4, wcg = tid & 15;
    float acc[4][4] = {};
    for (int k0 = 0; k0 < K; k0 += 32) {
        float4 a0 = *(const float4*)(A + (long)(m0 + arow) * K + k0 + acg * 4);
        float4 a1 = *(const float4*)(A + (long)(m0 + arow + 32) * K + k0 + acg * 4);
        float4 w0 = *(const float4*)(W + (long)(k0 + wrow) * N + n0 + wcg * 4);
        float4 w1 = *(const float4*)(W + (long)(k0 + wrow + 16) * N + n0 + wcg * 4);
        As[acg * 4 + 0][arow] = a0.x; As[acg * 4 + 1][arow] = a0.y;
        As[acg * 4 + 2][arow] = a0.z; As[acg * 4 + 3][arow] = a0.w;
        As[acg * 4 + 0][arow + 32] = a1.x; As[acg * 4 + 1][arow + 32] = a1.y;
        As[acg * 4 + 2][arow + 32] = a1.z; As[acg * 4 + 3][arow + 32] = a1.w;
        *(float4*)&Ws[wrow][wcg * 4]      = w0;
        *(float4*)&Ws[wrow + 16][wcg * 4] = w1;
        __syncthreads();
        #pragma unroll
        for (int kk = 0; kk < 32; kk++) {
            float4 av = *(const float4*)&As[kk][tr * 4];
            float4 bv = *(const float4*)&Ws[kk][tc * 4];
            acc[0][0] += av.x * bv.x; acc[0][1] += av.x * bv.y; acc[0][2] += av.x * bv.z; acc[0][3] += av.x * bv.w;
            acc[1][0] += av.y * bv.x; acc[1][1] += av.y * bv.y; acc[1][2] += av.y * bv.z; acc[1][3] += av.y * bv.w;
            acc[2][0] += av.z * bv.x; acc[2][1] += av.z * bv.y; acc[2][2] += av.z * bv.z; acc[2][3] += av.z * bv.w;
            acc[3][0] += av.w * bv.x; acc[3][1] += av.w * bv.y; acc[3][2] += av.w * bv.z; acc[3][3] += av.w * bv.w;
        }
        __syncthreads();
    }
    #pragma unroll
    for (int i = 0; i < 4; i++) {
        int row = m0 + tr * 4 + i;
        #pragma unroll
        for (int j = 0; j < 4; j++) {
            int col = n0 + tc * 4 + j;
            long idx = (long)row * N + col;
            float v = acc[i][j];
            if (EPI == 1) v += X[idx];
            if (EPI == 3 || EPI == 4) v += X[col];
            if (EPI == 2 || EPI == 4) v = fmaxf(v, 0.0f);
            C[idx] = v;
        }
    }
}

// QKV merged fp32 (mask encoder)
__global__ __launch_bounds__(256)
void gemm64_qkv(const float* __restrict__ A,
                const float* __restrict__ WQ, const float* __restrict__ WK, const float* __restrict__ WV,
                float* q, float* k, float* v, int M, int N, int K) {
    __shared__ float As[32][68];
    __shared__ float Ws[32][64];
    const float* W = (blockIdx.z == 0) ? WQ : (blockIdx.z == 1) ? WK : WV;
    float*       C = (blockIdx.z == 0) ? q  : (blockIdx.z == 1) ? k  : v;
    const int m0 = blockIdx.x * 64, n0 = blockIdx.y * 64;
    const int tid  = threadIdx.x;
    const int tr   = tid >> 4, tc = tid & 15;
    const int arow = tid >> 3, acg = tid & 7;
    const int wrow = tid >> 4, wcg = tid & 15;
    float acc[4][4] = {};
    for (int k0 = 0; k0 < K; k0 += 32) {
        float4 a0 = *(const float4*)(A + (long)(m0 + arow) * K + k0 + acg * 4);
        float4 a1 = *(const float4*)(A + (long)(m0 + arow + 32) * K + k0 + acg * 4);
        float4 w0 = *(const float4*)(W + (long)(k0 + wrow) * N + n0 + wcg * 4);
        float4 w1 = *(const float4*)(W + (long)(k0 + wrow + 16) * N + n0 + wcg * 4);
        As[acg * 4 + 0][arow] = a0.x; As[acg * 4 + 1][arow] = a0.y;
        As[acg * 4 + 2][arow] = a0.z; As[acg * 4 + 3][arow] = a0.w;
        As[acg * 4 + 0][arow + 32] = a1.x; As[acg * 4 + 1][arow + 32] = a1.y;
        As[acg * 4 + 2][arow + 32] = a1.z; As[acg * 4 + 3][arow + 32] = a1.w;
        *(float4*)&Ws[wrow][wcg * 4]      = w0;
        *(float4*)&Ws[wrow + 16][wcg * 4] = w1;
        __syncthreads();
        #pragma unroll
        for (int kk = 0; kk < 32; kk++) {
            float4 av = *(const float4*)&As[kk][tr * 4];
            float4 bv = *(const float4*)&Ws[kk][tc * 4];
            acc[0][0] += av.x * bv.x; acc[0][1] += av.x * bv.y; acc[0][2] += av.x * bv.z; acc[0][3] += av.x * bv.w;
            acc[1][0] += av.y * bv.x; acc[1][1] += av.y * bv.y; acc[1][2] += av.y * bv.z; acc[1][3] += av.y * bv.w;
            acc[2][0] += av.z * bv.x; acc[2][1] += av.z * bv.y; acc[2][2] += av.z * bv.z; acc[2][3] += av.z * bv.w;
            acc[3][0] += av.w * bv.x; acc[3][1] += av.w * bv.y; acc[3][2] += av.w * bv.z; acc[3][3] += av.w * bv.w;
        }
        __syncthreads();
    }
    #pragma unroll
    for (int i = 0; i < 4; i++)
        #pragma unroll
        for (int j = 0; j < 4; j++)
            C[(long)(m0 + tr * 4 + i) * N + n0 + tc * 4 + j] = acc[i][j];
}

// ---------------------------------------------------------------- pre-head layer-1: MFMA split-K
__global__ __launch_bounds__(256)
void gemm_ph1(const u16* __restrict__ Ah, const u16* __restrict__ Ahm,
              const float* __restrict__ W, float* __restrict__ P, int KC) {
    constexpr int N = 1024, K = 65536;
    __shared__ u16 As[128 * 32];
    __shared__ u16 Bs[128 * 32];
    const int n0 = blockIdx.x * 128;
    const int kbeg = blockIdx.y * KC;
    const int tid = threadIdx.x;
    const int w = tid >> 6, l = tid & 63;
    const int wr = w * 32;
    const int nl = tid >> 1, seg = tid & 1;
    const u16* aptr = (nl < 64 ? Ah + (long)nl * K : Ahm + (long)(nl - 64) * K) + seg * 16;
    const float* wcol = W + n0 + nl;

    f32x4 acc[2][8];
    #pragma unroll
    for (int mi = 0; mi < 2; mi++)
        #pragma unroll
        for (int ni = 0; ni < 8; ni++) { f32x4 z = {0.f, 0.f, 0.f, 0.f}; acc[mi][ni] = z; }

    for (int ks = 0; ks < KC; ks += 32) {
        const int k0 = kbeg + ks;
        uint4 a0 = *(const uint4*)(aptr + k0);
        uint4 a1 = *(const uint4*)(aptr + k0 + 8);
        float wv[16];
        #pragma unroll
        for (int j = 0; j < 16; j++)
            wv[j] = wcol[(long)(k0 + seg * 16 + j) * N];
        __syncthreads();
        *(uint4*)(As + nl * 32 + seg * 16)     = a0;
        *(uint4*)(As + nl * 32 + seg * 16 + 8) = a1;
        u32 pk[8];
        #pragma unroll
        for (int j = 0; j < 8; j++)
            pk[j] = (u32)f2b(wv[2 * j]) | ((u32)f2b(wv[2 * j + 1]) << 16);
        *(uint4*)(Bs + nl * 32 + seg * 16)     = *(uint4*)&pk[0];
        *(uint4*)(Bs + nl * 32 + seg * 16 + 8) = *(uint4*)&pk[4];
        __syncthreads();
        bf16x8 aF0 = *(const bf16x8*)(As + (wr + (l & 15)) * 32 + (l >> 4) * 8);
        bf16x8 aF1 = *(const bf16x8*)(As + (wr + 16 + (l & 15)) * 32 + (l >> 4) * 8);
        #pragma unroll
        for (int ni = 0; ni < 8; ni++) {
            bf16x8 bF = *(const bf16x8*)(Bs + (ni * 16 + (l & 15)) * 32 + (l >> 4) * 8);
            acc[0][ni] = __builtin_amdgcn_mfma_f32_16x16x32_bf16(aF0, bF, acc[0][ni], 0, 0, 0);
            acc[1][ni] = __builtin_amdgcn_mfma_f32_16x16x32_bf16(aF1, bF, acc[1][ni], 0, 0, 0);
        }
    }
    float* Pz = P + (long)blockIdx.y * 128 * N;
    #pragma unroll
    for (int mi = 0; mi < 2; mi++)
        #pragma unroll
        for (int ni = 0; ni < 8; ni++) {
            const int col = n0 + ni * 16 + (l & 15);
            #pragma unroll
            for (int r = 0; r < 4; r++)
                Pz[(long)(wr + mi * 16 + (l >> 4) * 4 + r) * N + col] = acc[mi][ni][r];
        }
}

// ---------------------------------------------------------------- fp32 attention (mask path, colsum only)
__global__ __launch_bounds__(128)
void attn_kernel(const float* __restrict__ Q, const float* __restrict__ K,
                 const int* __restrict__ toks, float* __restrict__ colsum, int Hn) {
    __shared__ float sc[S][129];
    __shared__ float KV[S][DK];
    __shared__ int   padS[S];
    const int b = blockIdx.x / Hn;
    const int h = blockIdx.x % Hn;
    const int stride = Hn * DK;
    const int tid = threadIdx.x;

    for (int idx = tid; idx < S * DK; idx += 128) {
        int r = idx >> 6, c = idx & 63;
        KV[r][c] = K[(long)(b * S + r) * stride + h * DK + c];
    }
    padS[tid] = (toks[b * S + tid] == 0) ? 1 : 0;
    float qreg[DK];
    {
        const float* qp = Q + (long)(b * S + tid) * stride + h * DK;
        #pragma unroll
        for (int i = 0; i < 16; i++) {
            float4 t4 = *(const float4*)(qp + i * 4);
            qreg[i * 4 + 0] = t4.x; qreg[i * 4 + 1] = t4.y;
            qreg[i * 4 + 2] = t4.z; qreg[i * 4 + 3] = t4.w;
        }
    }
    __syncthreads();
    for (int k = 0; k < S; k++) {
        float s = 0.0f;
        #pragma unroll
        for (int d4 = 0; d4 < 16; d4++) {
            float4 kv = *(const float4*)&KV[k][d4 * 4];
            s += qreg[d4 * 4 + 0] * kv.x + qreg[d4 * 4 + 1] * kv.y
               + qreg[d4 * 4 + 2] * kv.z + qreg[d4 * 4 + 3] * kv.w;
        }
        sc[tid][k] = padS[k] ? -1e9f : (s * 0.125f);
    }
    float mx = -INFINITY;
    for (int k = 0; k < S; k++) mx = fmaxf(mx, sc[tid][k]);
    float sum = 0.0f;
    for (int k = 0; k < S; k++) { float e = expf(sc[tid][k] - mx); sc[tid][k] = e; sum += e; }
    for (int k = 0; k < S; k++) sc[tid][k] = sc[tid][k] / sum;
    __syncthreads();
    {
        double a = 0.0;
        for (int q2 = 0; q2 < S; q2++) a += (double)sc[q2][tid];
        colsum[(long)(b * Hn + h) * S + tid] = (float)a;
    }
}

// ---------------------------------------------------------------- MFMA attention (batched passes)
__global__ __launch_bounds__(256)
void attn_mfma_kernel(u16* qb, const u16* __restrict__ kb, const u16* __restrict__ vb,
                      const int* __restrict__ toks, const int* __restrict__ mtok,
                      float* __restrict__ colsum) {
    __shared__ u16 pool[18432];          // Qs[128][72] | Ks[128][72] ; Ps[128][136] aliases
    __shared__ u16 Vt[64 * 136];
    __shared__ float colsLds[4][128];
    __shared__ u32 padF[128];
    u16* Qs = pool;
    u16* Ks = pool + 9216;
    u16* Ps = pool;

    const int gb = blockIdx.x >> 3, h = blockIdx.x & 7;
    const int tid = threadIdx.x;
    const int w = tid >> 6, l = tid & 63;
    const long base = (long)gb * S * D + h * 64;
    const int* tsrc = (gb < B) ? (toks + (long)gb * S) : (mtok + (long)(gb - B) * S);

    for (int j = tid; j < 1024; j += 256) {
        int r = j >> 3, c = j & 7;
        uint4 uq = *(const uint4*)(qb + base + (long)r * D + c * 8);
        uint4 uk = *(const uint4*)(kb + base + (long)r * D + c * 8);
        uint4 uv = *(const uint4*)(vb + base + (long)r * D + c * 8);
        *(uint4*)(Qs + r * 72 + c * 8) = uq;
        *(uint4*)(Ks + r * 72 + c * 8) = uk;
        u16 vv[8]; *(uint4*)vv = uv;
        #pragma unroll
        for (int t = 0; t < 8; t++) Vt[(c * 8 + t) * 136 + r] = vv[t];
    }
    if (tid < 128) padF[tid] = (tsrc[tid] == 0) ? 1u : 0u;
    __syncthreads();

    const int rowB = w * 32;
    f32x4 acc[2][8];
    #pragma unroll
    for (int mi = 0; mi < 2; mi++)
        #pragma unroll
        for (int ni = 0; ni < 8; ni++) { f32x4 z = {0.f, 0.f, 0.f, 0.f}; acc[mi][ni] = z; }
    #pragma unroll
    for (int ks = 0; ks < 2; ks++) {
        bf16x8 a0 = *(const bf16x8*)(Qs + (rowB + (l & 15)) * 72 + ks * 32 + (l >> 4) * 8);
        bf16x8 a1 = *(const bf16x8*)(Qs + (rowB + 16 + (l & 15)) * 72 + ks * 32 + (l >> 4) * 8);
        #pragma unroll
        for (int ni = 0; ni < 8; ni++) {
            bf16x8 bv = *(const bf16x8*)(Ks + (ni * 16 + (l & 15)) * 72 + ks * 32 + (l >> 4) * 8);
            acc[0][ni] = __builtin_amdgcn_mfma_f32_16x16x32_bf16(a0, bv, acc[0][ni], 0, 0, 0);
            acc[1][ni] = __builtin_amdgcn_mfma_f32_16x16x32_bf16(a1, bv, acc[1][ni], 0, 0, 0);
        }
    }
    float pf[8];
    #pragma unroll
    for (int ni = 0; ni < 8; ni++) pf[ni] = padF[ni * 16 + (l & 15)] ? 1.0f : 0.0f;
    #pragma unroll
    for (int mi = 0; mi < 2; mi++)
        #pragma unroll
        for (int ni = 0; ni < 8; ni++)
            #pragma unroll
            for (int r = 0; r < 4; r++) {
                float v = acc[mi][ni][r] * 0.125f;
                acc[mi][ni][r] = (pf[ni] != 0.0f) ? -1e9f : v;
            }
    #pragma unroll
    for (int mi = 0; mi < 2; mi++)
        #pragma unroll
        for (int r = 0; r < 4; r++) {
            float m = -INFINITY;
            #pragma unroll
            for (int ni = 0; ni < 8; ni++) m = fmaxf(m, acc[mi][ni][r]);
            m = fmaxf(m, __shfl_xor(m, 1)); m = fmaxf(m, __shfl_xor(m, 2));
            m = fmaxf(m, __shfl_xor(m, 4)); m = fmaxf(m, __shfl_xor(m, 8));
            float s = 0.0f;
            #pragma unroll
            for (int ni = 0; ni < 8; ni++) { float e = expf(acc[mi][ni][r] - m); acc[mi][ni][r] = e; s += e; }
            s += __shfl_xor(s, 1); s += __shfl_xor(s, 2);
            s += __shfl_xor(s, 4); s += __shfl_xor(s, 8);
            float inv = 1.0f / s;
            #pragma unroll
            for (int ni = 0; ni < 8; ni++) acc[mi][ni][r] *= inv;
        }
    float cs[8];
    #pragma unroll
    for (int ni = 0; ni < 8; ni++) {
        float s = 0.0f;
        #pragma unroll
        for (int mi = 0; mi < 2; mi++)
            #pragma unroll
            for (int r = 0; r < 4; r++) s += acc[mi][ni][r];
        s += __shfl_xor(s, 16); s += __shfl_xor(s, 32);
        cs[ni] = s;
    }
    __syncthreads();
    if (l < 16)
        #pragma unroll
        for (int ni = 0; ni < 8; ni++) colsLds[w][ni * 16 + l] = cs[ni];
    #pragma unroll
    for (int mi = 0; mi < 2; mi++)
        #pragma unroll
        for (int ni = 0; ni < 8; ni++)
            #pragma unroll
            for (int r = 0; r < 4; r++)
                Ps[(rowB + mi * 16 + (l >> 4) * 4 + r) * 136 + ni * 16 + (l & 15)] =
                    f2b(acc[mi][ni][r]);
    __syncthreads();
    if (tid < 128) {
        float s = colsLds[0][tid] + colsLds[1][tid] + colsLds[2][tid] + colsLds[3][tid];
        colsum[((long)gb * H + h) * S + tid] = s;
    }
    f32x4 o[2][4];
    #pragma unroll
    for (int mi = 0; mi < 2; mi++)
        #pragma unroll
        for (int n = 0; n < 4; n++) { f32x4 z = {0.f, 0.f, 0.f, 0.f}; o[mi][n] = z; }
    #pragma unroll
    for (int ks = 0; ks < 4; ks++) {
        bf16x8 p0 = *(const bf16x8*)(Ps + (rowB + (l & 15)) * 136 + ks * 32 + (l >> 4) * 8);
        bf16x8 p1 = *(const bf16x8*)(Ps + (rowB + 16 + (l & 15)) * 136 + ks * 32 + (l >> 4) * 8);
        #pragma unroll
        for (int n = 0; n < 4; n++) {
            bf16x8 bv = *(const bf16x8*)(Vt + (n * 16 + (l & 15)) * 136 + ks * 32 + (l >> 4) * 8);
            o[0][n] = __builtin_amdgcn_mfma_f32_16x16x32_bf16(p0, bv, o[0][n], 0, 0, 0);
            o[1][n] = __builtin_amdgcn_mfma_f32_16x16x32_bf16(p1, bv, o[1][n], 0, 0, 0);
        }
    }
    #pragma unroll
    for (int mi = 0; mi < 2; mi++)
        #pragma unroll
        for (int n = 0; n < 4; n++) {
            const int col = n * 16 + (l & 15);
            #pragma unroll
            for (int r = 0; r < 4; r++) {
                const int row = rowB + mi * 16 + (l >> 4) * 4 + r;
                qb[base + (long)row * D + col] = f2b(o[mi][n][r]);
            }
        }
}

// ---------------------------------------------------------------- creat_mask
__global__ __launch_bounds__(128)
void creat_mask_kernel(const float* __restrict__ colpart, const int* __restrict__ toks,
                       int* __restrict__ mtok, float* __restrict__ out) {
    __shared__ float colS[S];
    __shared__ int   j0s, kks;
    const int b = blockIdx.x, j = threadIdx.x;
    float c = colpart[(long)(b * AH + 0) * S + j] + colpart[(long)(b * AH + 1) * S + j];
    colS[j] = c;
    int tk = toks[b * S + j];
    __syncthreads();
    if (j == 0) {
        int j0 = S;
        for (int i = 0; i < S; i++) if (colS[i] == 0.0f) { j0 = i; break; }
        int kk = (j0 < S) ? (int)ceilf(0.2f * (float)j0) : 0;
        j0s = j0; kks = kk;
    }
    __syncthreads();
    const int j0 = j0s, kk = kks;
    float vj = (j < j0) ? colS[j] : INFINITY;
    int rank = 0;
    for (int i = 0; i < S; i++) {
        float vi = (i < j0) ? colS[i] : INFINITY;
        if (vi < vj || (vi == vj && i < j)) rank++;
    }
    int mt = (rank >= kk) ? tk : 0;
    mtok[b * S + j] = mt;
    out[OUT_TOK + b * S + j]  = (float)tk;
    out[OUT_MTOK + b * S + j] = (float)mt;
}

// ---------------------------------------------------------------- scores output (pass-0 half)
__global__ void score_reduce_kernel(const float* __restrict__ ascorep, float* __restrict__ dst) {
    int idx = blockIdx.x * 256 + threadIdx.x;
    if (idx >= B * S) return;
    int b = idx >> 7, j = idx & 127;
    float s = 0.0f;
    for (int h = 0; h < H; h++) s += ascorep[(long)(b * H + h) * S + j];
    dst[idx] = s;
}

// ---------------------------------------------------------------- pre-head reduce/pack
__global__ void reduce1_kernel(const float* __restrict__ parts, const float* __restrict__ b1,
                               float* __restrict__ o) {
    int idx = blockIdx.x * 256 + threadIdx.x;
    if (idx >= 128 * 1024) return;
    float s = 0.0f;
    for (int z = 0; z < 64; z++) s += parts[(long)z * 128 * 1024 + idx];
    s += b1[idx & 1023];
    o[idx] = fmaxf(s, 0.0f);
}

__global__ void pack_out_kernel(const float* __restrict__ ph3, float* __restrict__ out) {
    int idx = blockIdx.x * 256 + threadIdx.x;
    if (idx >= 128 * 128) return;
    int row = idx >> 7, col = idx & 127;
    long base = (row < 64) ? (OUT_OUT1 + (long)row * 128) : (OUT_OUTM + (long)(row - 64) * 128);
    out[base + col] = ph3[idx];
}

// ================================================================ launch
extern "C" void kernel_launch(void* const* d_in, const int* in_sizes, int n_in,
                              void* d_out, int out_size, void* d_ws, size_t ws_size,
                              hipStream_t stream) {
    const int*   toks = (const int*)d_in[0];
    const float* emb  = (const float*)d_in[1];
    const float* aWQ  = (const float*)d_in[2];
    const float* aWK  = (const float*)d_in[3];
    const float* tWQ  = (const float*)d_in[8];
    const float* tWK  = (const float*)d_in[9];
    const float* tWV  = (const float*)d_in[10];
    const float* tFC  = (const float*)d_in[11];
    const float* tF1  = (const float*)d_in[12];
    const float* tF2  = (const float*)d_in[13];
    const float* pW1  = (const float*)d_in[14];
    const float* pb1  = (const float*)d_in[15];
    const float* pW2  = (const float*)d_in[16];
    const float* pb2  = (const float*)d_in[17];
    const float* pW3  = (const float*)d_in[18];
    const float* pb3  = (const float*)d_in[19];
    float* out = (float*)d_out;

    float* ws   = (float*)d_ws;
    float* pe   = ws + OFF_PE;
    float* ascp = ws + OFF_ASC;
    float* colp = ws + OFF_COLP;
    int*   mtok = (int*)(ws + OFF_MTOK);
    float* x    = ws + OFF_X;          // [BS2][D] fp32 (h ‖ hm)
    u16*   xb   = (u16*)(ws + OFF_XB); // [BS2][D] bf16
    u16*   qb   = (u16*)(ws + OFF_QB);
    u16*   kb   = (u16*)(ws + OFF_KB);
    u16*   vb   = (u16*)(ws + OFF_VB);
    u16*   tb   = (u16*)(ws + OFF_TB); // [BS2][DFF] bf16
    u16*   wAll = (u16*)(ws + OFF_W);

    // phase-disjoint aliases of the TB region
    float* maq   = ws + OFF_TB;                 // mask encoder q [BS][128] fp32
    float* mak   = maq + (long)BS * 128;
    float* parts = ws + OFF_TB;                 // pre-head partials 64 x [128][1024]
    float* ph1o  = parts + 8388608;
    float* ph2o  = ph1o + 131072;
    float* ph3o  = ph2o + 65536;

    // --- setup: pos-enc, all-layer weight conversion, clean embedding
    pe_kernel<<<128, 256, 0, stream>>>(pe);
    wconv_all<<<6 * 3072, 256, 0, stream>>>(tWQ, tWK, tWV, tFC, tF1, tF2, wAll);
    embed_dual<<<2048, 256, 0, stream>>>(toks, emb, pe, x, xb);

    // --- mask-generating encoder (fp32; only the attention matrix is consumed)
    gemm64_qkv<<<dim3(BS / 64, 2, 2), 256, 0, stream>>>(
        x, aWQ, aWK, nullptr, maq, mak, nullptr, BS, AH * DK, D);
    attn_kernel<<<B * AH, 128, 0, stream>>>(maq, mak, toks, colp, AH);
    creat_mask_kernel<<<B, 128, 0, stream>>>(colp, toks, mtok, out);
    embed_dual<<<2048, 256, 0, stream>>>(mtok, emb, pe, x + (long)BS * D, xb + (long)BS * D);

    // --- 6 layers, both passes batched (rows 0..8191 = clean, 8192..16383 = masked)
    for (int l = 0; l < L; l++) {
        const u16* wq = wAll + (long)l * WSTRIDE;
        const u16* wk = wq + 262144;
        const u16* wv = wq + 524288;
        const u16* wo = wq + 786432;
        const u16* w1 = wq + 1048576;
        const u16* w2 = wq + 2097152;
        gemm_qkv_b<<<dim3(BS2 / 128, D / 128, 3), 256, 0, stream>>>(
            xb, wq, wk, wv, qb, kb, vb, BS2, D, D);
        attn_mfma_kernel<<<2 * B * H, 256, 0, stream>>>(qb, kb, vb, toks, mtok, ascp);
        score_reduce_kernel<<<32, 256, 0, stream>>>(ascp, out + OUT_SCORES + (long)l * BS);
        gemm_ln<<<BS2 / 64, 512, 0, stream>>>(qb, wo, x, xb, D);        // WO + residual + LN
        gemm_relu_b<<<dim3(BS2 / 128, DFF / 128), 256, 0, stream>>>(xb, w1, tb, BS2, DFF, D);
        gemm_ln<<<BS2 / 64, 512, 0, stream>>>(tb, w2, x, xb, DFF);      // FFN2 + residual + LN
    }

    // --- pre_head: MFMA split-K over pW1 (xb already holds bf16 h ‖ hm)
    gemm_ph1<<<dim3(8, 64), 256, 0, stream>>>(xb, xb + (long)BS * D, pW1, parts, 1024);
    reduce1_kernel<<<512, 256, 0, stream>>>(parts, pb1, ph1o);
    gemm64<4><<<dim3(2, 8), 256, 0, stream>>>(ph1o, pW2, ph2o, pb2, 128, 512, 1024);
    gemm64<3><<<dim3(2, 2), 256, 0, stream>>>(ph2o, pW3, ph3o, pb3, 128, 128, 512);
    pack_out_kernel<<<64, 256, 0, stream>>>(ph3o, out);
}

// Round 9
// 1739.266 us; speedup vs baseline: 1.0404x; 1.0404x over previous
//
#include <hip/hip_runtime.h>
#include <hip/hip_bf16.h>
#include <math.h>

using u16 = unsigned short;
using u32 = unsigned int;

// Problem constants
constexpr int B   = 64;
constexpr int S   = 128;
constexpr int D   = 512;
constexpr int H   = 8;
constexpr int DK  = 64;
constexpr int L   = 6;
constexpr int DFF = 2048;
constexpr int AH  = 2;
constexpr int BS  = B * S;          // 8192
constexpr int BS2 = 2 * BS;         // 16384 (both passes batched)

// Output layout (fp32 elements)
constexpr long OUT_TOK    = 0;
constexpr long OUT_OUT1   = 8192;
constexpr long OUT_MTOK   = 16384;
constexpr long OUT_OUTM   = 24576;
constexpr long OUT_SCORES = 32768;

// Workspace layout (float units). ~206 MB of ~1 GiB ws
constexpr long OFF_PE   = 0;            // 65536
constexpr long OFF_ASC  = 65536;        // 2*B*H*S = 131072
constexpr long OFF_COLP = 196608;       // B*AH*S = 16384
constexpr long OFF_MTOK = 212992;       // 8192 ints
constexpr long OFF_X    = 221184;       // BS2*D fp32 = 8,388,608
constexpr long OFF_XB   = 8609792;      // BS2*D bf16 = 4,194,304 fl
constexpr long OFF_QB   = 12804096;     // BS2*D bf16
constexpr long OFF_KB   = 16998400;     // BS2*D bf16
constexpr long OFF_VB   = 21192704;     // BS2*D bf16
constexpr long OFF_TB   = 25387008;     // BS2*DFF bf16 = 16,777,216 fl (alias: mask q/k, pre-head parts)
constexpr long OFF_W    = 42164224;     // 6 layers x 3,145,728 bf16 = 9,437,184 fl
constexpr long WSTRIDE  = 3145728;      // bf16 elems per layer

typedef __attribute__((ext_vector_type(8))) short bf16x8;
typedef __attribute__((ext_vector_type(4))) float f32x4;

__device__ __forceinline__ float b2f(u16 u) {
    union { u32 i; float f; } v; v.i = ((u32)u) << 16; return v.f;
}
__device__ __forceinline__ u16 f2b(float f) {      // RNE f32 -> bf16
    union { float f; u32 i; } v; v.f = f;
    u32 r = v.i + 0x7fffu + ((v.i >> 16) & 1u);
    return (u16)(r >> 16);
}

#define GLOAD_LDS16(g, l) __builtin_amdgcn_global_load_lds(                        \
    (const __attribute__((address_space(1))) u32*)(const void*)(g),               \
    (__attribute__((address_space(3))) u32*)(void*)(l), 16, 0, 0)

// ---------------------------------------------------------------- pos enc
__global__ void pe_kernel(float* __restrict__ pe) {
    int idx = blockIdx.x * 256 + threadIdx.x;
    if (idx >= S * (D / 2)) return;
    int s = idx >> 8;
    int i = idx & 255;
    const float CPE = (float)(-9.210340371976184 / 512.0);
    float div = expf((float)(2 * i) * CPE);
    float ang = (float)s * div;
    pe[(long)s * D + 2 * i]     = sinf(ang);
    pe[(long)s * D + 2 * i + 1] = cosf(ang);
}

// ---------------------------------------------------------------- embed + pe (fp32 + bf16 out)
__global__ void embed_dual(const int* __restrict__ toks, const float* __restrict__ emb,
                           const float* __restrict__ pe, float* __restrict__ x,
                           u16* __restrict__ xb) {
    int i8 = blockIdx.x * 256 + threadIdx.x;      // over BS*D/8 = 524288
    if (i8 >= BS * D / 8) return;
    int row = i8 >> 6;
    int c8  = i8 & 63;
    int s   = row & (S - 1);
    int t   = toks[row];
    float4 e0 = *(const float4*)(emb + (long)t * D + c8 * 8);
    float4 e1 = *(const float4*)(emb + (long)t * D + c8 * 8 + 4);
    float4 p0 = *(const float4*)(pe + (long)s * D + c8 * 8);
    float4 p1 = *(const float4*)(pe + (long)s * D + c8 * 8 + 4);
    float4 o0, o1;
    o0.x = e0.x + p0.x; o0.y = e0.y + p0.y; o0.z = e0.z + p0.z; o0.w = e0.w + p0.w;
    o1.x = e1.x + p1.x; o1.y = e1.y + p1.y; o1.z = e1.z + p1.z; o1.w = e1.w + p1.w;
    *(float4*)(x + (long)i8 * 8)     = o0;
    *(float4*)(x + (long)i8 * 8 + 4) = o1;
    u16 u[8] = {f2b(o0.x), f2b(o0.y), f2b(o0.z), f2b(o0.w), f2b(o1.x), f2b(o1.y), f2b(o1.z), f2b(o1.w)};
    *(uint4*)(xb + (long)i8 * 8) = *(uint4*)u;
}

// ---------------------------------------------------------------- all-layer weight transpose+convert
__global__ __launch_bounds__(256)
void wconv_all(const float* __restrict__ tWQ, const float* __restrict__ tWK,
               const float* __restrict__ tWV, const float* __restrict__ tFC,
               const float* __restrict__ tF1, const float* __restrict__ tF2,
               u16* __restrict__ wAll) {
    __shared__ float t[32][33];
    const int lyr = blockIdx.x / 3072;
    const int bid = blockIdx.x % 3072;
    u16* base = wAll + (long)lyr * WSTRIDE;
    const float* src; u16* dst; int KK, NN, tk, tn;
    if (bid < 1024) {
        int which = bid >> 8, tt = bid & 255;
        src = (which == 0 ? tWQ : which == 1 ? tWK : which == 2 ? tWV : tFC) + (long)lyr * D * D;
        dst = base + (long)which * 262144;
        KK = 512; NN = 512; tk = tt >> 4; tn = tt & 15;
    } else if (bid < 2048) {
        int tt = bid - 1024;
        src = tF1 + (long)lyr * D * DFF; dst = base + 1048576;
        KK = 512; NN = 2048; tk = tt >> 6; tn = tt & 63;
    } else {
        int tt = bid - 2048;
        src = tF2 + (long)lyr * DFF * D; dst = base + 2097152;
        KK = 2048; NN = 512; tk = tt >> 4; tn = tt & 15;
    }
    int ty = threadIdx.x >> 5, tx = threadIdx.x & 31;
    #pragma unroll
    for (int i = 0; i < 4; i++)
        t[ty + i * 8][tx] = src[(long)(tk * 32 + ty + i * 8) * NN + tn * 32 + tx];
    __syncthreads();
    #pragma unroll
    for (int i = 0; i < 4; i++)
        dst[(long)(tn * 32 + ty + i * 8) * KK + tk * 32 + tx] = f2b(t[tx][ty + i * 8]);
}

// ---------------------------------------------------------------- bf16 MFMA GEMM core (128x128, 4 waves)
template<int EPI, int OUTB>
__device__ __forceinline__ void gemm_core(
        const u16* __restrict__ A, const u16* __restrict__ Wt,
        float* C, u16* Cb, const float* __restrict__ X,
        int M, int N, int K, int m0, int n0) {
    __shared__ u16 As[128 * 32];
    __shared__ u16 Bs[128 * 32];
    const int tid = threadIdx.x;
    const int w = tid >> 6, l = tid & 63;
    const int wr = (w >> 1) * 64, wc = (w & 1) * 64;
    f32x4 acc[4][4];
    #pragma unroll
    for (int i = 0; i < 4; i++)
        #pragma unroll
        for (int j = 0; j < 4; j++) { f32x4 z = {0.f, 0.f, 0.f, 0.f}; acc[i][j] = z; }

    const int srow = w * 32 + (l >> 2);
    const int scol = (l & 3) * 8;
    const u16* gA = A + (long)(m0 + srow) * K + scol;
    const u16* gB = Wt + (long)(n0 + srow) * K + scol;
    u16* lA0 = As + w * 1024;
    u16* lA1 = As + w * 1024 + 512;
    u16* lB0 = Bs + w * 1024;
    u16* lB1 = Bs + w * 1024 + 512;

    for (int k0 = 0; k0 < K; k0 += 32) {
        GLOAD_LDS16(gA + k0,               lA0);
        GLOAD_LDS16(gA + (long)16 * K + k0, lA1);
        GLOAD_LDS16(gB + k0,               lB0);
        GLOAD_LDS16(gB + (long)16 * K + k0, lB1);
        __syncthreads();
        bf16x8 aF[4], bF[4];
        #pragma unroll
        for (int mi = 0; mi < 4; mi++)
            aF[mi] = *(const bf16x8*)(As + (wr + mi * 16 + (l & 15)) * 32 + (l >> 4) * 8);
        #pragma unroll
        for (int ni = 0; ni < 4; ni++)
            bF[ni] = *(const bf16x8*)(Bs + (wc + ni * 16 + (l & 15)) * 32 + (l >> 4) * 8);
        #pragma unroll
        for (int mi = 0; mi < 4; mi++)
            #pragma unroll
            for (int ni = 0; ni < 4; ni++)
                acc[mi][ni] = __builtin_amdgcn_mfma_f32_16x16x32_bf16(aF[mi], bF[ni], acc[mi][ni], 0, 0, 0);
        __syncthreads();
    }

    #pragma unroll
    for (int mi = 0; mi < 4; mi++) {
        #pragma unroll
        for (int ni = 0; ni < 4; ni++) {
            const int col = n0 + wc + ni * 16 + (l & 15);
            #pragma unroll
            for (int r = 0; r < 4; r++) {
                const int row = m0 + wr + mi * 16 + (l >> 4) * 4 + r;
                const long idx = (long)row * N + col;
                float v = acc[mi][ni][r];
                if (EPI == 1) v += X[idx];
                if (EPI == 2) v = fmaxf(v, 0.0f);
                if (OUTB) Cb[idx] = f2b(v);
                else      C[idx]  = v;
            }
        }
    }
}

__global__ __launch_bounds__(256)
void gemm_qkv_b(const u16* __restrict__ A, const u16* wq, const u16* wk, const u16* wv,
                u16* qb, u16* kb, u16* vb, int M, int N, int K) {
    const u16* Wt = blockIdx.z == 0 ? wq : blockIdx.z == 1 ? wk : wv;
    u16* Cb       = blockIdx.z == 0 ? qb : blockIdx.z == 1 ? kb : vb;
    gemm_core<0, 1>(A, Wt, nullptr, Cb, nullptr, M, N, K, blockIdx.x * 128, blockIdx.y * 128);
}
__global__ __launch_bounds__(256)
void gemm_relu_b(const u16* __restrict__ A, const u16* __restrict__ Wt,
                 u16* Cb, int M, int N, int K) {
    gemm_core<2, 1>(A, Wt, nullptr, Cb, nullptr, M, N, K, blockIdx.x * 128, blockIdx.y * 128);
}

// ---------------------------------------------------------------- GEMM + residual + LayerNorm fused v2
// 32 rows x full width 512 per block; 256 threads = 4 waves; wave w owns cols [w*128, w*128+128).
// Grid = BS2/32 = 512 blocks (2 blocks/CU -> inter-block latency hiding).
// out = LN(A @ Wt + x); writes x fp32 (if writeX) and xb bf16.
__global__ __launch_bounds__(256)
void gemm_ln2(const u16* __restrict__ A, const u16* __restrict__ Wt,
              float* x, u16* __restrict__ xb, int K, int writeX) {
    __shared__ u16 As[32 * 32];      // 2 KB
    __shared__ u16 Bs[512 * 32];     // 32 KB
    __shared__ float redS[32][5];
    __shared__ float redQ[32][5];
    __shared__ float meanS[32], invS[32];
    const int m0 = blockIdx.x * 32;
    const int tid = threadIdx.x;
    const int w = tid >> 6, l = tid & 63;
    const int wc = w * 128;

    f32x4 acc[2][8];
    #pragma unroll
    for (int i = 0; i < 2; i++)
        #pragma unroll
        for (int j = 0; j < 8; j++) { f32x4 z = {0.f, 0.f, 0.f, 0.f}; acc[i][j] = z; }

    const int srow = l >> 2;          // 0..15
    const int scol = (l & 3) * 8;
    const u16* gB = Wt + (long)(wc + srow) * K + scol;   // wave stages its own 128 B-rows
    u16* lB = Bs + wc * 32;
    const u16* gA = A + (long)(m0 + w * 16 + srow) * K + scol;   // waves 0,1 stage A
    u16* lA = As + (w * 16) * 32;

    for (int k0 = 0; k0 < K; k0 += 32) {
        if (w < 2) GLOAD_LDS16(gA + k0, lA);
        #pragma unroll
        for (int j = 0; j < 8; j++)
            GLOAD_LDS16(gB + (long)j * 16 * K + k0, lB + j * 16 * 32);
        __syncthreads();
        bf16x8 aF[2];
        aF[0] = *(const bf16x8*)(As + ((l & 15)) * 32 + (l >> 4) * 8);
        aF[1] = *(const bf16x8*)(As + (16 + (l & 15)) * 32 + (l >> 4) * 8);
        #pragma unroll
        for (int ni = 0; ni < 8; ni++) {
            bf16x8 bF = *(const bf16x8*)(Bs + (wc + ni * 16 + (l & 15)) * 32 + (l >> 4) * 8);
            acc[0][ni] = __builtin_amdgcn_mfma_f32_16x16x32_bf16(aF[0], bF, acc[0][ni], 0, 0, 0);
            acc[1][ni] = __builtin_amdgcn_mfma_f32_16x16x32_bf16(aF[1], bF, acc[1][ni], 0, 0, 0);
        }
        __syncthreads();
    }

    // residual add + per-row partial sums (each 16-lane group holds one row slice of 128 cols)
    #pragma unroll
    for (int mi = 0; mi < 2; mi++)
        #pragma unroll
        for (int r = 0; r < 4; r++) {
            const int row = mi * 16 + (l >> 4) * 4 + r;
            float s = 0.0f, q = 0.0f;
            #pragma unroll
            for (int ni = 0; ni < 8; ni++) {
                const int col = wc + ni * 16 + (l & 15);
                float v = acc[mi][ni][r] + x[(long)(m0 + row) * D + col];
                acc[mi][ni][r] = v;
                s += v; q += v * v;
            }
            s += __shfl_xor(s, 1); s += __shfl_xor(s, 2); s += __shfl_xor(s, 4); s += __shfl_xor(s, 8);
            q += __shfl_xor(q, 1); q += __shfl_xor(q, 2); q += __shfl_xor(q, 4); q += __shfl_xor(q, 8);
            if ((l & 15) == 0) { redS[row][w] = s; redQ[row][w] = q; }
        }
    __syncthreads();
    if (tid < 32) {
        float s = 0.0f, q = 0.0f;
        #pragma unroll
        for (int ww = 0; ww < 4; ww++) { s += redS[tid][ww]; q += redQ[tid][ww]; }
        float mean = s * (1.0f / 512.0f);
        float var  = q * (1.0f / 512.0f) - mean * mean;
        meanS[tid] = mean;
        invS[tid]  = 1.0f / sqrtf(var + 1e-5f);
    }
    __syncthreads();
    #pragma unroll
    for (int mi = 0; mi < 2; mi++)
        #pragma unroll
        for (int r = 0; r < 4; r++) {
            const int row = mi * 16 + (l >> 4) * 4 + r;
            const float mn = meanS[row], iv = invS[row];
            #pragma unroll
            for (int ni = 0; ni < 8; ni++) {
                const int col = wc + ni * 16 + (l & 15);
                const long idx = (long)(m0 + row) * D + col;
                float o = (acc[mi][ni][r] - mn) * iv;
                if (writeX) x[idx] = o;
                xb[idx] = f2b(o);
            }
        }
}

// ---------------------------------------------------------------- fp32 GEMM (pre-head tail)
template<int EPI>
__global__ __launch_bounds__(256)
void gemm64(const float* __restrict__ A, const float* __restrict__ W,
            float* C, const float* X, int M, int N, int K) {
    __shared__ float As[32][68];
    __shared__ float Ws[32][64];
    const int m0 = blockIdx.x * 64, n0 = blockIdx.y * 64;
    const int tid  = threadIdx.x;
    const int tr   = tid >> 4, tc = tid & 15;
    const int arow = tid >> 3, acg = tid & 7;
    const int wrow = tid >> 4, wcg = tid & 15;
    float acc[4][4] = {};
    for (int k0 = 0; k0 < K; k0 += 32) {
        float4 a0 = *(const float4*)(A + (long)(m0 + arow) * K + k0 + acg * 4);
        float4 a1 = *(const float4*)(A + (long)(m0 + arow + 32) * K + k0 + acg * 4);
        float4 w0 = *(const float4*)(W + (long)(k0 + wrow) * N + n0 + wcg * 4);
        float4 w1 = *(const float4*)(W + (long)(k0 + wrow + 16) * N + n0 + wcg * 4);
        As[acg * 4 + 0][arow] = a0.x; As[acg * 4 + 1][arow] = a0.y;
        As[acg * 4 + 2][arow] = a0.z; As[acg * 4 + 3][arow] = a0.w;
        As[acg * 4 + 0][arow + 32] = a1.x; As[acg * 4 + 1][arow + 32] = a1.y;
        As[acg * 4 + 2][arow + 32] = a1.z; As[acg * 4 + 3][arow + 32] = a1.w;
        *(float4*)&Ws[wrow][wcg * 4]      = w0;
        *(float4*)&Ws[wrow + 16][wcg * 4] = w1;
        __syncthreads();
        #pragma unroll
        for (int kk = 0; kk < 32; kk++) {
            float4 av = *(const float4*)&As[kk][tr * 4];
            float4 bv = *(const float4*)&Ws[kk][tc * 4];
            acc[0][0] += av.x * bv.x; acc[0][1] += av.x * bv.y; acc[0][2] += av.x * bv.z; acc[0][3] += av.x * bv.w;
            acc[1][0] += av.y * bv.x; acc[1][1] += av.y * bv.y; acc[1][2] += av.y * bv.z; acc[1][3] += av.y * bv.w;
            acc[2][0] += av.z * bv.x; acc[2][1] += av.z * bv.y; acc[2][2] += av.z * bv.z; acc[2][3] += av.z * bv.w;
            acc[3][0] += av.w * bv.x; acc[3][1] += av.w * bv.y; acc[3][2] += av.w * bv.z; acc[3][3] += av.w * bv.w;
        }
        __syncthreads();
    }
    #pragma unroll
    for (int i = 0; i < 4; i++) {
        int row = m0 + tr * 4 + i;
        #pragma unroll
        for (int j = 0; j < 4; j++) {
            int col = n0 + tc * 4 + j;
            long idx = (long)row * N + col;
            float v = acc[i][j];
            if (EPI == 1) v += X[idx];
            if (EPI == 3 || EPI == 4) v += X[col];
            if (EPI == 2 || EPI == 4) v = fmaxf(v, 0.0f);
            C[idx] = v;
        }
    }
}

// QKV merged fp32 (mask encoder)
__global__ __launch_bounds__(256)
void gemm64_qkv(const float* __restrict__ A,
                const float* __restrict__ WQ, const float* __restrict__ WK, const float* __restrict__ WV,
                float* q, float* k, float* v, int M, int N, int K) {
    __shared__ float As[32][68];
    __shared__ float Ws[32][64];
    const float* W = (blockIdx.z == 0) ? WQ : (blockIdx.z == 1) ? WK : WV;
    float*       C = (blockIdx.z == 0) ? q  : (blockIdx.z == 1) ? k  : v;
    const int m0 = blockIdx.x * 64, n0 = blockIdx.y * 64;
    const int tid  = threadIdx.x;
    const int tr   = tid >> 4, tc = tid & 15;
    const int arow = tid >> 3, acg = tid & 7;
    const int wrow = tid >> 4, wcg = tid & 15;
    float acc[4][4] = {};
    for (int k0 = 0; k0 < K; k0 += 32) {
        float4 a0 = *(const float4*)(A + (long)(m0 + arow) * K + k0 + acg * 4);
        float4 a1 = *(const float4*)(A + (long)(m0 + arow + 32) * K + k0 + acg * 4);
        float4 w0 = *(const float4*)(W + (long)(k0 + wrow) * N + n0 + wcg * 4);
        float4 w1 = *(const float4*)(W + (long)(k0 + wrow + 16) * N + n0 + wcg * 4);
        As[acg * 4 + 0][arow] = a0.x; As[acg * 4 + 1][arow] = a0.y;
        As[acg * 4 + 2][arow] = a0.z; As[acg * 4 + 3][arow] = a0.w;
        As[acg * 4 + 0][arow + 32] = a1.x; As[acg * 4 + 1][arow + 32] = a1.y;
        As[acg * 4 + 2][arow + 32] = a1.z; As[acg * 4 + 3][arow + 32] = a1.w;
        *(float4*)&Ws[wrow][wcg * 4]      = w0;
        *(float4*)&Ws[wrow + 16][wcg * 4] = w1;
        __syncthreads();
        #pragma unroll
        for (int kk = 0; kk < 32; kk++) {
            float4 av = *(const float4*)&As[kk][tr * 4];
            float4 bv = *(const float4*)&Ws[kk][tc * 4];
            acc[0][0] += av.x * bv.x; acc[0][1] += av.x * bv.y; acc[0][2] += av.x * bv.z; acc[0][3] += av.x * bv.w;
            acc[1][0] += av.y * bv.x; acc[1][1] += av.y * bv.y; acc[1][2] += av.y * bv.z; acc[1][3] += av.y * bv.w;
            acc[2][0] += av.z * bv.x; acc[2][1] += av.z * bv.y; acc[2][2] += av.z * bv.z; acc[2][3] += av.z * bv.w;
            acc[3][0] += av.w * bv.x; acc[3][1] += av.w * bv.y; acc[3][2] += av.w * bv.z; acc[3][3] += av.w * bv.w;
        }
        __syncthreads();
    }
    #pragma unroll
    for (int i = 0; i < 4; i++)
        #pragma unroll
        for (int j = 0; j < 4; j++)
            C[(long)(m0 + tr * 4 + i) * N + n0 + tc * 4 + j] = acc[i][j];
}

// ---------------------------------------------------------------- pre-head layer-1: MFMA split-K
__global__ __launch_bounds__(256)
void gemm_ph1(const u16* __restrict__ Ah, const u16* __restrict__ Ahm,
              const float* __restrict__ W, float* __restrict__ P, int KC) {
    constexpr int N = 1024, K = 65536;
    __shared__ u16 As[128 * 32];
    __shared__ u16 Bs[128 * 32];
    const int n0 = blockIdx.x * 128;
    const int kbeg = blockIdx.y * KC;
    const int tid = threadIdx.x;
    const int w = tid >> 6, l = tid & 63;
    const int wr = w * 32;
    const int nl = tid >> 1, seg = tid & 1;
    const u16* aptr = (nl < 64 ? Ah + (long)nl * K : Ahm + (long)(nl - 64) * K) + seg * 16;
    const float* wcol = W + n0 + nl;

    f32x4 acc[2][8];
    #pragma unroll
    for (int mi = 0; mi < 2; mi++)
        #pragma unroll
        for (int ni = 0; ni < 8; ni++) { f32x4 z = {0.f, 0.f, 0.f, 0.f}; acc[mi][ni] = z; }

    for (int ks = 0; ks < KC; ks += 32) {
        const int k0 = kbeg + ks;
        uint4 a0 = *(const uint4*)(aptr + k0);
        uint4 a1 = *(const uint4*)(aptr + k0 + 8);
        float wv[16];
        #pragma unroll
        for (int j = 0; j < 16; j++)
            wv[j] = wcol[(long)(k0 + seg * 16 + j) * N];
        __syncthreads();
        *(uint4*)(As + nl * 32 + seg * 16)     = a0;
        *(uint4*)(As + nl * 32 + seg * 16 + 8) = a1;
        u32 pk[8];
        #pragma unroll
        for (int j = 0; j < 8; j++)
            pk[j] = (u32)f2b(wv[2 * j]) | ((u32)f2b(wv[2 * j + 1]) << 16);
        *(uint4*)(Bs + nl * 32 + seg * 16)     = *(uint4*)&pk[0];
        *(uint4*)(Bs + nl * 32 + seg * 16 + 8) = *(uint4*)&pk[4];
        __syncthreads();
        bf16x8 aF0 = *(const bf16x8*)(As + (wr + (l & 15)) * 32 + (l >> 4) * 8);
        bf16x8 aF1 = *(const bf16x8*)(As + (wr + 16 + (l & 15)) * 32 + (l >> 4) * 8);
        #pragma unroll
        for (int ni = 0; ni < 8; ni++) {
            bf16x8 bF = *(const bf16x8*)(Bs + (ni * 16 + (l & 15)) * 32 + (l >> 4) * 8);
            acc[0][ni] = __builtin_amdgcn_mfma_f32_16x16x32_bf16(aF0, bF, acc[0][ni], 0, 0, 0);
            acc[1][ni] = __builtin_amdgcn_mfma_f32_16x16x32_bf16(aF1, bF, acc[1][ni], 0, 0, 0);
        }
    }
    float* Pz = P + (long)blockIdx.y * 128 * N;
    #pragma unroll
    for (int mi = 0; mi < 2; mi++)
        #pragma unroll
        for (int ni = 0; ni < 8; ni++) {
            const int col = n0 + ni * 16 + (l & 15);
            #pragma unroll
            for (int r = 0; r < 4; r++)
                Pz[(long)(wr + mi * 16 + (l >> 4) * 4 + r) * N + col] = acc[mi][ni][r];
        }
}

// ---------------------------------------------------------------- fp32 attention (mask path, colsum only)
__global__ __launch_bounds__(128)
void attn_kernel(const float* __restrict__ Q, const float* __restrict__ K,
                 const int* __restrict__ toks, float* __restrict__ colsum, int Hn) {
    __shared__ float sc[S][129];
    __shared__ float KV[S][DK];
    __shared__ int   padS[S];
    const int b = blockIdx.x / Hn;
    const int h = blockIdx.x % Hn;
    const int stride = Hn * DK;
    const int tid = threadIdx.x;

    for (int idx = tid; idx < S * DK; idx += 128) {
        int r = idx >> 6, c = idx & 63;
        KV[r][c] = K[(long)(b * S + r) * stride + h * DK + c];
    }
    padS[tid] = (toks[b * S + tid] == 0) ? 1 : 0;
    float qreg[DK];
    {
        const float* qp = Q + (long)(b * S + tid) * stride + h * DK;
        #pragma unroll
        for (int i = 0; i < 16; i++) {
            float4 t4 = *(const float4*)(qp + i * 4);
            qreg[i * 4 + 0] = t4.x; qreg[i * 4 + 1] = t4.y;
            qreg[i * 4 + 2] = t4.z; qreg[i * 4 + 3] = t4.w;
        }
    }
    __syncthreads();
    for (int k = 0; k < S; k++) {
        float s = 0.0f;
        #pragma unroll
        for (int d4 = 0; d4 < 16; d4++) {
            float4 kv = *(const float4*)&KV[k][d4 * 4];
            s += qreg[d4 * 4 + 0] * kv.x + qreg[d4 * 4 + 1] * kv.y
               + qreg[d4 * 4 + 2] * kv.z + qreg[d4 * 4 + 3] * kv.w;
        }
        sc[tid][k] = padS[k] ? -1e9f : (s * 0.125f);
    }
    float mx = -INFINITY;
    for (int k = 0; k < S; k++) mx = fmaxf(mx, sc[tid][k]);
    float sum = 0.0f;
    for (int k = 0; k < S; k++) { float e = expf(sc[tid][k] - mx); sc[tid][k] = e; sum += e; }
    for (int k = 0; k < S; k++) sc[tid][k] = sc[tid][k] / sum;
    __syncthreads();
    {
        double a = 0.0;
        for (int q2 = 0; q2 < S; q2++) a += (double)sc[q2][tid];
        colsum[(long)(b * Hn + h) * S + tid] = (float)a;
    }
}

// ---------------------------------------------------------------- MFMA attention (batched passes)
__global__ __launch_bounds__(256)
void attn_mfma_kernel(u16* qb, const u16* __restrict__ kb, const u16* __restrict__ vb,
                      const int* __restrict__ toks, const int* __restrict__ mtok,
                      float* __restrict__ colsum) {
    __shared__ u16 pool[18432];          // Qs[128][72] | Ks[128][72] ; Ps[128][136] aliases
    __shared__ u16 Vt[64 * 136];
    __shared__ float colsLds[4][128];
    __shared__ u32 padF[128];
    u16* Qs = pool;
    u16* Ks = pool + 9216;
    u16* Ps = pool;

    const int gb = blockIdx.x >> 3, h = blockIdx.x & 7;
    const int tid = threadIdx.x;
    const int w = tid >> 6, l = tid & 63;
    const long base = (long)gb * S * D + h * 64;
    const int* tsrc = (gb < B) ? (toks + (long)gb * S) : (mtok + (long)(gb - B) * S);

    for (int j = tid; j < 1024; j += 256) {
        int r = j >> 3, c = j & 7;
        uint4 uq = *(const uint4*)(qb + base + (long)r * D + c * 8);
        uint4 uk = *(const uint4*)(kb + base + (long)r * D + c * 8);
        uint4 uv = *(const uint4*)(vb + base + (long)r * D + c * 8);
        *(uint4*)(Qs + r * 72 + c * 8) = uq;
        *(uint4*)(Ks + r * 72 + c * 8) = uk;
        u16 vv[8]; *(uint4*)vv = uv;
        #pragma unroll
        for (int t = 0; t < 8; t++) Vt[(c * 8 + t) * 136 + r] = vv[t];
    }
    if (tid < 128) padF[tid] = (tsrc[tid] == 0) ? 1u : 0u;
    __syncthreads();

    const int rowB = w * 32;
    f32x4 acc[2][8];
    #pragma unroll
    for (int mi = 0; mi < 2; mi++)
        #pragma unroll
        for (int ni = 0; ni < 8; ni++) { f32x4 z = {0.f, 0.f, 0.f, 0.f}; acc[mi][ni] = z; }
    #pragma unroll
    for (int ks = 0; ks < 2; ks++) {
        bf16x8 a0 = *(const bf16x8*)(Qs + (rowB + (l & 15)) * 72 + ks * 32 + (l >> 4) * 8);
        bf16x8 a1 = *(const bf16x8*)(Qs + (rowB + 16 + (l & 15)) * 72 + ks * 32 + (l >> 4) * 8);
        #pragma unroll
        for (int ni = 0; ni < 8; ni++) {
            bf16x8 bv = *(const bf16x8*)(Ks + (ni * 16 + (l & 15)) * 72 + ks * 32 + (l >> 4) * 8);
            acc[0][ni] = __builtin_amdgcn_mfma_f32_16x16x32_bf16(a0, bv, acc[0][ni], 0, 0, 0);
            acc[1][ni] = __builtin_amdgcn_mfma_f32_16x16x32_bf16(a1, bv, acc[1][ni], 0, 0, 0);
        }
    }
    float pf[8];
    #pragma unroll
    for (int ni = 0; ni < 8; ni++) pf[ni] = padF[ni * 16 + (l & 15)] ? 1.0f : 0.0f;
    #pragma unroll
    for (int mi = 0; mi < 2; mi++)
        #pragma unroll
        for (int ni = 0; ni < 8; ni++)
            #pragma unroll
            for (int r = 0; r < 4; r++) {
                float v = acc[mi][ni][r] * 0.125f;
                acc[mi][ni][r] = (pf[ni] != 0.0f) ? -1e9f : v;
            }
    #pragma unroll
    for (int mi = 0; mi < 2; mi++)
        #pragma unroll
        for (int r = 0; r < 4; r++) {
            float m = -INFINITY;
            #pragma unroll
            for (int ni = 0; ni < 8; ni++) m = fmaxf(m, acc[mi][ni][r]);
            m = fmaxf(m, __shfl_xor(m, 1)); m = fmaxf(m, __shfl_xor(m, 2));
            m = fmaxf(m, __shfl_xor(m, 4)); m = fmaxf(m, __shfl_xor(m, 8));
            float s = 0.0f;
            #pragma unroll
            for (int ni = 0; ni < 8; ni++) { float e = expf(acc[mi][ni][r] - m); acc[mi][ni][r] = e; s += e; }
            s += __shfl_xor(s, 1); s += __shfl_xor(s, 2);
            s += __shfl_xor(s, 4); s += __shfl_xor(s, 8);
            float inv = 1.0f / s;
            #pragma unroll
            for (int ni = 0; ni < 8; ni++) acc[mi][ni][r] *= inv;
        }
    float cs[8];
    #pragma unroll
    for (int ni = 0; ni < 8; ni++) {
        float s = 0.0f;
        #pragma unroll
        for (int mi = 0; mi < 2; mi++)
            #pragma unroll
            for (int r = 0; r < 4; r++) s += acc[mi][ni][r];
        s += __shfl_xor(s, 16); s += __shfl_xor(s, 32);
        cs[ni] = s;
    }
    __syncthreads();
    if (l < 16)
        #pragma unroll
        for (int ni = 0; ni < 8; ni++) colsLds[w][ni * 16 + l] = cs[ni];
    #pragma unroll
    for (int mi = 0; mi < 2; mi++)
        #pragma unroll
        for (int ni = 0; ni < 8; ni++)
            #pragma unroll
            for (int r = 0; r < 4; r++)
                Ps[(rowB + mi * 16 + (l >> 4) * 4 + r) * 136 + ni * 16 + (l & 15)] =
                    f2b(acc[mi][ni][r]);
    __syncthreads();
    if (tid < 128) {
        float s = colsLds[0][tid] + colsLds[1][tid] + colsLds[2][tid] + colsLds[3][tid];
        colsum[((long)gb * H + h) * S + tid] = s;
    }
    f32x4 o[2][4];
    #pragma unroll
    for (int mi = 0; mi < 2; mi++)
        #pragma unroll
        for (int n = 0; n < 4; n++) { f32x4 z = {0.f, 0.f, 0.f, 0.f}; o[mi][n] = z; }
    #pragma unroll
    for (int ks = 0; ks < 4; ks++) {
        bf16x8 p0 = *(const bf16x8*)(Ps + (rowB + (l & 15)) * 136 + ks * 32 + (l >> 4) * 8);
        bf16x8 p1 = *(const bf16x8*)(Ps + (rowB + 16 + (l & 15)) * 136 + ks * 32 + (l >> 4) * 8);
        #pragma unroll
        for (int n = 0; n < 4; n++) {
            bf16x8 bv = *(const bf16x8*)(Vt + (n * 16 + (l & 15)) * 136 + ks * 32 + (l >> 4) * 8);
            o[0][n] = __builtin_amdgcn_mfma_f32_16x16x32_bf16(p0, bv, o[0][n], 0, 0, 0);
            o[1][n] = __builtin_amdgcn_mfma_f32_16x16x32_bf16(p1, bv, o[1][n], 0, 0, 0);
        }
    }
    #pragma unroll
    for (int mi = 0; mi < 2; mi++)
        #pragma unroll
        for (int n = 0; n < 4; n++) {
            const int col = n * 16 + (l & 15);
            #pragma unroll
            for (int r = 0; r < 4; r++) {
                const int row = rowB + mi * 16 + (l >> 4) * 4 + r;
                qb[base + (long)row * D + col] = f2b(o[mi][n][r]);
            }
        }
}

// ---------------------------------------------------------------- creat_mask
__global__ __launch_bounds__(128)
void creat_mask_kernel(const float* __restrict__ colpart, const int* __restrict__ toks,
                       int* __restrict__ mtok, float* __restrict__ out) {
    __shared__ float colS[S];
    __shared__ int   j0s, kks;
    const int b = blockIdx.x, j = threadIdx.x;
    float c = colpart[(long)(b * AH + 0) * S + j] + colpart[(long)(b * AH + 1) * S + j];
    colS[j] = c;
    int tk = toks[b * S + j];
    __syncthreads();
    if (j == 0) {
        int j0 = S;
        for (int i = 0; i < S; i++) if (colS[i] == 0.0f) { j0 = i; break; }
        int kk = (j0 < S) ? (int)ceilf(0.2f * (float)j0) : 0;
        j0s = j0; kks = kk;
    }
    __syncthreads();
    const int j0 = j0s, kk = kks;
    float vj = (j < j0) ? colS[j] : INFINITY;
    int rank = 0;
    for (int i = 0; i < S; i++) {
        float vi = (i < j0) ? colS[i] : INFINITY;
        if (vi < vj || (vi == vj && i < j)) rank++;
    }
    int mt = (rank >= kk) ? tk : 0;
    mtok[b * S + j] = mt;
    out[OUT_TOK + b * S + j]  = (float)tk;
    out[OUT_MTOK + b * S + j] = (float)mt;
}

// ---------------------------------------------------------------- scores output (pass-0 half)
__global__ void score_reduce_kernel(const float* __restrict__ ascorep, float* __restrict__ dst) {
    int idx = blockIdx.x * 256 + threadIdx.x;
    if (idx >= B * S) return;
    int b = idx >> 7, j = idx & 127;
    float s = 0.0f;
    for (int h = 0; h < H; h++) s += ascorep[(long)(b * H + h) * S + j];
    dst[idx] = s;
}

// ---------------------------------------------------------------- pre-head reduce/pack
__global__ void reduce1_kernel(const float* __restrict__ parts, const float* __restrict__ b1,
                               float* __restrict__ o) {
    int idx = blockIdx.x * 256 + threadIdx.x;
    if (idx >= 128 * 1024) return;
    float s = 0.0f;
    for (int z = 0; z < 64; z++) s += parts[(long)z * 128 * 1024 + idx];
    s += b1[idx & 1023];
    o[idx] = fmaxf(s, 0.0f);
}

__global__ void pack_out_kernel(const float* __restrict__ ph3, float* __restrict__ out) {
    int idx = blockIdx.x * 256 + threadIdx.x;
    if (idx >= 128 * 128) return;
    int row = idx >> 7, col = idx & 127;
    long base = (row < 64) ? (OUT_OUT1 + (long)row * 128) : (OUT_OUTM + (long)(row - 64) * 128);
    out[base + col] = ph3[idx];
}

// ================================================================ launch
extern "C" void kernel_launch(void* const* d_in, const int* in_sizes, int n_in,
                              void* d_out, int out_size, void* d_ws, size_t ws_size,
                              hipStream_t stream) {
    const int*   toks = (const int*)d_in[0];
    const float* emb  = (const float*)d_in[1];
    const float* aWQ  = (const float*)d_in[2];
    const float* aWK  = (const float*)d_in[3];
    const float* tWQ  = (const float*)d_in[8];
    const float* tWK  = (const float*)d_in[9];
    const float* tWV  = (const float*)d_in[10];
    const float* tFC  = (const float*)d_in[11];
    const float* tF1  = (const float*)d_in[12];
    const float* tF2  = (const float*)d_in[13];
    const float* pW1  = (const float*)d_in[14];
    const float* pb1  = (const float*)d_in[15];
    const float* pW2  = (const float*)d_in[16];
    const float* pb2  = (const float*)d_in[17];
    const float* pW3  = (const float*)d_in[18];
    const float* pb3  = (const float*)d_in[19];
    float* out = (float*)d_out;

    float* ws   = (float*)d_ws;
    float* pe   = ws + OFF_PE;
    float* ascp = ws + OFF_ASC;
    float* colp = ws + OFF_COLP;
    int*   mtok = (int*)(ws + OFF_MTOK);
    float* x    = ws + OFF_X;          // [BS2][D] fp32 (h ‖ hm)
    u16*   xb   = (u16*)(ws + OFF_XB); // [BS2][D] bf16
    u16*   qb   = (u16*)(ws + OFF_QB);
    u16*   kb   = (u16*)(ws + OFF_KB);
    u16*   vb   = (u16*)(ws + OFF_VB);
    u16*   tb   = (u16*)(ws + OFF_TB); // [BS2][DFF] bf16
    u16*   wAll = (u16*)(ws + OFF_W);

    // phase-disjoint aliases of the TB region
    float* maq   = ws + OFF_TB;                 // mask encoder q [BS][128] fp32
    float* mak   = maq + (long)BS * 128;
    float* parts = ws + OFF_TB;                 // pre-head partials 64 x [128][1024]
    float* ph1o  = parts + 8388608;
    float* ph2o  = ph1o + 131072;
    float* ph3o  = ph2o + 65536;

    // --- setup: pos-enc, all-layer weight conversion, clean embedding
    pe_kernel<<<128, 256, 0, stream>>>(pe);
    wconv_all<<<6 * 3072, 256, 0, stream>>>(tWQ, tWK, tWV, tFC, tF1, tF2, wAll);
    embed_dual<<<2048, 256, 0, stream>>>(toks, emb, pe, x, xb);

    // --- mask-generating encoder (fp32; only the attention matrix is consumed)
    gemm64_qkv<<<dim3(BS / 64, 2, 2), 256, 0, stream>>>(
        x, aWQ, aWK, nullptr, maq, mak, nullptr, BS, AH * DK, D);
    attn_kernel<<<B * AH, 128, 0, stream>>>(maq, mak, toks, colp, AH);
    creat_mask_kernel<<<B, 128, 0, stream>>>(colp, toks, mtok, out);
    embed_dual<<<2048, 256, 0, stream>>>(mtok, emb, pe, x + (long)BS * D, xb + (long)BS * D);

    // --- 6 layers, both passes batched (rows 0..8191 = clean, 8192..16383 = masked)
    for (int l = 0; l < L; l++) {
        const u16* wq = wAll + (long)l * WSTRIDE;
        const u16* wk = wq + 262144;
        const u16* wv = wq + 524288;
        const u16* wo = wq + 786432;
        const u16* w1 = wq + 1048576;
        const u16* w2 = wq + 2097152;
        gemm_qkv_b<<<dim3(BS2 / 128, D / 128, 3), 256, 0, stream>>>(
            xb, wq, wk, wv, qb, kb, vb, BS2, D, D);
        attn_mfma_kernel<<<2 * B * H, 256, 0, stream>>>(qb, kb, vb, toks, mtok, ascp);
        score_reduce_kernel<<<32, 256, 0, stream>>>(ascp, out + OUT_SCORES + (long)l * BS);
        gemm_ln2<<<BS2 / 32, 256, 0, stream>>>(qb, wo, x, xb, D, 1);          // WO+resid+LN
        gemm_relu_b<<<dim3(BS2 / 128, DFF / 128), 256, 0, stream>>>(xb, w1, tb, BS2, DFF, D);
        gemm_ln2<<<BS2 / 32, 256, 0, stream>>>(tb, w2, x, xb, DFF, l < L - 1); // FFN2+resid+LN
    }

    // --- pre_head: MFMA split-K over pW1 (xb already holds bf16 h ‖ hm)
    gemm_ph1<<<dim3(8, 64), 256, 0, stream>>>(xb, xb + (long)BS * D, pW1, parts, 1024);
    reduce1_kernel<<<512, 256, 0, stream>>>(parts, pb1, ph1o);
    gemm64<4><<<dim3(2, 8), 256, 0, stream>>>(ph1o, pW2, ph2o, pb2, 128, 512, 1024);
    gemm64<3><<<dim3(2, 2), 256, 0, stream>>>(ph2o, pW3, ph3o, pb3, 128, 128, 512);
    pack_out_kernel<<<64, 256, 0, stream>>>(ph3o, out);
}

// Round 10
// 1601.325 us; speedup vs baseline: 1.1300x; 1.0861x over previous
//
#include <hip/hip_runtime.h>
#include <hip/hip_bf16.h>
#include <math.h>

using u16 = unsigned short;
using u32 = unsigned int;

// Problem constants
constexpr int B   = 64;
constexpr int S   = 128;
constexpr int D   = 512;
constexpr int H   = 8;
constexpr int DK  = 64;
constexpr int L   = 6;
constexpr int DFF = 2048;
constexpr int AH  = 2;
constexpr int BS  = B * S;          // 8192
constexpr int BS2 = 2 * BS;         // 16384 (both passes batched)

// Output layout (fp32 elements)
constexpr long OUT_TOK    = 0;
constexpr long OUT_OUT1   = 8192;
constexpr long OUT_MTOK   = 16384;
constexpr long OUT_OUTM   = 24576;
constexpr long OUT_SCORES = 32768;

// Workspace layout (float units). ~206 MB of ~1 GiB ws
constexpr long OFF_PE   = 0;            // 65536
constexpr long OFF_ASC  = 65536;        // 2*B*H*S = 131072
constexpr long OFF_COLP = 196608;       // B*AH*S = 16384
constexpr long OFF_MTOK = 212992;       // 8192 ints
constexpr long OFF_X    = 221184;       // BS2*D fp32 = 8,388,608
constexpr long OFF_XB   = 8609792;      // BS2*D bf16 = 4,194,304 fl
constexpr long OFF_QB   = 12804096;     // BS2*D bf16
constexpr long OFF_KB   = 16998400;     // BS2*D bf16
constexpr long OFF_VB   = 21192704;     // BS2*D bf16
constexpr long OFF_TB   = 25387008;     // BS2*DFF bf16 = 16,777,216 fl (alias: mask q/k, pre-head parts)
constexpr long OFF_W    = 42164224;     // 6 layers x 3,145,728 bf16 = 9,437,184 fl
constexpr long WSTRIDE  = 3145728;      // bf16 elems per layer

typedef __attribute__((ext_vector_type(8))) short bf16x8;
typedef __attribute__((ext_vector_type(4))) float f32x4;

__device__ __forceinline__ float b2f(u16 u) {
    union { u32 i; float f; } v; v.i = ((u32)u) << 16; return v.f;
}
__device__ __forceinline__ u16 f2b(float f) {      // RNE f32 -> bf16
    union { float f; u32 i; } v; v.f = f;
    u32 r = v.i + 0x7fffu + ((v.i >> 16) & 1u);
    return (u16)(r >> 16);
}

#define GLOAD_LDS16(g, l) __builtin_amdgcn_global_load_lds(                        \
    (const __attribute__((address_space(1))) u32*)(const void*)(g),               \
    (__attribute__((address_space(3))) u32*)(void*)(l), 16, 0, 0)

// ---------------------------------------------------------------- pos enc
__global__ void pe_kernel(float* __restrict__ pe) {
    int idx = blockIdx.x * 256 + threadIdx.x;
    if (idx >= S * (D / 2)) return;
    int s = idx >> 8;
    int i = idx & 255;
    const float CPE = (float)(-9.210340371976184 / 512.0);
    float div = expf((float)(2 * i) * CPE);
    float ang = (float)s * div;
    pe[(long)s * D + 2 * i]     = sinf(ang);
    pe[(long)s * D + 2 * i + 1] = cosf(ang);
}

// ---------------------------------------------------------------- embed + pe (fp32 + bf16 out)
__global__ void embed_dual(const int* __restrict__ toks, const float* __restrict__ emb,
                           const float* __restrict__ pe, float* __restrict__ x,
                           u16* __restrict__ xb) {
    int i8 = blockIdx.x * 256 + threadIdx.x;      // over BS*D/8 = 524288
    if (i8 >= BS * D / 8) return;
    int row = i8 >> 6;
    int c8  = i8 & 63;
    int s   = row & (S - 1);
    int t   = toks[row];
    float4 e0 = *(const float4*)(emb + (long)t * D + c8 * 8);
    float4 e1 = *(const float4*)(emb + (long)t * D + c8 * 8 + 4);
    float4 p0 = *(const float4*)(pe + (long)s * D + c8 * 8);
    float4 p1 = *(const float4*)(pe + (long)s * D + c8 * 8 + 4);
    float4 o0, o1;
    o0.x = e0.x + p0.x; o0.y = e0.y + p0.y; o0.z = e0.z + p0.z; o0.w = e0.w + p0.w;
    o1.x = e1.x + p1.x; o1.y = e1.y + p1.y; o1.z = e1.z + p1.z; o1.w = e1.w + p1.w;
    *(float4*)(x + (long)i8 * 8)     = o0;
    *(float4*)(x + (long)i8 * 8 + 4) = o1;
    u16 u[8] = {f2b(o0.x), f2b(o0.y), f2b(o0.z), f2b(o0.w), f2b(o1.x), f2b(o1.y), f2b(o1.z), f2b(o1.w)};
    *(uint4*)(xb + (long)i8 * 8) = *(uint4*)u;
}

// ---------------------------------------------------------------- all-layer weight transpose+convert
__global__ __launch_bounds__(256)
void wconv_all(const float* __restrict__ tWQ, const float* __restrict__ tWK,
               const float* __restrict__ tWV, const float* __restrict__ tFC,
               const float* __restrict__ tF1, const float* __restrict__ tF2,
               u16* __restrict__ wAll) {
    __shared__ float t[32][33];
    const int lyr = blockIdx.x / 3072;
    const int bid = blockIdx.x % 3072;
    u16* base = wAll + (long)lyr * WSTRIDE;
    const float* src; u16* dst; int KK, NN, tk, tn;
    if (bid < 1024) {
        int which = bid >> 8, tt = bid & 255;
        src = (which == 0 ? tWQ : which == 1 ? tWK : which == 2 ? tWV : tFC) + (long)lyr * D * D;
        dst = base + (long)which * 262144;
        KK = 512; NN = 512; tk = tt >> 4; tn = tt & 15;
    } else if (bid < 2048) {
        int tt = bid - 1024;
        src = tF1 + (long)lyr * D * DFF; dst = base + 1048576;
        KK = 512; NN = 2048; tk = tt >> 6; tn = tt & 63;
    } else {
        int tt = bid - 2048;
        src = tF2 + (long)lyr * DFF * D; dst = base + 2097152;
        KK = 2048; NN = 512; tk = tt >> 4; tn = tt & 15;
    }
    int ty = threadIdx.x >> 5, tx = threadIdx.x & 31;
    #pragma unroll
    for (int i = 0; i < 4; i++)
        t[ty + i * 8][tx] = src[(long)(tk * 32 + ty + i * 8) * NN + tn * 32 + tx];
    __syncthreads();
    #pragma unroll
    for (int i = 0; i < 4; i++)
        dst[(long)(tn * 32 + ty + i * 8) * KK + tk * 32 + tx] = f2b(t[tx][ty + i * 8]);
}

// ---------------------------------------------------------------- bf16 MFMA GEMM core
// 128x128 tile, 4 waves, BK=64 via TWO independent 128x32 panels per barrier pair.
// Each panel keeps the proven row-major [128][32] layout (2-way-free fragment reads).
template<int EPI, int OUTB>
__device__ __forceinline__ void gemm_core(
        const u16* __restrict__ A, const u16* __restrict__ Wt,
        float* C, u16* Cb, const float* __restrict__ X,
        int M, int N, int K, int m0, int n0) {
    __shared__ u16 As[2][128 * 32];
    __shared__ u16 Bs[2][128 * 32];
    const int tid = threadIdx.x;
    const int w = tid >> 6, l = tid & 63;
    const int wr = (w >> 1) * 64, wc = (w & 1) * 64;
    f32x4 acc[4][4];
    #pragma unroll
    for (int i = 0; i < 4; i++)
        #pragma unroll
        for (int j = 0; j < 4; j++) { f32x4 z = {0.f, 0.f, 0.f, 0.f}; acc[i][j] = z; }

    const int srow = w * 32 + (l >> 2);
    const int scol = (l & 3) * 8;
    const u16* gA = A + (long)(m0 + srow) * K + scol;
    const u16* gB = Wt + (long)(n0 + srow) * K + scol;

    for (int k0 = 0; k0 < K; k0 += 64) {
        #pragma unroll
        for (int p = 0; p < 2; p++) {
            GLOAD_LDS16(gA + k0 + p * 32,               As[p] + w * 1024);
            GLOAD_LDS16(gA + (long)16 * K + k0 + p * 32, As[p] + w * 1024 + 512);
            GLOAD_LDS16(gB + k0 + p * 32,               Bs[p] + w * 1024);
            GLOAD_LDS16(gB + (long)16 * K + k0 + p * 32, Bs[p] + w * 1024 + 512);
        }
        __syncthreads();
        #pragma unroll
        for (int p = 0; p < 2; p++) {
            bf16x8 aF[4], bF[4];
            #pragma unroll
            for (int mi = 0; mi < 4; mi++)
                aF[mi] = *(const bf16x8*)(As[p] + (wr + mi * 16 + (l & 15)) * 32 + (l >> 4) * 8);
            #pragma unroll
            for (int ni = 0; ni < 4; ni++)
                bF[ni] = *(const bf16x8*)(Bs[p] + (wc + ni * 16 + (l & 15)) * 32 + (l >> 4) * 8);
            #pragma unroll
            for (int mi = 0; mi < 4; mi++)
                #pragma unroll
                for (int ni = 0; ni < 4; ni++)
                    acc[mi][ni] = __builtin_amdgcn_mfma_f32_16x16x32_bf16(aF[mi], bF[ni], acc[mi][ni], 0, 0, 0);
        }
        __syncthreads();
    }

    #pragma unroll
    for (int mi = 0; mi < 4; mi++) {
        #pragma unroll
        for (int ni = 0; ni < 4; ni++) {
            const int col = n0 + wc + ni * 16 + (l & 15);
            #pragma unroll
            for (int r = 0; r < 4; r++) {
                const int row = m0 + wr + mi * 16 + (l >> 4) * 4 + r;
                const long idx = (long)row * N + col;
                float v = acc[mi][ni][r];
                if (EPI == 1) v += X[idx];
                if (EPI == 2) v = fmaxf(v, 0.0f);
                if (OUTB) Cb[idx] = f2b(v);
                else      C[idx]  = v;
            }
        }
    }
}

__global__ __launch_bounds__(256)
void gemm_qkv_b(const u16* __restrict__ A, const u16* wq, const u16* wk, const u16* wv,
                u16* qb, u16* kb, u16* vb, int M, int N, int K) {
    const u16* Wt = blockIdx.z == 0 ? wq : blockIdx.z == 1 ? wk : wv;
    u16* Cb       = blockIdx.z == 0 ? qb : blockIdx.z == 1 ? kb : vb;
    gemm_core<0, 1>(A, Wt, nullptr, Cb, nullptr, M, N, K, blockIdx.x * 128, blockIdx.y * 128);
}
__global__ __launch_bounds__(256)
void gemm_resid_b(const u16* __restrict__ A, const u16* __restrict__ Wt,
                  float* C, const float* __restrict__ X, int M, int N, int K) {
    gemm_core<1, 0>(A, Wt, C, nullptr, X, M, N, K, blockIdx.x * 128, blockIdx.y * 128);
}
__global__ __launch_bounds__(256)
void gemm_relu_b(const u16* __restrict__ A, const u16* __restrict__ Wt,
                 u16* Cb, int M, int N, int K) {
    gemm_core<2, 1>(A, Wt, nullptr, Cb, nullptr, M, N, K, blockIdx.x * 128, blockIdx.y * 128);
}

// ---------------------------------------------------------------- fp32 GEMM (pre-head tail)
template<int EPI>
__global__ __launch_bounds__(256)
void gemm64(const float* __restrict__ A, const float* __restrict__ W,
            float* C, const float* X, int M, int N, int K) {
    __shared__ float As[32][68];
    __shared__ float Ws[32][64];
    const int m0 = blockIdx.x * 64, n0 = blockIdx.y * 64;
    const int tid  = threadIdx.x;
    const int tr   = tid >> 4, tc = tid & 15;
    const int arow = tid >> 3, acg = tid & 7;
    const int wrow = tid >> 4, wcg = tid & 15;
    float acc[4][4] = {};
    for (int k0 = 0; k0 < K; k0 += 32) {
        float4 a0 = *(const float4*)(A + (long)(m0 + arow) * K + k0 + acg * 4);
        float4 a1 = *(const float4*)(A + (long)(m0 + arow + 32) * K + k0 + acg * 4);
        float4 w0 = *(const float4*)(W + (long)(k0 + wrow) * N + n0 + wcg * 4);
        float4 w1 = *(const float4*)(W + (long)(k0 + wrow + 16) * N + n0 + wcg * 4);
        As[acg * 4 + 0][arow] = a0.x; As[acg * 4 + 1][arow] = a0.y;
        As[acg * 4 + 2][arow] = a0.z; As[acg * 4 + 3][arow] = a0.w;
        As[acg * 4 + 0][arow + 32] = a1.x; As[acg * 4 + 1][arow + 32] = a1.y;
        As[acg * 4 + 2][arow + 32] = a1.z; As[acg * 4 + 3][arow + 32] = a1.w;
        *(float4*)&Ws[wrow][wcg * 4]      = w0;
        *(float4*)&Ws[wrow + 16][wcg * 4] = w1;
        __syncthreads();
        #pragma unroll
        for (int kk = 0; kk < 32; kk++) {
            float4 av = *(const float4*)&As[kk][tr * 4];
            float4 bv = *(const float4*)&Ws[kk][tc * 4];
            acc[0][0] += av.x * bv.x; acc[0][1] += av.x * bv.y; acc[0][2] += av.x * bv.z; acc[0][3] += av.x * bv.w;
            acc[1][0] += av.y * bv.x; acc[1][1] += av.y * bv.y; acc[1][2] += av.y * bv.z; acc[1][3] += av.y * bv.w;
            acc[2][0] += av.z * bv.x; acc[2][1] += av.z * bv.y; acc[2][2] += av.z * bv.z; acc[2][3] += av.z * bv.w;
            acc[3][0] += av.w * bv.x; acc[3][1] += av.w * bv.y; acc[3][2] += av.w * bv.z; acc[3][3] += av.w * bv.w;
        }
        __syncthreads();
    }
    #pragma unroll
    for (int i = 0; i < 4; i++) {
        int row = m0 + tr * 4 + i;
        #pragma unroll
        for (int j = 0; j < 4; j++) {
            int col = n0 + tc * 4 + j;
            long idx = (long)row * N + col;
            float v = acc[i][j];
            if (EPI == 1) v += X[idx];
            if (EPI == 3 || EPI == 4) v += X[col];
            if (EPI == 2 || EPI == 4) v = fmaxf(v, 0.0f);
            C[idx] = v;
        }
    }
}

// QKV merged fp32 (mask encoder)
__global__ __launch_bounds__(256)
void gemm64_qkv(const float* __restrict__ A,
                const float* __restrict__ WQ, const float* __restrict__ WK, const float* __restrict__ WV,
                float* q, float* k, float* v, int M, int N, int K) {
    __shared__ float As[32][68];
    __shared__ float Ws[32][64];
    const float* W = (blockIdx.z == 0) ? WQ : (blockIdx.z == 1) ? WK : WV;
    float*       C = (blockIdx.z == 0) ? q  : (blockIdx.z == 1) ? k  : v;
    const int m0 = blockIdx.x * 64, n0 = blockIdx.y * 64;
    const int tid  = threadIdx.x;
    const int tr   = tid >> 4, tc = tid & 15;
    const int arow = tid >> 3, acg = tid & 7;
    const int wrow = tid >> 4, wcg = tid & 15;
    float acc[4][4] = {};
    for (int k0 = 0; k0 < K; k0 += 32) {
        float4 a0 = *(const float4*)(A + (long)(m0 + arow) * K + k0 + acg * 4);
        float4 a1 = *(const float4*)(A + (long)(m0 + arow + 32) * K + k0 + acg * 4);
        float4 w0 = *(const float4*)(W + (long)(k0 + wrow) * N + n0 + wcg * 4);
        float4 w1 = *(const float4*)(W + (long)(k0 + wrow + 16) * N + n0 + wcg * 4);
        As[acg * 4 + 0][arow] = a0.x; As[acg * 4 + 1][arow] = a0.y;
        As[acg * 4 + 2][arow] = a0.z; As[acg * 4 + 3][arow] = a0.w;
        As[acg * 4 + 0][arow + 32] = a1.x; As[acg * 4 + 1][arow + 32] = a1.y;
        As[acg * 4 + 2][arow + 32] = a1.z; As[acg * 4 + 3][arow + 32] = a1.w;
        *(float4*)&Ws[wrow][wcg * 4]      = w0;
        *(float4*)&Ws[wrow + 16][wcg * 4] = w1;
        __syncthreads();
        #pragma unroll
        for (int kk = 0; kk < 32; kk++) {
            float4 av = *(const float4*)&As[kk][tr * 4];
            float4 bv = *(const float4*)&Ws[kk][tc * 4];
            acc[0][0] += av.x * bv.x; acc[0][1] += av.x * bv.y; acc[0][2] += av.x * bv.z; acc[0][3] += av.x * bv.w;
            acc[1][0] += av.y * bv.x; acc[1][1] += av.y * bv.y; acc[1][2] += av.y * bv.z; acc[1][3] += av.y * bv.w;
            acc[2][0] += av.z * bv.x; acc[2][1] += av.z * bv.y; acc[2][2] += av.z * bv.z; acc[2][3] += av.z * bv.w;
            acc[3][0] += av.w * bv.x; acc[3][1] += av.w * bv.y; acc[3][2] += av.w * bv.z; acc[3][3] += av.w * bv.w;
        }
        __syncthreads();
    }
    #pragma unroll
    for (int i = 0; i < 4; i++)
        #pragma unroll
        for (int j = 0; j < 4; j++)
            C[(long)(m0 + tr * 4 + i) * N + n0 + tc * 4 + j] = acc[i][j];
}

// ---------------------------------------------------------------- pre-head layer-1: MFMA split-K
__global__ __launch_bounds__(256)
void gemm_ph1(const u16* __restrict__ Ah, const u16* __restrict__ Ahm,
              const float* __restrict__ W, float* __restrict__ P, int KC) {
    constexpr int N = 1024, K = 65536;
    __shared__ u16 As[128 * 32];
    __shared__ u16 Bs[128 * 32];
    const int n0 = blockIdx.x * 128;
    const int kbeg = blockIdx.y * KC;
    const int tid = threadIdx.x;
    const int w = tid >> 6, l = tid & 63;
    const int wr = w * 32;
    const int nl = tid >> 1, seg = tid & 1;
    const u16* aptr = (nl < 64 ? Ah + (long)nl * K : Ahm + (long)(nl - 64) * K) + seg * 16;
    const float* wcol = W + n0 + nl;

    f32x4 acc[2][8];
    #pragma unroll
    for (int mi = 0; mi < 2; mi++)
        #pragma unroll
        for (int ni = 0; ni < 8; ni++) { f32x4 z = {0.f, 0.f, 0.f, 0.f}; acc[mi][ni] = z; }

    for (int ks = 0; ks < KC; ks += 32) {
        const int k0 = kbeg + ks;
        uint4 a0 = *(const uint4*)(aptr + k0);
        uint4 a1 = *(const uint4*)(aptr + k0 + 8);
        float wv[16];
        #pragma unroll
        for (int j = 0; j < 16; j++)
            wv[j] = wcol[(long)(k0 + seg * 16 + j) * N];
        __syncthreads();
        *(uint4*)(As + nl * 32 + seg * 16)     = a0;
        *(uint4*)(As + nl * 32 + seg * 16 + 8) = a1;
        u32 pk[8];
        #pragma unroll
        for (int j = 0; j < 8; j++)
            pk[j] = (u32)f2b(wv[2 * j]) | ((u32)f2b(wv[2 * j + 1]) << 16);
        *(uint4*)(Bs + nl * 32 + seg * 16)     = *(uint4*)&pk[0];
        *(uint4*)(Bs + nl * 32 + seg * 16 + 8) = *(uint4*)&pk[4];
        __syncthreads();
        bf16x8 aF0 = *(const bf16x8*)(As + (wr + (l & 15)) * 32 + (l >> 4) * 8);
        bf16x8 aF1 = *(const bf16x8*)(As + (wr + 16 + (l & 15)) * 32 + (l >> 4) * 8);
        #pragma unroll
        for (int ni = 0; ni < 8; ni++) {
            bf16x8 bF = *(const bf16x8*)(Bs + (ni * 16 + (l & 15)) * 32 + (l >> 4) * 8);
            acc[0][ni] = __builtin_amdgcn_mfma_f32_16x16x32_bf16(aF0, bF, acc[0][ni], 0, 0, 0);
            acc[1][ni] = __builtin_amdgcn_mfma_f32_16x16x32_bf16(aF1, bF, acc[1][ni], 0, 0, 0);
        }
    }
    float* Pz = P + (long)blockIdx.y * 128 * N;
    #pragma unroll
    for (int mi = 0; mi < 2; mi++)
        #pragma unroll
        for (int ni = 0; ni < 8; ni++) {
            const int col = n0 + ni * 16 + (l & 15);
            #pragma unroll
            for (int r = 0; r < 4; r++)
                Pz[(long)(wr + mi * 16 + (l >> 4) * 4 + r) * N + col] = acc[mi][ni][r];
        }
}

// ---------------------------------------------------------------- fp32 attention (mask path, colsum only)
__global__ __launch_bounds__(128)
void attn_kernel(const float* __restrict__ Q, const float* __restrict__ K,
                 const int* __restrict__ toks, float* __restrict__ colsum, int Hn) {
    __shared__ float sc[S][129];
    __shared__ float KV[S][DK];
    __shared__ int   padS[S];
    const int b = blockIdx.x / Hn;
    const int h = blockIdx.x % Hn;
    const int stride = Hn * DK;
    const int tid = threadIdx.x;

    for (int idx = tid; idx < S * DK; idx += 128) {
        int r = idx >> 6, c = idx & 63;
        KV[r][c] = K[(long)(b * S + r) * stride + h * DK + c];
    }
    padS[tid] = (toks[b * S + tid] == 0) ? 1 : 0;
    float qreg[DK];
    {
        const float* qp = Q + (long)(b * S + tid) * stride + h * DK;
        #pragma unroll
        for (int i = 0; i < 16; i++) {
            float4 t4 = *(const float4*)(qp + i * 4);
            qreg[i * 4 + 0] = t4.x; qreg[i * 4 + 1] = t4.y;
            qreg[i * 4 + 2] = t4.z; qreg[i * 4 + 3] = t4.w;
        }
    }
    __syncthreads();
    for (int k = 0; k < S; k++) {
        float s = 0.0f;
        #pragma unroll
        for (int d4 = 0; d4 < 16; d4++) {
            float4 kv = *(const float4*)&KV[k][d4 * 4];
            s += qreg[d4 * 4 + 0] * kv.x + qreg[d4 * 4 + 1] * kv.y
               + qreg[d4 * 4 + 2] * kv.z + qreg[d4 * 4 + 3] * kv.w;
        }
        sc[tid][k] = padS[k] ? -1e9f : (s * 0.125f);
    }
    float mx = -INFINITY;
    for (int k = 0; k < S; k++) mx = fmaxf(mx, sc[tid][k]);
    float sum = 0.0f;
    for (int k = 0; k < S; k++) { float e = expf(sc[tid][k] - mx); sc[tid][k] = e; sum += e; }
    for (int k = 0; k < S; k++) sc[tid][k] = sc[tid][k] / sum;
    __syncthreads();
    {
        double a = 0.0;
        for (int q2 = 0; q2 < S; q2++) a += (double)sc[q2][tid];
        colsum[(long)(b * Hn + h) * S + tid] = (float)a;
    }
}

// ---------------------------------------------------------------- MFMA attention (batched passes)
__global__ __launch_bounds__(256)
void attn_mfma_kernel(u16* qb, const u16* __restrict__ kb, const u16* __restrict__ vb,
                      const int* __restrict__ toks, const int* __restrict__ mtok,
                      float* __restrict__ colsum) {
    __shared__ u16 pool[18432];          // Qs[128][72] | Ks[128][72] ; Ps[128][136] aliases
    __shared__ u16 Vt[64 * 136];
    __shared__ float colsLds[4][128];
    __shared__ u32 padF[128];
    u16* Qs = pool;
    u16* Ks = pool + 9216;
    u16* Ps = pool;

    const int gb = blockIdx.x >> 3, h = blockIdx.x & 7;
    const int tid = threadIdx.x;
    const int w = tid >> 6, l = tid & 63;
    const long base = (long)gb * S * D + h * 64;
    const int* tsrc = (gb < B) ? (toks + (long)gb * S) : (mtok + (long)(gb - B) * S);

    for (int j = tid; j < 1024; j += 256) {
        int r = j >> 3, c = j & 7;
        uint4 uq = *(const uint4*)(qb + base + (long)r * D + c * 8);
        uint4 uk = *(const uint4*)(kb + base + (long)r * D + c * 8);
        uint4 uv = *(const uint4*)(vb + base + (long)r * D + c * 8);
        *(uint4*)(Qs + r * 72 + c * 8) = uq;
        *(uint4*)(Ks + r * 72 + c * 8) = uk;
        u16 vv[8]; *(uint4*)vv = uv;
        #pragma unroll
        for (int t = 0; t < 8; t++) Vt[(c * 8 + t) * 136 + r] = vv[t];
    }
    if (tid < 128) padF[tid] = (tsrc[tid] == 0) ? 1u : 0u;
    __syncthreads();

    const int rowB = w * 32;
    f32x4 acc[2][8];
    #pragma unroll
    for (int mi = 0; mi < 2; mi++)
        #pragma unroll
        for (int ni = 0; ni < 8; ni++) { f32x4 z = {0.f, 0.f, 0.f, 0.f}; acc[mi][ni] = z; }
    #pragma unroll
    for (int ks = 0; ks < 2; ks++) {
        bf16x8 a0 = *(const bf16x8*)(Qs + (rowB + (l & 15)) * 72 + ks * 32 + (l >> 4) * 8);
        bf16x8 a1 = *(const bf16x8*)(Qs + (rowB + 16 + (l & 15)) * 72 + ks * 32 + (l >> 4) * 8);
        #pragma unroll
        for (int ni = 0; ni < 8; ni++) {
            bf16x8 bv = *(const bf16x8*)(Ks + (ni * 16 + (l & 15)) * 72 + ks * 32 + (l >> 4) * 8);
            acc[0][ni] = __builtin_amdgcn_mfma_f32_16x16x32_bf16(a0, bv, acc[0][ni], 0, 0, 0);
            acc[1][ni] = __builtin_amdgcn_mfma_f32_16x16x32_bf16(a1, bv, acc[1][ni], 0, 0, 0);
        }
    }
    float pf[8];
    #pragma unroll
    for (int ni = 0; ni < 8; ni++) pf[ni] = padF[ni * 16 + (l & 15)] ? 1.0f : 0.0f;
    #pragma unroll
    for (int mi = 0; mi < 2; mi++)
        #pragma unroll
        for (int ni = 0; ni < 8; ni++)
            #pragma unroll
            for (int r = 0; r < 4; r++) {
                float v = acc[mi][ni][r] * 0.125f;
                acc[mi][ni][r] = (pf[ni] != 0.0f) ? -1e9f : v;
            }
    #pragma unroll
    for (int mi = 0; mi < 2; mi++)
        #pragma unroll
        for (int r = 0; r < 4; r++) {
            float m = -INFINITY;
            #pragma unroll
            for (int ni = 0; ni < 8; ni++) m = fmaxf(m, acc[mi][ni][r]);
            m = fmaxf(m, __shfl_xor(m, 1)); m = fmaxf(m, __shfl_xor(m, 2));
            m = fmaxf(m, __shfl_xor(m, 4)); m = fmaxf(m, __shfl_xor(m, 8));
            float s = 0.0f;
            #pragma unroll
            for (int ni = 0; ni < 8; ni++) { float e = expf(acc[mi][ni][r] - m); acc[mi][ni][r] = e; s += e; }
            s += __shfl_xor(s, 1); s += __shfl_xor(s, 2);
            s += __shfl_xor(s, 4); s += __shfl_xor(s, 8);
            float inv = 1.0f / s;
            #pragma unroll
            for (int ni = 0; ni < 8; ni++) acc[mi][ni][r] *= inv;
        }
    float cs[8];
    #pragma unroll
    for (int ni = 0; ni < 8; ni++) {
        float s = 0.0f;
        #pragma unroll
        for (int mi = 0; mi < 2; mi++)
            #pragma unroll
            for (int r = 0; r < 4; r++) s += acc[mi][ni][r];
        s += __shfl_xor(s, 16); s += __shfl_xor(s, 32);
        cs[ni] = s;
    }
    __syncthreads();
    if (l < 16)
        #pragma unroll
        for (int ni = 0; ni < 8; ni++) colsLds[w][ni * 16 + l] = cs[ni];
    #pragma unroll
    for (int mi = 0; mi < 2; mi++)
        #pragma unroll
        for (int ni = 0; ni < 8; ni++)
            #pragma unroll
            for (int r = 0; r < 4; r++)
                Ps[(rowB + mi * 16 + (l >> 4) * 4 + r) * 136 + ni * 16 + (l & 15)] =
                    f2b(acc[mi][ni][r]);
    __syncthreads();
    if (tid < 128) {
        float s = colsLds[0][tid] + colsLds[1][tid] + colsLds[2][tid] + colsLds[3][tid];
        colsum[((long)gb * H + h) * S + tid] = s;
    }
    f32x4 o[2][4];
    #pragma unroll
    for (int mi = 0; mi < 2; mi++)
        #pragma unroll
        for (int n = 0; n < 4; n++) { f32x4 z = {0.f, 0.f, 0.f, 0.f}; o[mi][n] = z; }
    #pragma unroll
    for (int ks = 0; ks < 4; ks++) {
        bf16x8 p0 = *(const bf16x8*)(Ps + (rowB + (l & 15)) * 136 + ks * 32 + (l >> 4) * 8);
        bf16x8 p1 = *(const bf16x8*)(Ps + (rowB + 16 + (l & 15)) * 136 + ks * 32 + (l >> 4) * 8);
        #pragma unroll
        for (int n = 0; n < 4; n++) {
            bf16x8 bv = *(const bf16x8*)(Vt + (n * 16 + (l & 15)) * 136 + ks * 32 + (l >> 4) * 8);
            o[0][n] = __builtin_amdgcn_mfma_f32_16x16x32_bf16(p0, bv, o[0][n], 0, 0, 0);
            o[1][n] = __builtin_amdgcn_mfma_f32_16x16x32_bf16(p1, bv, o[1][n], 0, 0, 0);
        }
    }
    #pragma unroll
    for (int mi = 0; mi < 2; mi++)
        #pragma unroll
        for (int n = 0; n < 4; n++) {
            const int col = n * 16 + (l & 15);
            #pragma unroll
            for (int r = 0; r < 4; r++) {
                const int row = rowB + mi * 16 + (l >> 4) * 4 + r;
                qb[base + (long)row * D + col] = f2b(o[mi][n][r]);
            }
        }
}

// ---------------------------------------------------------------- creat_mask
__global__ __launch_bounds__(128)
void creat_mask_kernel(const float* __restrict__ colpart, const int* __restrict__ toks,
                       int* __restrict__ mtok, float* __restrict__ out) {
    __shared__ float colS[S];
    __shared__ int   j0s, kks;
    const int b = blockIdx.x, j = threadIdx.x;
    float c = colpart[(long)(b * AH + 0) * S + j] + colpart[(long)(b * AH + 1) * S + j];
    colS[j] = c;
    int tk = toks[b * S + j];
    __syncthreads();
    if (j == 0) {
        int j0 = S;
        for (int i = 0; i < S; i++) if (colS[i] == 0.0f) { j0 = i; break; }
        int kk = (j0 < S) ? (int)ceilf(0.2f * (float)j0) : 0;
        j0s = j0; kks = kk;
    }
    __syncthreads();
    const int j0 = j0s, kk = kks;
    float vj = (j < j0) ? colS[j] : INFINITY;
    int rank = 0;
    for (int i = 0; i < S; i++) {
        float vi = (i < j0) ? colS[i] : INFINITY;
        if (vi < vj || (vi == vj && i < j)) rank++;
    }
    int mt = (rank >= kk) ? tk : 0;
    mtok[b * S + j] = mt;
    out[OUT_TOK + b * S + j]  = (float)tk;
    out[OUT_MTOK + b * S + j] = (float)mt;
}

// ---------------------------------------------------------------- LayerNorm (in place) + bf16 copy-out
__global__ __launch_bounds__(256)
void ln_kernel(float* __restrict__ x, u16* __restrict__ xb) {
    const int row  = blockIdx.x * 4 + (threadIdx.x >> 6);
    const int lane = threadIdx.x & 63;
    float* r = x + (long)row * D;
    float4 v0 = *(const float4*)(r + lane * 4);
    float4 v1 = *(const float4*)(r + 256 + lane * 4);
    float s = v0.x + v0.y + v0.z + v0.w + v1.x + v1.y + v1.z + v1.w;
    #pragma unroll
    for (int off = 32; off; off >>= 1) s += __shfl_xor(s, off);
    float m = s * (1.0f / 512.0f);
    float d0 = v0.x - m, d1 = v0.y - m, d2 = v0.z - m, d3 = v0.w - m;
    float d4 = v1.x - m, d5 = v1.y - m, d6 = v1.z - m, d7 = v1.w - m;
    float q = d0*d0 + d1*d1 + d2*d2 + d3*d3 + d4*d4 + d5*d5 + d6*d6 + d7*d7;
    #pragma unroll
    for (int off = 32; off; off >>= 1) q += __shfl_xor(q, off);
    float inv = 1.0f / sqrtf(q * (1.0f / 512.0f) + 1e-5f);
    float4 o0, o1;
    o0.x = d0 * inv; o0.y = d1 * inv; o0.z = d2 * inv; o0.w = d3 * inv;
    o1.x = d4 * inv; o1.y = d5 * inv; o1.z = d6 * inv; o1.w = d7 * inv;
    *(float4*)(r + lane * 4)       = o0;
    *(float4*)(r + 256 + lane * 4) = o1;
    u16* rb = xb + (long)row * D;
    u16 p0[4] = {f2b(o0.x), f2b(o0.y), f2b(o0.z), f2b(o0.w)};
    u16 p1[4] = {f2b(o1.x), f2b(o1.y), f2b(o1.z), f2b(o1.w)};
    *(uint2*)(rb + lane * 4)       = *(uint2*)p0;
    *(uint2*)(rb + 256 + lane * 4) = *(uint2*)p1;
}

// ---------------------------------------------------------------- scores output (pass-0 half)
__global__ void score_reduce_kernel(const float* __restrict__ ascorep, float* __restrict__ dst) {
    int idx = blockIdx.x * 256 + threadIdx.x;
    if (idx >= B * S) return;
    int b = idx >> 7, j = idx & 127;
    float s = 0.0f;
    for (int h = 0; h < H; h++) s += ascorep[(long)(b * H + h) * S + j];
    dst[idx] = s;
}

// ---------------------------------------------------------------- pre-head reduce/pack
__global__ void reduce1_kernel(const float* __restrict__ parts, const float* __restrict__ b1,
                               float* __restrict__ o) {
    int idx = blockIdx.x * 256 + threadIdx.x;
    if (idx >= 128 * 1024) return;
    float s = 0.0f;
    for (int z = 0; z < 64; z++) s += parts[(long)z * 128 * 1024 + idx];
    s += b1[idx & 1023];
    o[idx] = fmaxf(s, 0.0f);
}

__global__ void pack_out_kernel(const float* __restrict__ ph3, float* __restrict__ out) {
    int idx = blockIdx.x * 256 + threadIdx.x;
    if (idx >= 128 * 128) return;
    int row = idx >> 7, col = idx & 127;
    long base = (row < 64) ? (OUT_OUT1 + (long)row * 128) : (OUT_OUTM + (long)(row - 64) * 128);
    out[base + col] = ph3[idx];
}

// ================================================================ launch
extern "C" void kernel_launch(void* const* d_in, const int* in_sizes, int n_in,
                              void* d_out, int out_size, void* d_ws, size_t ws_size,
                              hipStream_t stream) {
    const int*   toks = (const int*)d_in[0];
    const float* emb  = (const float*)d_in[1];
    const float* aWQ  = (const float*)d_in[2];
    const float* aWK  = (const float*)d_in[3];
    const float* tWQ  = (const float*)d_in[8];
    const float* tWK  = (const float*)d_in[9];
    const float* tWV  = (const float*)d_in[10];
    const float* tFC  = (const float*)d_in[11];
    const float* tF1  = (const float*)d_in[12];
    const float* tF2  = (const float*)d_in[13];
    const float* pW1  = (const float*)d_in[14];
    const float* pb1  = (const float*)d_in[15];
    const float* pW2  = (const float*)d_in[16];
    const float* pb2  = (const float*)d_in[17];
    const float* pW3  = (const float*)d_in[18];
    const float* pb3  = (const float*)d_in[19];
    float* out = (float*)d_out;

    float* ws   = (float*)d_ws;
    float* pe   = ws + OFF_PE;
    float* ascp = ws + OFF_ASC;
    float* colp = ws + OFF_COLP;
    int*   mtok = (int*)(ws + OFF_MTOK);
    float* x    = ws + OFF_X;          // [BS2][D] fp32 (h ‖ hm)
    u16*   xb   = (u16*)(ws + OFF_XB); // [BS2][D] bf16
    u16*   qb   = (u16*)(ws + OFF_QB);
    u16*   kb   = (u16*)(ws + OFF_KB);
    u16*   vb   = (u16*)(ws + OFF_VB);
    u16*   tb   = (u16*)(ws + OFF_TB); // [BS2][DFF] bf16
    u16*   wAll = (u16*)(ws + OFF_W);

    // phase-disjoint aliases of the TB region
    float* maq   = ws + OFF_TB;                 // mask encoder q [BS][128] fp32
    float* mak   = maq + (long)BS * 128;
    float* parts = ws + OFF_TB;                 // pre-head partials 64 x [128][1024]
    float* ph1o  = parts + 8388608;
    float* ph2o  = ph1o + 131072;
    float* ph3o  = ph2o + 65536;

    // --- setup: pos-enc, all-layer weight conversion, clean embedding
    pe_kernel<<<128, 256, 0, stream>>>(pe);
    wconv_all<<<6 * 3072, 256, 0, stream>>>(tWQ, tWK, tWV, tFC, tF1, tF2, wAll);
    embed_dual<<<2048, 256, 0, stream>>>(toks, emb, pe, x, xb);

    // --- mask-generating encoder (fp32; only the attention matrix is consumed)
    gemm64_qkv<<<dim3(BS / 64, 2, 2), 256, 0, stream>>>(
        x, aWQ, aWK, nullptr, maq, mak, nullptr, BS, AH * DK, D);
    attn_kernel<<<B * AH, 128, 0, stream>>>(maq, mak, toks, colp, AH);
    creat_mask_kernel<<<B, 128, 0, stream>>>(colp, toks, mtok, out);
    embed_dual<<<2048, 256, 0, stream>>>(mtok, emb, pe, x + (long)BS * D, xb + (long)BS * D);

    // --- 6 layers, both passes batched (rows 0..8191 = clean, 8192..16383 = masked)
    for (int l = 0; l < L; l++) {
        const u16* wq = wAll + (long)l * WSTRIDE;
        const u16* wk = wq + 262144;
        const u16* wv = wq + 524288;
        const u16* wo = wq + 786432;
        const u16* w1 = wq + 1048576;
        const u16* w2 = wq + 2097152;
        gemm_qkv_b<<<dim3(BS2 / 128, D / 128, 3), 256, 0, stream>>>(
            xb, wq, wk, wv, qb, kb, vb, BS2, D, D);
        attn_mfma_kernel<<<2 * B * H, 256, 0, stream>>>(qb, kb, vb, toks, mtok, ascp);
        score_reduce_kernel<<<32, 256, 0, stream>>>(ascp, out + OUT_SCORES + (long)l * BS);
        gemm_resid_b<<<dim3(BS2 / 128, D / 128), 256, 0, stream>>>(qb, wo, x, x, BS2, D, D);
        ln_kernel<<<BS2 / 4, 256, 0, stream>>>(x, xb);
        gemm_relu_b<<<dim3(BS2 / 128, DFF / 128), 256, 0, stream>>>(xb, w1, tb, BS2, DFF, D);
        gemm_resid_b<<<dim3(BS2 / 128, D / 128), 256, 0, stream>>>(tb, w2, x, x, BS2, D, DFF);
        ln_kernel<<<BS2 / 4, 256, 0, stream>>>(x, xb);
    }

    // --- pre_head: MFMA split-K over pW1 (xb already holds bf16 h ‖ hm)
    gemm_ph1<<<dim3(8, 64), 256, 0, stream>>>(xb, xb + (long)BS * D, pW1, parts, 1024);
    reduce1_kernel<<<512, 256, 0, stream>>>(parts, pb1, ph1o);
    gemm64<4><<<dim3(2, 8), 256, 0, stream>>>(ph1o, pW2, ph2o, pb2, 128, 512, 1024);
    gemm64<3><<<dim3(2, 2), 256, 0, stream>>>(ph2o, pW3, ph3o, pb3, 128, 128, 512);
    pack_out_kernel<<<64, 256, 0, stream>>>(ph3o, out);
}

// Round 11
// 1496.629 us; speedup vs baseline: 1.2090x; 1.0700x over previous
//
#include <hip/hip_runtime.h>
#include <hip/hip_bf16.h>
#include <math.h>

using u16 = unsigned short;
using u32 = unsigned int;

// Problem constants
constexpr int B   = 64;
constexpr int S   = 128;
constexpr int D   = 512;
constexpr int H   = 8;
constexpr int DK  = 64;
constexpr int L   = 6;
constexpr int DFF = 2048;
constexpr int AH  = 2;
constexpr int BS  = B * S;          // 8192
constexpr int BS2 = 2 * BS;         // 16384 (both passes batched)

// Output layout (fp32 elements)
constexpr long OUT_TOK    = 0;
constexpr long OUT_OUT1   = 8192;
constexpr long OUT_MTOK   = 16384;
constexpr long OUT_OUTM   = 24576;
constexpr long OUT_SCORES = 32768;

// Workspace layout (float units). ~206 MB of ~1 GiB ws
constexpr long OFF_PE   = 0;            // 65536
constexpr long OFF_ASC  = 65536;        // 2*B*H*S = 131072
constexpr long OFF_COLP = 196608;       // B*AH*S = 16384
constexpr long OFF_MTOK = 212992;       // 8192 ints
constexpr long OFF_X    = 221184;       // BS2*D fp32 = 8,388,608 (clean-emb fp32 / pre-LN scratch y)
constexpr long OFF_XB   = 8609792;      // BS2*D bf16 = 4,194,304 fl (canonical residual state)
constexpr long OFF_QB   = 12804096;     // BS2*D bf16
constexpr long OFF_KB   = 16998400;     // BS2*D bf16
constexpr long OFF_VB   = 21192704;     // BS2*D bf16
constexpr long OFF_TB   = 25387008;     // BS2*DFF bf16 = 16,777,216 fl (alias: mask q/k, pre-head parts)
constexpr long OFF_W    = 42164224;     // 6 layers x 3,145,728 bf16 = 9,437,184 fl
constexpr long WSTRIDE  = 3145728;      // bf16 elems per layer

typedef __attribute__((ext_vector_type(8))) short bf16x8;
typedef __attribute__((ext_vector_type(4))) float f32x4;

__device__ __forceinline__ float b2f(u16 u) {
    union { u32 i; float f; } v; v.i = ((u32)u) << 16; return v.f;
}
__device__ __forceinline__ u16 f2b(float f) {      // RNE f32 -> bf16
    union { float f; u32 i; } v; v.f = f;
    u32 r = v.i + 0x7fffu + ((v.i >> 16) & 1u);
    return (u16)(r >> 16);
}

#define GLOAD_LDS16(g, l) __builtin_amdgcn_global_load_lds(                        \
    (const __attribute__((address_space(1))) u32*)(const void*)(g),               \
    (__attribute__((address_space(3))) u32*)(void*)(l), 16, 0, 0)

// ---------------------------------------------------------------- pos enc
__global__ void pe_kernel(float* __restrict__ pe) {
    int idx = blockIdx.x * 256 + threadIdx.x;
    if (idx >= S * (D / 2)) return;
    int s = idx >> 8;
    int i = idx & 255;
    const float CPE = (float)(-9.210340371976184 / 512.0);
    float div = expf((float)(2 * i) * CPE);
    float ang = (float)s * div;
    pe[(long)s * D + 2 * i]     = sinf(ang);
    pe[(long)s * D + 2 * i + 1] = cosf(ang);
}

// ---------------------------------------------------------------- embed + pe (fp32 + bf16 out)
__global__ void embed_dual(const int* __restrict__ toks, const float* __restrict__ emb,
                           const float* __restrict__ pe, float* __restrict__ x,
                           u16* __restrict__ xb) {
    int i8 = blockIdx.x * 256 + threadIdx.x;      // over BS*D/8 = 524288
    if (i8 >= BS * D / 8) return;
    int row = i8 >> 6;
    int c8  = i8 & 63;
    int s   = row & (S - 1);
    int t   = toks[row];
    float4 e0 = *(const float4*)(emb + (long)t * D + c8 * 8);
    float4 e1 = *(const float4*)(emb + (long)t * D + c8 * 8 + 4);
    float4 p0 = *(const float4*)(pe + (long)s * D + c8 * 8);
    float4 p1 = *(const float4*)(pe + (long)s * D + c8 * 8 + 4);
    float4 o0, o1;
    o0.x = e0.x + p0.x; o0.y = e0.y + p0.y; o0.z = e0.z + p0.z; o0.w = e0.w + p0.w;
    o1.x = e1.x + p1.x; o1.y = e1.y + p1.y; o1.z = e1.z + p1.z; o1.w = e1.w + p1.w;
    *(float4*)(x + (long)i8 * 8)     = o0;
    *(float4*)(x + (long)i8 * 8 + 4) = o1;
    u16 u[8] = {f2b(o0.x), f2b(o0.y), f2b(o0.z), f2b(o0.w), f2b(o1.x), f2b(o1.y), f2b(o1.z), f2b(o1.w)};
    *(uint4*)(xb + (long)i8 * 8) = *(uint4*)u;
}

// ---------------------------------------------------------------- all-layer weight transpose+convert
__global__ __launch_bounds__(256)
void wconv_all(const float* __restrict__ tWQ, const float* __restrict__ tWK,
               const float* __restrict__ tWV, const float* __restrict__ tFC,
               const float* __restrict__ tF1, const float* __restrict__ tF2,
               u16* __restrict__ wAll) {
    __shared__ float t[32][33];
    const int lyr = blockIdx.x / 3072;
    const int bid = blockIdx.x % 3072;
    u16* base = wAll + (long)lyr * WSTRIDE;
    const float* src; u16* dst; int KK, NN, tk, tn;
    if (bid < 1024) {
        int which = bid >> 8, tt = bid & 255;
        src = (which == 0 ? tWQ : which == 1 ? tWK : which == 2 ? tWV : tFC) + (long)lyr * D * D;
        dst = base + (long)which * 262144;
        KK = 512; NN = 512; tk = tt >> 4; tn = tt & 15;
    } else if (bid < 2048) {
        int tt = bid - 1024;
        src = tF1 + (long)lyr * D * DFF; dst = base + 1048576;
        KK = 512; NN = 2048; tk = tt >> 6; tn = tt & 63;
    } else {
        int tt = bid - 2048;
        src = tF2 + (long)lyr * DFF * D; dst = base + 2097152;
        KK = 2048; NN = 512; tk = tt >> 4; tn = tt & 15;
    }
    int ty = threadIdx.x >> 5, tx = threadIdx.x & 31;
    #pragma unroll
    for (int i = 0; i < 4; i++)
        t[ty + i * 8][tx] = src[(long)(tk * 32 + ty + i * 8) * NN + tn * 32 + tx];
    __syncthreads();
    #pragma unroll
    for (int i = 0; i < 4; i++)
        dst[(long)(tn * 32 + ty + i * 8) * KK + tk * 32 + tx] = f2b(t[tx][ty + i * 8]);
}

// ---------------------------------------------------------------- bf16 MFMA GEMM core
// 128x128 tile, 4 waves, BK=64 via TWO independent 128x32 panels per barrier pair.
// EPI: 0 none, 2 relu, 3 +bf16 residual X[M,N]. OUTB: bf16 output.
template<int EPI, int OUTB>
__device__ __forceinline__ void gemm_core(
        const u16* __restrict__ A, const u16* __restrict__ Wt,
        float* C, u16* Cb, const void* __restrict__ X,
        int M, int N, int K, int m0, int n0) {
    __shared__ u16 As[2][128 * 32];
    __shared__ u16 Bs[2][128 * 32];
    const int tid = threadIdx.x;
    const int w = tid >> 6, l = tid & 63;
    const int wr = (w >> 1) * 64, wc = (w & 1) * 64;
    f32x4 acc[4][4];
    #pragma unroll
    for (int i = 0; i < 4; i++)
        #pragma unroll
        for (int j = 0; j < 4; j++) { f32x4 z = {0.f, 0.f, 0.f, 0.f}; acc[i][j] = z; }

    const int srow = w * 32 + (l >> 2);
    const int scol = (l & 3) * 8;
    const u16* gA = A + (long)(m0 + srow) * K + scol;
    const u16* gB = Wt + (long)(n0 + srow) * K + scol;

    for (int k0 = 0; k0 < K; k0 += 64) {
        #pragma unroll
        for (int p = 0; p < 2; p++) {
            GLOAD_LDS16(gA + k0 + p * 32,               As[p] + w * 1024);
            GLOAD_LDS16(gA + (long)16 * K + k0 + p * 32, As[p] + w * 1024 + 512);
            GLOAD_LDS16(gB + k0 + p * 32,               Bs[p] + w * 1024);
            GLOAD_LDS16(gB + (long)16 * K + k0 + p * 32, Bs[p] + w * 1024 + 512);
        }
        __syncthreads();
        #pragma unroll
        for (int p = 0; p < 2; p++) {
            bf16x8 aF[4], bF[4];
            #pragma unroll
            for (int mi = 0; mi < 4; mi++)
                aF[mi] = *(const bf16x8*)(As[p] + (wr + mi * 16 + (l & 15)) * 32 + (l >> 4) * 8);
            #pragma unroll
            for (int ni = 0; ni < 4; ni++)
                bF[ni] = *(const bf16x8*)(Bs[p] + (wc + ni * 16 + (l & 15)) * 32 + (l >> 4) * 8);
            #pragma unroll
            for (int mi = 0; mi < 4; mi++)
                #pragma unroll
                for (int ni = 0; ni < 4; ni++)
                    acc[mi][ni] = __builtin_amdgcn_mfma_f32_16x16x32_bf16(aF[mi], bF[ni], acc[mi][ni], 0, 0, 0);
        }
        __syncthreads();
    }

    #pragma unroll
    for (int mi = 0; mi < 4; mi++) {
        #pragma unroll
        for (int ni = 0; ni < 4; ni++) {
            const int col = n0 + wc + ni * 16 + (l & 15);
            #pragma unroll
            for (int r = 0; r < 4; r++) {
                const int row = m0 + wr + mi * 16 + (l >> 4) * 4 + r;
                const long idx = (long)row * N + col;
                float v = acc[mi][ni][r];
                if (EPI == 3) v += b2f(((const u16*)X)[idx]);
                if (EPI == 2) v = fmaxf(v, 0.0f);
                if (OUTB) Cb[idx] = f2b(v);
                else      C[idx]  = v;
            }
        }
    }
}

__global__ __launch_bounds__(256)
void gemm_qkv_b(const u16* __restrict__ A, const u16* wq, const u16* wk, const u16* wv,
                u16* qb, u16* kb, u16* vb, int M, int N, int K) {
    const u16* Wt = blockIdx.z == 0 ? wq : blockIdx.z == 1 ? wk : wv;
    u16* Cb       = blockIdx.z == 0 ? qb : blockIdx.z == 1 ? kb : vb;
    gemm_core<0, 1>(A, Wt, nullptr, Cb, nullptr, M, N, K, blockIdx.x * 128, blockIdx.y * 128);
}
__global__ __launch_bounds__(256)
void gemm_resid_b(const u16* __restrict__ A, const u16* __restrict__ Wt,
                  float* C, const u16* __restrict__ X, int M, int N, int K) {
    gemm_core<3, 0>(A, Wt, C, nullptr, X, M, N, K, blockIdx.x * 128, blockIdx.y * 128);
}
__global__ __launch_bounds__(256)
void gemm_relu_b(const u16* __restrict__ A, const u16* __restrict__ Wt,
                 u16* Cb, int M, int N, int K) {
    gemm_core<2, 1>(A, Wt, nullptr, Cb, nullptr, M, N, K, blockIdx.x * 128, blockIdx.y * 128);
}

// ---------------------------------------------------------------- fp32 GEMM (pre-head tail)
template<int EPI>
__global__ __launch_bounds__(256)
void gemm64(const float* __restrict__ A, const float* __restrict__ W,
            float* C, const float* X, int M, int N, int K) {
    __shared__ float As[32][68];
    __shared__ float Ws[32][64];
    const int m0 = blockIdx.x * 64, n0 = blockIdx.y * 64;
    const int tid  = threadIdx.x;
    const int tr   = tid >> 4, tc = tid & 15;
    const int arow = tid >> 3, acg = tid & 7;
    const int wrow = tid >> 4, wcg = tid & 15;
    float acc[4][4] = {};
    for (int k0 = 0; k0 < K; k0 += 32) {
        float4 a0 = *(const float4*)(A + (long)(m0 + arow) * K + k0 + acg * 4);
        float4 a1 = *(const float4*)(A + (long)(m0 + arow + 32) * K + k0 + acg * 4);
        float4 w0 = *(const float4*)(W + (long)(k0 + wrow) * N + n0 + wcg * 4);
        float4 w1 = *(const float4*)(W + (long)(k0 + wrow + 16) * N + n0 + wcg * 4);
        As[acg * 4 + 0][arow] = a0.x; As[acg * 4 + 1][arow] = a0.y;
        As[acg * 4 + 2][arow] = a0.z; As[acg * 4 + 3][arow] = a0.w;
        As[acg * 4 + 0][arow + 32] = a1.x; As[acg * 4 + 1][arow + 32] = a1.y;
        As[acg * 4 + 2][arow + 32] = a1.z; As[acg * 4 + 3][arow + 32] = a1.w;
        *(float4*)&Ws[wrow][wcg * 4]      = w0;
        *(float4*)&Ws[wrow + 16][wcg * 4] = w1;
        __syncthreads();
        #pragma unroll
        for (int kk = 0; kk < 32; kk++) {
            float4 av = *(const float4*)&As[kk][tr * 4];
            float4 bv = *(const float4*)&Ws[kk][tc * 4];
            acc[0][0] += av.x * bv.x; acc[0][1] += av.x * bv.y; acc[0][2] += av.x * bv.z; acc[0][3] += av.x * bv.w;
            acc[1][0] += av.y * bv.x; acc[1][1] += av.y * bv.y; acc[1][2] += av.y * bv.z; acc[1][3] += av.y * bv.w;
            acc[2][0] += av.z * bv.x; acc[2][1] += av.z * bv.y; acc[2][2] += av.z * bv.z; acc[2][3] += av.z * bv.w;
            acc[3][0] += av.w * bv.x; acc[3][1] += av.w * bv.y; acc[3][2] += av.w * bv.z; acc[3][3] += av.w * bv.w;
        }
        __syncthreads();
    }
    #pragma unroll
    for (int i = 0; i < 4; i++) {
        int row = m0 + tr * 4 + i;
        #pragma unroll
        for (int j = 0; j < 4; j++) {
            int col = n0 + tc * 4 + j;
            long idx = (long)row * N + col;
            float v = acc[i][j];
            if (EPI == 1) v += X[idx];
            if (EPI == 3 || EPI == 4) v += X[col];
            if (EPI == 2 || EPI == 4) v = fmaxf(v, 0.0f);
            C[idx] = v;
        }
    }
}

// QKV merged fp32 (mask encoder)
__global__ __launch_bounds__(256)
void gemm64_qkv(const float* __restrict__ A,
                const float* __restrict__ WQ, const float* __restrict__ WK, const float* __restrict__ WV,
                float* q, float* k, float* v, int M, int N, int K) {
    __shared__ float As[32][68];
    __shared__ float Ws[32][64];
    const float* W = (blockIdx.z == 0) ? WQ : (blockIdx.z == 1) ? WK : WV;
    float*       C = (blockIdx.z == 0) ? q  : (blockIdx.z == 1) ? k  : v;
    const int m0 = blockIdx.x * 64, n0 = blockIdx.y * 64;
    const int tid  = threadIdx.x;
    const int tr   = tid >> 4, tc = tid & 15;
    const int arow = tid >> 3, acg = tid & 7;
    const int wrow = tid >> 4, wcg = tid & 15;
    float acc[4][4] = {};
    for (int k0 = 0; k0 < K; k0 += 32) {
        float4 a0 = *(const float4*)(A + (long)(m0 + arow) * K + k0 + acg * 4);
        float4 a1 = *(const float4*)(A + (long)(m0 + arow + 32) * K + k0 + acg * 4);
        float4 w0 = *(const float4*)(W + (long)(k0 + wrow) * N + n0 + wcg * 4);
        float4 w1 = *(const float4*)(W + (long)(k0 + wrow + 16) * N + n0 + wcg * 4);
        As[acg * 4 + 0][arow] = a0.x; As[acg * 4 + 1][arow] = a0.y;
        As[acg * 4 + 2][arow] = a0.z; As[acg * 4 + 3][arow] = a0.w;
        As[acg * 4 + 0][arow + 32] = a1.x; As[acg * 4 + 1][arow + 32] = a1.y;
        As[acg * 4 + 2][arow + 32] = a1.z; As[acg * 4 + 3][arow + 32] = a1.w;
        *(float4*)&Ws[wrow][wcg * 4]      = w0;
        *(float4*)&Ws[wrow + 16][wcg * 4] = w1;
        __syncthreads();
        #pragma unroll
        for (int kk = 0; kk < 32; kk++) {
            float4 av = *(const float4*)&As[kk][tr * 4];
            float4 bv = *(const float4*)&Ws[kk][tc * 4];
            acc[0][0] += av.x * bv.x; acc[0][1] += av.x * bv.y; acc[0][2] += av.x * bv.z; acc[0][3] += av.x * bv.w;
            acc[1][0] += av.y * bv.x; acc[1][1] += av.y * bv.y; acc[1][2] += av.y * bv.z; acc[1][3] += av.y * bv.w;
            acc[2][0] += av.z * bv.x; acc[2][1] += av.z * bv.y; acc[2][2] += av.z * bv.z; acc[2][3] += av.z * bv.w;
            acc[3][0] += av.w * bv.x; acc[3][1] += av.w * bv.y; acc[3][2] += av.w * bv.z; acc[3][3] += av.w * bv.w;
        }
        __syncthreads();
    }
    #pragma unroll
    for (int i = 0; i < 4; i++)
        #pragma unroll
        for (int j = 0; j < 4; j++)
            C[(long)(m0 + tr * 4 + i) * N + n0 + tc * 4 + j] = acc[i][j];
}

// ---------------------------------------------------------------- pre-head layer-1: MFMA split-K
__global__ __launch_bounds__(256)
void gemm_ph1(const u16* __restrict__ Ah, const u16* __restrict__ Ahm,
              const float* __restrict__ W, float* __restrict__ P, int KC) {
    constexpr int N = 1024, K = 65536;
    __shared__ u16 As[128 * 32];
    __shared__ u16 Bs[128 * 32];
    const int n0 = blockIdx.x * 128;
    const int kbeg = blockIdx.y * KC;
    const int tid = threadIdx.x;
    const int w = tid >> 6, l = tid & 63;
    const int wr = w * 32;
    const int nl = tid >> 1, seg = tid & 1;
    const u16* aptr = (nl < 64 ? Ah + (long)nl * K : Ahm + (long)(nl - 64) * K) + seg * 16;
    const float* wcol = W + n0 + nl;

    f32x4 acc[2][8];
    #pragma unroll
    for (int mi = 0; mi < 2; mi++)
        #pragma unroll
        for (int ni = 0; ni < 8; ni++) { f32x4 z = {0.f, 0.f, 0.f, 0.f}; acc[mi][ni] = z; }

    for (int ks = 0; ks < KC; ks += 32) {
        const int k0 = kbeg + ks;
        uint4 a0 = *(const uint4*)(aptr + k0);
        uint4 a1 = *(const uint4*)(aptr + k0 + 8);
        float wv[16];
        #pragma unroll
        for (int j = 0; j < 16; j++)
            wv[j] = wcol[(long)(k0 + seg * 16 + j) * N];
        __syncthreads();
        *(uint4*)(As + nl * 32 + seg * 16)     = a0;
        *(uint4*)(As + nl * 32 + seg * 16 + 8) = a1;
        u32 pk[8];
        #pragma unroll
        for (int j = 0; j < 8; j++)
            pk[j] = (u32)f2b(wv[2 * j]) | ((u32)f2b(wv[2 * j + 1]) << 16);
        *(uint4*)(Bs + nl * 32 + seg * 16)     = *(uint4*)&pk[0];
        *(uint4*)(Bs + nl * 32 + seg * 16 + 8) = *(uint4*)&pk[4];
        __syncthreads();
        bf16x8 aF0 = *(const bf16x8*)(As + (wr + (l & 15)) * 32 + (l >> 4) * 8);
        bf16x8 aF1 = *(const bf16x8*)(As + (wr + 16 + (l & 15)) * 32 + (l >> 4) * 8);
        #pragma unroll
        for (int ni = 0; ni < 8; ni++) {
            bf16x8 bF = *(const bf16x8*)(Bs + (ni * 16 + (l & 15)) * 32 + (l >> 4) * 8);
            acc[0][ni] = __builtin_amdgcn_mfma_f32_16x16x32_bf16(aF0, bF, acc[0][ni], 0, 0, 0);
            acc[1][ni] = __builtin_amdgcn_mfma_f32_16x16x32_bf16(aF1, bF, acc[1][ni], 0, 0, 0);
        }
    }
    float* Pz = P + (long)blockIdx.y * 128 * N;
    #pragma unroll
    for (int mi = 0; mi < 2; mi++)
        #pragma unroll
        for (int ni = 0; ni < 8; ni++) {
            const int col = n0 + ni * 16 + (l & 15);
            #pragma unroll
            for (int r = 0; r < 4; r++)
                Pz[(long)(wr + mi * 16 + (l >> 4) * 4 + r) * N + col] = acc[mi][ni][r];
        }
}

// ---------------------------------------------------------------- fp32 attention (mask path, colsum only)
__global__ __launch_bounds__(128)
void attn_kernel(const float* __restrict__ Q, const float* __restrict__ K,
                 const int* __restrict__ toks, float* __restrict__ colsum, int Hn) {
    __shared__ float sc[S][129];
    __shared__ float KV[S][DK];
    __shared__ int   padS[S];
    const int b = blockIdx.x / Hn;
    const int h = blockIdx.x % Hn;
    const int stride = Hn * DK;
    const int tid = threadIdx.x;

    for (int idx = tid; idx < S * DK; idx += 128) {
        int r = idx >> 6, c = idx & 63;
        KV[r][c] = K[(long)(b * S + r) * stride + h * DK + c];
    }
    padS[tid] = (toks[b * S + tid] == 0) ? 1 : 0;
    float qreg[DK];
    {
        const float* qp = Q + (long)(b * S + tid) * stride + h * DK;
        #pragma unroll
        for (int i = 0; i < 16; i++) {
            float4 t4 = *(const float4*)(qp + i * 4);
            qreg[i * 4 + 0] = t4.x; qreg[i * 4 + 1] = t4.y;
            qreg[i * 4 + 2] = t4.z; qreg[i * 4 + 3] = t4.w;
        }
    }
    __syncthreads();
    for (int k = 0; k < S; k++) {
        float s = 0.0f;
        #pragma unroll
        for (int d4 = 0; d4 < 16; d4++) {
            float4 kv = *(const float4*)&KV[k][d4 * 4];
            s += qreg[d4 * 4 + 0] * kv.x + qreg[d4 * 4 + 1] * kv.y
               + qreg[d4 * 4 + 2] * kv.z + qreg[d4 * 4 + 3] * kv.w;
        }
        sc[tid][k] = padS[k] ? -1e9f : (s * 0.125f);
    }
    float mx = -INFINITY;
    for (int k = 0; k < S; k++) mx = fmaxf(mx, sc[tid][k]);
    float sum = 0.0f;
    for (int k = 0; k < S; k++) { float e = expf(sc[tid][k] - mx); sc[tid][k] = e; sum += e; }
    for (int k = 0; k < S; k++) sc[tid][k] = sc[tid][k] / sum;
    __syncthreads();
    {
        double a = 0.0;
        for (int q2 = 0; q2 < S; q2++) a += (double)sc[q2][tid];
        colsum[(long)(b * Hn + h) * S + tid] = (float)a;
    }
}

// ---------------------------------------------------------------- MFMA attention (batched passes)
__global__ __launch_bounds__(256)
void attn_mfma_kernel(u16* qb, const u16* __restrict__ kb, const u16* __restrict__ vb,
                      const int* __restrict__ toks, const int* __restrict__ mtok,
                      float* __restrict__ colsum) {
    __shared__ u16 pool[18432];          // Qs[128][72] | Ks[128][72] ; Ps[128][136] aliases
    __shared__ u16 Vt[64 * 136];
    __shared__ float colsLds[4][128];
    __shared__ u32 padF[128];
    u16* Qs = pool;
    u16* Ks = pool + 9216;
    u16* Ps = pool;

    const int gb = blockIdx.x >> 3, h = blockIdx.x & 7;
    const int tid = threadIdx.x;
    const int w = tid >> 6, l = tid & 63;
    const long base = (long)gb * S * D + h * 64;
    const int* tsrc = (gb < B) ? (toks + (long)gb * S) : (mtok + (long)(gb - B) * S);

    for (int j = tid; j < 1024; j += 256) {
        int r = j >> 3, c = j & 7;
        uint4 uq = *(const uint4*)(qb + base + (long)r * D + c * 8);
        uint4 uk = *(const uint4*)(kb + base + (long)r * D + c * 8);
        uint4 uv = *(const uint4*)(vb + base + (long)r * D + c * 8);
        *(uint4*)(Qs + r * 72 + c * 8) = uq;
        *(uint4*)(Ks + r * 72 + c * 8) = uk;
        u16 vv[8]; *(uint4*)vv = uv;
        #pragma unroll
        for (int t = 0; t < 8; t++) Vt[(c * 8 + t) * 136 + r] = vv[t];
    }
    if (tid < 128) padF[tid] = (tsrc[tid] == 0) ? 1u : 0u;
    __syncthreads();

    const int rowB = w * 32;
    f32x4 acc[2][8];
    #pragma unroll
    for (int mi = 0; mi < 2; mi++)
        #pragma unroll
        for (int ni = 0; ni < 8; ni++) { f32x4 z = {0.f, 0.f, 0.f, 0.f}; acc[mi][ni] = z; }
    #pragma unroll
    for (int ks = 0; ks < 2; ks++) {
        bf16x8 a0 = *(const bf16x8*)(Qs + (rowB + (l & 15)) * 72 + ks * 32 + (l >> 4) * 8);
        bf16x8 a1 = *(const bf16x8*)(Qs + (rowB + 16 + (l & 15)) * 72 + ks * 32 + (l >> 4) * 8);
        #pragma unroll
        for (int ni = 0; ni < 8; ni++) {
            bf16x8 bv = *(const bf16x8*)(Ks + (ni * 16 + (l & 15)) * 72 + ks * 32 + (l >> 4) * 8);
            acc[0][ni] = __builtin_amdgcn_mfma_f32_16x16x32_bf16(a0, bv, acc[0][ni], 0, 0, 0);
            acc[1][ni] = __builtin_amdgcn_mfma_f32_16x16x32_bf16(a1, bv, acc[1][ni], 0, 0, 0);
        }
    }
    float pf[8];
    #pragma unroll
    for (int ni = 0; ni < 8; ni++) pf[ni] = padF[ni * 16 + (l & 15)] ? 1.0f : 0.0f;
    #pragma unroll
    for (int mi = 0; mi < 2; mi++)
        #pragma unroll
        for (int ni = 0; ni < 8; ni++)
            #pragma unroll
            for (int r = 0; r < 4; r++) {
                float v = acc[mi][ni][r] * 0.125f;
                acc[mi][ni][r] = (pf[ni] != 0.0f) ? -1e9f : v;
            }
    #pragma unroll
    for (int mi = 0; mi < 2; mi++)
        #pragma unroll
        for (int r = 0; r < 4; r++) {
            float m = -INFINITY;
            #pragma unroll
            for (int ni = 0; ni < 8; ni++) m = fmaxf(m, acc[mi][ni][r]);
            m = fmaxf(m, __shfl_xor(m, 1)); m = fmaxf(m, __shfl_xor(m, 2));
            m = fmaxf(m, __shfl_xor(m, 4)); m = fmaxf(m, __shfl_xor(m, 8));
            float s = 0.0f;
            #pragma unroll
            for (int ni = 0; ni < 8; ni++) { float e = expf(acc[mi][ni][r] - m); acc[mi][ni][r] = e; s += e; }
            s += __shfl_xor(s, 1); s += __shfl_xor(s, 2);
            s += __shfl_xor(s, 4); s += __shfl_xor(s, 8);
            float inv = 1.0f / s;
            #pragma unroll
            for (int ni = 0; ni < 8; ni++) acc[mi][ni][r] *= inv;
        }
    float cs[8];
    #pragma unroll
    for (int ni = 0; ni < 8; ni++) {
        float s = 0.0f;
        #pragma unroll
        for (int mi = 0; mi < 2; mi++)
            #pragma unroll
            for (int r = 0; r < 4; r++) s += acc[mi][ni][r];
        s += __shfl_xor(s, 16); s += __shfl_xor(s, 32);
        cs[ni] = s;
    }
    __syncthreads();
    if (l < 16)
        #pragma unroll
        for (int ni = 0; ni < 8; ni++) colsLds[w][ni * 16 + l] = cs[ni];
    #pragma unroll
    for (int mi = 0; mi < 2; mi++)
        #pragma unroll
        for (int ni = 0; ni < 8; ni++)
            #pragma unroll
            for (int r = 0; r < 4; r++)
                Ps[(rowB + mi * 16 + (l >> 4) * 4 + r) * 136 + ni * 16 + (l & 15)] =
                    f2b(acc[mi][ni][r]);
    __syncthreads();
    if (tid < 128) {
        float s = colsLds[0][tid] + colsLds[1][tid] + colsLds[2][tid] + colsLds[3][tid];
        colsum[((long)gb * H + h) * S + tid] = s;
    }
    f32x4 o[2][4];
    #pragma unroll
    for (int mi = 0; mi < 2; mi++)
        #pragma unroll
        for (int n = 0; n < 4; n++) { f32x4 z = {0.f, 0.f, 0.f, 0.f}; o[mi][n] = z; }
    #pragma unroll
    for (int ks = 0; ks < 4; ks++) {
        bf16x8 p0 = *(const bf16x8*)(Ps + (rowB + (l & 15)) * 136 + ks * 32 + (l >> 4) * 8);
        bf16x8 p1 = *(const bf16x8*)(Ps + (rowB + 16 + (l & 15)) * 136 + ks * 32 + (l >> 4) * 8);
        #pragma unroll
        for (int n = 0; n < 4; n++) {
            bf16x8 bv = *(const bf16x8*)(Vt + (n * 16 + (l & 15)) * 136 + ks * 32 + (l >> 4) * 8);
            o[0][n] = __builtin_amdgcn_mfma_f32_16x16x32_bf16(p0, bv, o[0][n], 0, 0, 0);
            o[1][n] = __builtin_amdgcn_mfma_f32_16x16x32_bf16(p1, bv, o[1][n], 0, 0, 0);
        }
    }
    #pragma unroll
    for (int mi = 0; mi < 2; mi++)
        #pragma unroll
        for (int n = 0; n < 4; n++) {
            const int col = n * 16 + (l & 15);
            #pragma unroll
            for (int r = 0; r < 4; r++) {
                const int row = rowB + mi * 16 + (l >> 4) * 4 + r;
                qb[base + (long)row * D + col] = f2b(o[mi][n][r]);
            }
        }
}

// ---------------------------------------------------------------- creat_mask
__global__ __launch_bounds__(128)
void creat_mask_kernel(const float* __restrict__ colpart, const int* __restrict__ toks,
                       int* __restrict__ mtok, float* __restrict__ out) {
    __shared__ float colS[S];
    __shared__ int   j0s, kks;
    const int b = blockIdx.x, j = threadIdx.x;
    float c = colpart[(long)(b * AH + 0) * S + j] + colpart[(long)(b * AH + 1) * S + j];
    colS[j] = c;
    int tk = toks[b * S + j];
    __syncthreads();
    if (j == 0) {
        int j0 = S;
        for (int i = 0; i < S; i++) if (colS[i] == 0.0f) { j0 = i; break; }
        int kk = (j0 < S) ? (int)ceilf(0.2f * (float)j0) : 0;
        j0s = j0; kks = kk;
    }
    __syncthreads();
    const int j0 = j0s, kk = kks;
    float vj = (j < j0) ? colS[j] : INFINITY;
    int rank = 0;
    for (int i = 0; i < S; i++) {
        float vi = (i < j0) ? colS[i] : INFINITY;
        if (vi < vj || (vi == vj && i < j)) rank++;
    }
    int mt = (rank >= kk) ? tk : 0;
    mtok[b * S + j] = mt;
    out[OUT_TOK + b * S + j]  = (float)tk;
    out[OUT_MTOK + b * S + j] = (float)mt;
}

// ---------------------------------------------------------------- LayerNorm: y (pre-LN fp32) -> xb (bf16)
__global__ __launch_bounds__(256)
void ln_kernel(const float* __restrict__ y, u16* __restrict__ xb) {
    const int row  = blockIdx.x * 4 + (threadIdx.x >> 6);
    const int lane = threadIdx.x & 63;
    const float* r = y + (long)row * D;
    float4 v0 = *(const float4*)(r + lane * 4);
    float4 v1 = *(const float4*)(r + 256 + lane * 4);
    float s = v0.x + v0.y + v0.z + v0.w + v1.x + v1.y + v1.z + v1.w;
    #pragma unroll
    for (int off = 32; off; off >>= 1) s += __shfl_xor(s, off);
    float m = s * (1.0f / 512.0f);
    float d0 = v0.x - m, d1 = v0.y - m, d2 = v0.z - m, d3 = v0.w - m;
    float d4 = v1.x - m, d5 = v1.y - m, d6 = v1.z - m, d7 = v1.w - m;
    float q = d0*d0 + d1*d1 + d2*d2 + d3*d3 + d4*d4 + d5*d5 + d6*d6 + d7*d7;
    #pragma unroll
    for (int off = 32; off; off >>= 1) q += __shfl_xor(q, off);
    float inv = 1.0f / sqrtf(q * (1.0f / 512.0f) + 1e-5f);
    u16* rb = xb + (long)row * D;
    u16 p0[4] = {f2b(d0 * inv), f2b(d1 * inv), f2b(d2 * inv), f2b(d3 * inv)};
    u16 p1[4] = {f2b(d4 * inv), f2b(d5 * inv), f2b(d6 * inv), f2b(d7 * inv)};
    *(uint2*)(rb + lane * 4)       = *(uint2*)p0;
    *(uint2*)(rb + 256 + lane * 4) = *(uint2*)p1;
}

// ---------------------------------------------------------------- scores output (pass-0 half)
__global__ void score_reduce_kernel(const float* __restrict__ ascorep, float* __restrict__ dst) {
    int idx = blockIdx.x * 256 + threadIdx.x;
    if (idx >= B * S) return;
    int b = idx >> 7, j = idx & 127;
    float s = 0.0f;
    for (int h = 0; h < H; h++) s += ascorep[(long)(b * H + h) * S + j];
    dst[idx] = s;
}

// ---------------------------------------------------------------- pre-head reduce/pack
__global__ void reduce1_kernel(const float* __restrict__ parts, const float* __restrict__ b1,
                               float* __restrict__ o) {
    int idx = blockIdx.x * 256 + threadIdx.x;
    if (idx >= 128 * 1024) return;
    float s = 0.0f;
    for (int z = 0; z < 64; z++) s += parts[(long)z * 128 * 1024 + idx];
    s += b1[idx & 1023];
    o[idx] = fmaxf(s, 0.0f);
}

__global__ void pack_out_kernel(const float* __restrict__ ph3, float* __restrict__ out) {
    int idx = blockIdx.x * 256 + threadIdx.x;
    if (idx >= 128 * 128) return;
    int row = idx >> 7, col = idx & 127;
    long base = (row < 64) ? (OUT_OUT1 + (long)row * 128) : (OUT_OUTM + (long)(row - 64) * 128);
    out[base + col] = ph3[idx];
}

// ================================================================ launch
extern "C" void kernel_launch(void* const* d_in, const int* in_sizes, int n_in,
                              void* d_out, int out_size, void* d_ws, size_t ws_size,
                              hipStream_t stream) {
    const int*   toks = (const int*)d_in[0];
    const float* emb  = (const float*)d_in[1];
    const float* aWQ  = (const float*)d_in[2];
    const float* aWK  = (const float*)d_in[3];
    const float* tWQ  = (const float*)d_in[8];
    const float* tWK  = (const float*)d_in[9];
    const float* tWV  = (const float*)d_in[10];
    const float* tFC  = (const float*)d_in[11];
    const float* tF1  = (const float*)d_in[12];
    const float* tF2  = (const float*)d_in[13];
    const float* pW1  = (const float*)d_in[14];
    const float* pb1  = (const float*)d_in[15];
    const float* pW2  = (const float*)d_in[16];
    const float* pb2  = (const float*)d_in[17];
    const float* pW3  = (const float*)d_in[18];
    const float* pb3  = (const float*)d_in[19];
    float* out = (float*)d_out;

    float* ws   = (float*)d_ws;
    float* pe   = ws + OFF_PE;
    float* ascp = ws + OFF_ASC;
    float* colp = ws + OFF_COLP;
    int*   mtok = (int*)(ws + OFF_MTOK);
    float* x    = ws + OFF_X;          // clean-emb fp32 (mask path) / pre-LN scratch y
    u16*   xb   = (u16*)(ws + OFF_XB); // [BS2][D] bf16 canonical state
    u16*   qb   = (u16*)(ws + OFF_QB);
    u16*   kb   = (u16*)(ws + OFF_KB);
    u16*   vb   = (u16*)(ws + OFF_VB);
    u16*   tb   = (u16*)(ws + OFF_TB); // [BS2][DFF] bf16
    u16*   wAll = (u16*)(ws + OFF_W);

    // phase-disjoint aliases of the TB region
    float* maq   = ws + OFF_TB;                 // mask encoder q [BS][128] fp32
    float* mak   = maq + (long)BS * 128;
    float* parts = ws + OFF_TB;                 // pre-head partials 64 x [128][1024]
    float* ph1o  = parts + 8388608;
    float* ph2o  = ph1o + 131072;
    float* ph3o  = ph2o + 65536;

    // --- setup: pos-enc, all-layer weight conversion, clean embedding
    pe_kernel<<<128, 256, 0, stream>>>(pe);
    wconv_all<<<6 * 3072, 256, 0, stream>>>(tWQ, tWK, tWV, tFC, tF1, tF2, wAll);
    embed_dual<<<2048, 256, 0, stream>>>(toks, emb, pe, x, xb);

    // --- mask-generating encoder (fp32; only the attention matrix is consumed)
    gemm64_qkv<<<dim3(BS / 64, 2, 2), 256, 0, stream>>>(
        x, aWQ, aWK, nullptr, maq, mak, nullptr, BS, AH * DK, D);
    attn_kernel<<<B * AH, 128, 0, stream>>>(maq, mak, toks, colp, AH);
    creat_mask_kernel<<<B, 128, 0, stream>>>(colp, toks, mtok, out);
    embed_dual<<<2048, 256, 0, stream>>>(mtok, emb, pe, x + (long)BS * D, xb + (long)BS * D);

    // --- 6 layers, both passes batched; residual state lives in bf16 xb, pre-LN scratch in x
    for (int l = 0; l < L; l++) {
        const u16* wq = wAll + (long)l * WSTRIDE;
        const u16* wk = wq + 262144;
        const u16* wv = wq + 524288;
        const u16* wo = wq + 786432;
        const u16* w1 = wq + 1048576;
        const u16* w2 = wq + 2097152;
        gemm_qkv_b<<<dim3(BS2 / 128, D / 128, 3), 256, 0, stream>>>(
            xb, wq, wk, wv, qb, kb, vb, BS2, D, D);
        attn_mfma_kernel<<<2 * B * H, 256, 0, stream>>>(qb, kb, vb, toks, mtok, ascp);
        score_reduce_kernel<<<32, 256, 0, stream>>>(ascp, out + OUT_SCORES + (long)l * BS);
        gemm_resid_b<<<dim3(BS2 / 128, D / 128), 256, 0, stream>>>(qb, wo, x, xb, BS2, D, D);
        ln_kernel<<<BS2 / 4, 256, 0, stream>>>(x, xb);
        gemm_relu_b<<<dim3(BS2 / 128, DFF / 128), 256, 0, stream>>>(xb, w1, tb, BS2, DFF, D);
        gemm_resid_b<<<dim3(BS2 / 128, D / 128), 256, 0, stream>>>(tb, w2, x, xb, BS2, D, DFF);
        ln_kernel<<<BS2 / 4, 256, 0, stream>>>(x, xb);
    }

    // --- pre_head: MFMA split-K over pW1 (xb holds bf16 h ‖ hm)
    gemm_ph1<<<dim3(8, 64), 256, 0, stream>>>(xb, xb + (long)BS * D, pW1, parts, 1024);
    reduce1_kernel<<<512, 256, 0, stream>>>(parts, pb1, ph1o);
    gemm64<4><<<dim3(2, 8), 256, 0, stream>>>(ph1o, pW2, ph2o, pb2, 128, 512, 1024);
    gemm64<3><<<dim3(2, 2), 256, 0, stream>>>(ph2o, pW3, ph3o, pb3, 128, 128, 512);
    pack_out_kernel<<<64, 256, 0, stream>>>(ph3o, out);
}

// Round 12
// 1471.754 us; speedup vs baseline: 1.2295x; 1.0169x over previous
//
#include <hip/hip_runtime.h>
#include <hip/hip_bf16.h>
#include <math.h>

using u16 = unsigned short;
using u32 = unsigned int;

// Problem constants
constexpr int B   = 64;
constexpr int S   = 128;
constexpr int D   = 512;
constexpr int H   = 8;
constexpr int DK  = 64;
constexpr int L   = 6;
constexpr int DFF = 2048;
constexpr int AH  = 2;
constexpr int BS  = B * S;          // 8192
constexpr int BS2 = 2 * BS;         // 16384 (both passes batched)

// Output layout (fp32 elements)
constexpr long OUT_TOK    = 0;
constexpr long OUT_OUT1   = 8192;
constexpr long OUT_MTOK   = 16384;
constexpr long OUT_OUTM   = 24576;
constexpr long OUT_SCORES = 32768;

// Workspace layout (float units). ~226 MB of ~1 GiB ws
constexpr long OFF_PE   = 0;             // 65536
constexpr long OFF_ASCL = 65536;         // 6 layers x 2*B*H*S = 786432
constexpr long OFF_COLP = 851968;        // B*AH*S = 16384
constexpr long OFF_MTOK = 868352;        // 8192 ints
constexpr long OFF_X    = 876544;        // BS2*D fp32 (mask path uses first half)
constexpr long OFF_XB   = 9265152;       // BS2*D bf16 = 4,194,304 fl (canonical state)
constexpr long OFF_Y    = 13459456;      // BS2*D bf16 pre-LN scratch
constexpr long OFF_QB   = 17653760;      // BS2*D bf16
constexpr long OFF_KB   = 21848064;      // BS2*D bf16
constexpr long OFF_VB   = 26042368;      // BS2*D bf16
constexpr long OFF_TB   = 30236672;      // BS2*DFF bf16 = 16,777,216 fl (alias: mask q/k, pre-head parts)
constexpr long OFF_W    = 47013888;      // 6 layers x 3,145,728 bf16 = 9,437,184 fl
constexpr long WSTRIDE  = 3145728;       // bf16 elems per layer
constexpr long ASCL_STRIDE = 131072;     // per-layer colsum floats (2*B*H*S)

typedef __attribute__((ext_vector_type(8))) short bf16x8;
typedef __attribute__((ext_vector_type(4))) float f32x4;

__device__ __forceinline__ float b2f(u16 u) {
    union { u32 i; float f; } v; v.i = ((u32)u) << 16; return v.f;
}
__device__ __forceinline__ u16 f2b(float f) {      // RNE f32 -> bf16
    union { float f; u32 i; } v; v.f = f;
    u32 r = v.i + 0x7fffu + ((v.i >> 16) & 1u);
    return (u16)(r >> 16);
}

#define GLOAD_LDS16(g, l) __builtin_amdgcn_global_load_lds(                        \
    (const __attribute__((address_space(1))) u32*)(const void*)(g),               \
    (__attribute__((address_space(3))) u32*)(void*)(l), 16, 0, 0)

// ---------------------------------------------------------------- pos enc
__global__ void pe_kernel(float* __restrict__ pe) {
    int idx = blockIdx.x * 256 + threadIdx.x;
    if (idx >= S * (D / 2)) return;
    int s = idx >> 8;
    int i = idx & 255;
    const float CPE = (float)(-9.210340371976184 / 512.0);
    float div = expf((float)(2 * i) * CPE);
    float ang = (float)s * div;
    pe[(long)s * D + 2 * i]     = sinf(ang);
    pe[(long)s * D + 2 * i + 1] = cosf(ang);
}

// ---------------------------------------------------------------- embed + pe (optional fp32 + bf16 out)
__global__ void embed_dual(const int* __restrict__ toks, const float* __restrict__ emb,
                           const float* __restrict__ pe, float* x,
                           u16* __restrict__ xb) {
    int i8 = blockIdx.x * 256 + threadIdx.x;      // over BS*D/8 = 524288
    if (i8 >= BS * D / 8) return;
    int row = i8 >> 6;
    int c8  = i8 & 63;
    int s   = row & (S - 1);
    int t   = toks[row];
    float4 e0 = *(const float4*)(emb + (long)t * D + c8 * 8);
    float4 e1 = *(const float4*)(emb + (long)t * D + c8 * 8 + 4);
    float4 p0 = *(const float4*)(pe + (long)s * D + c8 * 8);
    float4 p1 = *(const float4*)(pe + (long)s * D + c8 * 8 + 4);
    float4 o0, o1;
    o0.x = e0.x + p0.x; o0.y = e0.y + p0.y; o0.z = e0.z + p0.z; o0.w = e0.w + p0.w;
    o1.x = e1.x + p1.x; o1.y = e1.y + p1.y; o1.z = e1.z + p1.z; o1.w = e1.w + p1.w;
    if (x) {
        *(float4*)(x + (long)i8 * 8)     = o0;
        *(float4*)(x + (long)i8 * 8 + 4) = o1;
    }
    u16 u[8] = {f2b(o0.x), f2b(o0.y), f2b(o0.z), f2b(o0.w), f2b(o1.x), f2b(o1.y), f2b(o1.z), f2b(o1.w)};
    *(uint4*)(xb + (long)i8 * 8) = *(uint4*)u;
}

// ---------------------------------------------------------------- all-layer weight transpose+convert
__global__ __launch_bounds__(256)
void wconv_all(const float* __restrict__ tWQ, const float* __restrict__ tWK,
               const float* __restrict__ tWV, const float* __restrict__ tFC,
               const float* __restrict__ tF1, const float* __restrict__ tF2,
               u16* __restrict__ wAll) {
    __shared__ float t[32][33];
    const int lyr = blockIdx.x / 3072;
    const int bid = blockIdx.x % 3072;
    u16* base = wAll + (long)lyr * WSTRIDE;
    const float* src; u16* dst; int KK, NN, tk, tn;
    if (bid < 1024) {
        int which = bid >> 8, tt = bid & 255;
        src = (which == 0 ? tWQ : which == 1 ? tWK : which == 2 ? tWV : tFC) + (long)lyr * D * D;
        dst = base + (long)which * 262144;
        KK = 512; NN = 512; tk = tt >> 4; tn = tt & 15;
    } else if (bid < 2048) {
        int tt = bid - 1024;
        src = tF1 + (long)lyr * D * DFF; dst = base + 1048576;
        KK = 512; NN = 2048; tk = tt >> 6; tn = tt & 63;
    } else {
        int tt = bid - 2048;
        src = tF2 + (long)lyr * DFF * D; dst = base + 2097152;
        KK = 2048; NN = 512; tk = tt >> 4; tn = tt & 15;
    }
    int ty = threadIdx.x >> 5, tx = threadIdx.x & 31;
    #pragma unroll
    for (int i = 0; i < 4; i++)
        t[ty + i * 8][tx] = src[(long)(tk * 32 + ty + i * 8) * NN + tn * 32 + tx];
    __syncthreads();
    #pragma unroll
    for (int i = 0; i < 4; i++)
        dst[(long)(tn * 32 + ty + i * 8) * KK + tk * 32 + tx] = f2b(t[tx][ty + i * 8]);
}

// ---------------------------------------------------------------- bf16 MFMA GEMM core
// 128x128 tile, 4 waves, BK=64 via TWO independent 128x32 panels per barrier pair.
// EPI: 0 none, 2 relu, 3 +bf16 residual X[M,N]. OUTB: bf16 output.
template<int EPI, int OUTB>
__device__ __forceinline__ void gemm_core(
        const u16* __restrict__ A, const u16* __restrict__ Wt,
        float* C, u16* Cb, const u16* __restrict__ X,
        int M, int N, int K, int m0, int n0) {
    __shared__ u16 As[2][128 * 32];
    __shared__ u16 Bs[2][128 * 32];
    const int tid = threadIdx.x;
    const int w = tid >> 6, l = tid & 63;
    const int wr = (w >> 1) * 64, wc = (w & 1) * 64;
    f32x4 acc[4][4];
    #pragma unroll
    for (int i = 0; i < 4; i++)
        #pragma unroll
        for (int j = 0; j < 4; j++) { f32x4 z = {0.f, 0.f, 0.f, 0.f}; acc[i][j] = z; }

    const int srow = w * 32 + (l >> 2);
    const int scol = (l & 3) * 8;
    const u16* gA = A + (long)(m0 + srow) * K + scol;
    const u16* gB = Wt + (long)(n0 + srow) * K + scol;

    for (int k0 = 0; k0 < K; k0 += 64) {
        #pragma unroll
        for (int p = 0; p < 2; p++) {
            GLOAD_LDS16(gA + k0 + p * 32,               As[p] + w * 1024);
            GLOAD_LDS16(gA + (long)16 * K + k0 + p * 32, As[p] + w * 1024 + 512);
            GLOAD_LDS16(gB + k0 + p * 32,               Bs[p] + w * 1024);
            GLOAD_LDS16(gB + (long)16 * K + k0 + p * 32, Bs[p] + w * 1024 + 512);
        }
        __syncthreads();
        #pragma unroll
        for (int p = 0; p < 2; p++) {
            bf16x8 aF[4], bF[4];
            #pragma unroll
            for (int mi = 0; mi < 4; mi++)
                aF[mi] = *(const bf16x8*)(As[p] + (wr + mi * 16 + (l & 15)) * 32 + (l >> 4) * 8);
            #pragma unroll
            for (int ni = 0; ni < 4; ni++)
                bF[ni] = *(const bf16x8*)(Bs[p] + (wc + ni * 16 + (l & 15)) * 32 + (l >> 4) * 8);
            #pragma unroll
            for (int mi = 0; mi < 4; mi++)
                #pragma unroll
                for (int ni = 0; ni < 4; ni++)
                    acc[mi][ni] = __builtin_amdgcn_mfma_f32_16x16x32_bf16(aF[mi], bF[ni], acc[mi][ni], 0, 0, 0);
        }
        __syncthreads();
    }

    #pragma unroll
    for (int mi = 0; mi < 4; mi++) {
        #pragma unroll
        for (int ni = 0; ni < 4; ni++) {
            const int col = n0 + wc + ni * 16 + (l & 15);
            #pragma unroll
            for (int r = 0; r < 4; r++) {
                const int row = m0 + wr + mi * 16 + (l >> 4) * 4 + r;
                const long idx = (long)row * N + col;
                float v = acc[mi][ni][r];
                if (EPI == 3) v += b2f(X[idx]);
                if (EPI == 2) v = fmaxf(v, 0.0f);
                if (OUTB) Cb[idx] = f2b(v);
                else      C[idx]  = v;
            }
        }
    }
}

__global__ __launch_bounds__(256)
void gemm_qkv_b(const u16* __restrict__ A, const u16* wq, const u16* wk, const u16* wv,
                u16* qb, u16* kb, u16* vb, int M, int N, int K) {
    const u16* Wt = blockIdx.z == 0 ? wq : blockIdx.z == 1 ? wk : wv;
    u16* Cb       = blockIdx.z == 0 ? qb : blockIdx.z == 1 ? kb : vb;
    gemm_core<0, 1>(A, Wt, nullptr, Cb, nullptr, M, N, K, blockIdx.x * 128, blockIdx.y * 128);
}
__global__ __launch_bounds__(256)
void gemm_resid_b(const u16* __restrict__ A, const u16* __restrict__ Wt,
                  u16* Yb, const u16* __restrict__ X, int M, int N, int K) {
    gemm_core<3, 1>(A, Wt, nullptr, Yb, X, M, N, K, blockIdx.x * 128, blockIdx.y * 128);
}
__global__ __launch_bounds__(256)
void gemm_relu_b(const u16* __restrict__ A, const u16* __restrict__ Wt,
                 u16* Cb, int M, int N, int K) {
    gemm_core<2, 1>(A, Wt, nullptr, Cb, nullptr, M, N, K, blockIdx.x * 128, blockIdx.y * 128);
}

// ---------------------------------------------------------------- fp32 GEMM (pre-head tail)
template<int EPI>
__global__ __launch_bounds__(256)
void gemm64(const float* __restrict__ A, const float* __restrict__ W,
            float* C, const float* X, int M, int N, int K) {
    __shared__ float As[32][68];
    __shared__ float Ws[32][64];
    const int m0 = blockIdx.x * 64, n0 = blockIdx.y * 64;
    const int tid  = threadIdx.x;
    const int tr   = tid >> 4, tc = tid & 15;
    const int arow = tid >> 3, acg = tid & 7;
    const int wrow = tid >> 4, wcg = tid & 15;
    float acc[4][4] = {};
    for (int k0 = 0; k0 < K; k0 += 32) {
        float4 a0 = *(const float4*)(A + (long)(m0 + arow) * K + k0 + acg * 4);
        float4 a1 = *(const float4*)(A + (long)(m0 + arow + 32) * K + k0 + acg * 4);
        float4 w0 = *(const float4*)(W + (long)(k0 + wrow) * N + n0 + wcg * 4);
        float4 w1 = *(const float4*)(W + (long)(k0 + wrow + 16) * N + n0 + wcg * 4);
        As[acg * 4 + 0][arow] = a0.x; As[acg * 4 + 1][arow] = a0.y;
        As[acg * 4 + 2][arow] = a0.z; As[acg * 4 + 3][arow] = a0.w;
        As[acg * 4 + 0][arow + 32] = a1.x; As[acg * 4 + 1][arow + 32] = a1.y;
        As[acg * 4 + 2][arow + 32] = a1.z; As[acg * 4 + 3][arow + 32] = a1.w;
        *(float4*)&Ws[wrow][wcg * 4]      = w0;
        *(float4*)&Ws[wrow + 16][wcg * 4] = w1;
        __syncthreads();
        #pragma unroll
        for (int kk = 0; kk < 32; kk++) {
            float4 av = *(const float4*)&As[kk][tr * 4];
            float4 bv = *(const float4*)&Ws[kk][tc * 4];
            acc[0][0] += av.x * bv.x; acc[0][1] += av.x * bv.y; acc[0][2] += av.x * bv.z; acc[0][3] += av.x * bv.w;
            acc[1][0] += av.y * bv.x; acc[1][1] += av.y * bv.y; acc[1][2] += av.y * bv.z; acc[1][3] += av.y * bv.w;
            acc[2][0] += av.z * bv.x; acc[2][1] += av.z * bv.y; acc[2][2] += av.z * bv.z; acc[2][3] += av.z * bv.w;
            acc[3][0] += av.w * bv.x; acc[3][1] += av.w * bv.y; acc[3][2] += av.w * bv.z; acc[3][3] += av.w * bv.w;
        }
        __syncthreads();
    }
    #pragma unroll
    for (int i = 0; i < 4; i++) {
        int row = m0 + tr * 4 + i;
        #pragma unroll
        for (int j = 0; j < 4; j++) {
            int col = n0 + tc * 4 + j;
            long idx = (long)row * N + col;
            float v = acc[i][j];
            if (EPI == 1) v += X[idx];
            if (EPI == 3 || EPI == 4) v += X[col];
            if (EPI == 2 || EPI == 4) v = fmaxf(v, 0.0f);
            C[idx] = v;
        }
    }
}

// QKV merged fp32 (mask encoder)
__global__ __launch_bounds__(256)
void gemm64_qkv(const float* __restrict__ A,
                const float* __restrict__ WQ, const float* __restrict__ WK, const float* __restrict__ WV,
                float* q, float* k, float* v, int M, int N, int K) {
    __shared__ float As[32][68];
    __shared__ float Ws[32][64];
    const float* W = (blockIdx.z == 0) ? WQ : (blockIdx.z == 1) ? WK : WV;
    float*       C = (blockIdx.z == 0) ? q  : (blockIdx.z == 1) ? k  : v;
    const int m0 = blockIdx.x * 64, n0 = blockIdx.y * 64;
    const int tid  = threadIdx.x;
    const int tr   = tid >> 4, tc = tid & 15;
    const int arow = tid >> 3, acg = tid & 7;
    const int wrow = tid >> 4, wcg = tid & 15;
    float acc[4][4] = {};
    for (int k0 = 0; k0 < K; k0 += 32) {
        float4 a0 = *(const float4*)(A + (long)(m0 + arow) * K + k0 + acg * 4);
        float4 a1 = *(const float4*)(A + (long)(m0 + arow + 32) * K + k0 + acg * 4);
        float4 w0 = *(const float4*)(W + (long)(k0 + wrow) * N + n0 + wcg * 4);
        float4 w1 = *(const float4*)(W + (long)(k0 + wrow + 16) * N + n0 + wcg * 4);
        As[acg * 4 + 0][arow] = a0.x; As[acg * 4 + 1][arow] = a0.y;
        As[acg * 4 + 2][arow] = a0.z; As[acg * 4 + 3][arow] = a0.w;
        As[acg * 4 + 0][arow + 32] = a1.x; As[acg * 4 + 1][arow + 32] = a1.y;
        As[acg * 4 + 2][arow + 32] = a1.z; As[acg * 4 + 3][arow + 32] = a1.w;
        *(float4*)&Ws[wrow][wcg * 4]      = w0;
        *(float4*)&Ws[wrow + 16][wcg * 4] = w1;
        __syncthreads();
        #pragma unroll
        for (int kk = 0; kk < 32; kk++) {
            float4 av = *(const float4*)&As[kk][tr * 4];
            float4 bv = *(const float4*)&Ws[kk][tc * 4];
            acc[0][0] += av.x * bv.x; acc[0][1] += av.x * bv.y; acc[0][2] += av.x * bv.z; acc[0][3] += av.x * bv.w;
            acc[1][0] += av.y * bv.x; acc[1][1] += av.y * bv.y; acc[1][2] += av.y * bv.z; acc[1][3] += av.y * bv.w;
            acc[2][0] += av.z * bv.x; acc[2][1] += av.z * bv.y; acc[2][2] += av.z * bv.z; acc[2][3] += av.z * bv.w;
            acc[3][0] += av.w * bv.x; acc[3][1] += av.w * bv.y; acc[3][2] += av.w * bv.z; acc[3][3] += av.w * bv.w;
        }
        __syncthreads();
    }
    #pragma unroll
    for (int i = 0; i < 4; i++)
        #pragma unroll
        for (int j = 0; j < 4; j++)
            C[(long)(m0 + tr * 4 + i) * N + n0 + tc * 4 + j] = acc[i][j];
}

// ---------------------------------------------------------------- pre-head layer-1: MFMA split-K
__global__ __launch_bounds__(256)
void gemm_ph1(const u16* __restrict__ Ah, const u16* __restrict__ Ahm,
              const float* __restrict__ W, float* __restrict__ P, int KC) {
    constexpr int N = 1024, K = 65536;
    __shared__ u16 As[128 * 32];
    __shared__ u16 Bs[128 * 32];
    const int n0 = blockIdx.x * 128;
    const int kbeg = blockIdx.y * KC;
    const int tid = threadIdx.x;
    const int w = tid >> 6, l = tid & 63;
    const int wr = w * 32;
    const int nl = tid >> 1, seg = tid & 1;
    const u16* aptr = (nl < 64 ? Ah + (long)nl * K : Ahm + (long)(nl - 64) * K) + seg * 16;
    const float* wcol = W + n0 + nl;

    f32x4 acc[2][8];
    #pragma unroll
    for (int mi = 0; mi < 2; mi++)
        #pragma unroll
        for (int ni = 0; ni < 8; ni++) { f32x4 z = {0.f, 0.f, 0.f, 0.f}; acc[mi][ni] = z; }

    for (int ks = 0; ks < KC; ks += 32) {
        const int k0 = kbeg + ks;
        uint4 a0 = *(const uint4*)(aptr + k0);
        uint4 a1 = *(const uint4*)(aptr + k0 + 8);
        float wv[16];
        #pragma unroll
        for (int j = 0; j < 16; j++)
            wv[j] = wcol[(long)(k0 + seg * 16 + j) * N];
        __syncthreads();
        *(uint4*)(As + nl * 32 + seg * 16)     = a0;
        *(uint4*)(As + nl * 32 + seg * 16 + 8) = a1;
        u32 pk[8];
        #pragma unroll
        for (int j = 0; j < 8; j++)
            pk[j] = (u32)f2b(wv[2 * j]) | ((u32)f2b(wv[2 * j + 1]) << 16);
        *(uint4*)(Bs + nl * 32 + seg * 16)     = *(uint4*)&pk[0];
        *(uint4*)(Bs + nl * 32 + seg * 16 + 8) = *(uint4*)&pk[4];
        __syncthreads();
        bf16x8 aF0 = *(const bf16x8*)(As + (wr + (l & 15)) * 32 + (l >> 4) * 8);
        bf16x8 aF1 = *(const bf16x8*)(As + (wr + 16 + (l & 15)) * 32 + (l >> 4) * 8);
        #pragma unroll
        for (int ni = 0; ni < 8; ni++) {
            bf16x8 bF = *(const bf16x8*)(Bs + (ni * 16 + (l & 15)) * 32 + (l >> 4) * 8);
            acc[0][ni] = __builtin_amdgcn_mfma_f32_16x16x32_bf16(aF0, bF, acc[0][ni], 0, 0, 0);
            acc[1][ni] = __builtin_amdgcn_mfma_f32_16x16x32_bf16(aF1, bF, acc[1][ni], 0, 0, 0);
        }
    }
    float* Pz = P + (long)blockIdx.y * 128 * N;
    #pragma unroll
    for (int mi = 0; mi < 2; mi++)
        #pragma unroll
        for (int ni = 0; ni < 8; ni++) {
            const int col = n0 + ni * 16 + (l & 15);
            #pragma unroll
            for (int r = 0; r < 4; r++)
                Pz[(long)(wr + mi * 16 + (l >> 4) * 4 + r) * N + col] = acc[mi][ni][r];
        }
}

// ---------------------------------------------------------------- fp32 attention (mask path, colsum only)
__global__ __launch_bounds__(128)
void attn_kernel(const float* __restrict__ Q, const float* __restrict__ K,
                 const int* __restrict__ toks, float* __restrict__ colsum, int Hn) {
    __shared__ float sc[S][129];
    __shared__ float KV[S][DK];
    __shared__ int   padS[S];
    const int b = blockIdx.x / Hn;
    const int h = blockIdx.x % Hn;
    const int stride = Hn * DK;
    const int tid = threadIdx.x;

    for (int idx = tid; idx < S * DK; idx += 128) {
        int r = idx >> 6, c = idx & 63;
        KV[r][c] = K[(long)(b * S + r) * stride + h * DK + c];
    }
    padS[tid] = (toks[b * S + tid] == 0) ? 1 : 0;
    float qreg[DK];
    {
        const float* qp = Q + (long)(b * S + tid) * stride + h * DK;
        #pragma unroll
        for (int i = 0; i < 16; i++) {
            float4 t4 = *(const float4*)(qp + i * 4);
            qreg[i * 4 + 0] = t4.x; qreg[i * 4 + 1] = t4.y;
            qreg[i * 4 + 2] = t4.z; qreg[i * 4 + 3] = t4.w;
        }
    }
    __syncthreads();
    for (int k = 0; k < S; k++) {
        float s = 0.0f;
        #pragma unroll
        for (int d4 = 0; d4 < 16; d4++) {
            float4 kv = *(const float4*)&KV[k][d4 * 4];
            s += qreg[d4 * 4 + 0] * kv.x + qreg[d4 * 4 + 1] * kv.y
               + qreg[d4 * 4 + 2] * kv.z + qreg[d4 * 4 + 3] * kv.w;
        }
        sc[tid][k] = padS[k] ? -1e9f : (s * 0.125f);
    }
    float mx = -INFINITY;
    for (int k = 0; k < S; k++) mx = fmaxf(mx, sc[tid][k]);
    float sum = 0.0f;
    for (int k = 0; k < S; k++) { float e = expf(sc[tid][k] - mx); sc[tid][k] = e; sum += e; }
    for (int k = 0; k < S; k++) sc[tid][k] = sc[tid][k] / sum;
    __syncthreads();
    {
        double a = 0.0;
        for (int q2 = 0; q2 < S; q2++) a += (double)sc[q2][tid];
        colsum[(long)(b * Hn + h) * S + tid] = (float)a;
    }
}

// ---------------------------------------------------------------- MFMA attention (batched passes)
__global__ __launch_bounds__(256)
void attn_mfma_kernel(u16* qb, const u16* __restrict__ kb, const u16* __restrict__ vb,
                      const int* __restrict__ toks, const int* __restrict__ mtok,
                      float* __restrict__ colsum) {
    __shared__ u16 pool[18432];          // Qs[128][72] | Ks[128][72] ; Ps[128][136] aliases
    __shared__ u16 Vt[64 * 136];
    __shared__ float colsLds[4][128];
    __shared__ u32 padF[128];
    u16* Qs = pool;
    u16* Ks = pool + 9216;
    u16* Ps = pool;

    const int gb = blockIdx.x >> 3, h = blockIdx.x & 7;
    const int tid = threadIdx.x;
    const int w = tid >> 6, l = tid & 63;
    const long base = (long)gb * S * D + h * 64;
    const int* tsrc = (gb < B) ? (toks + (long)gb * S) : (mtok + (long)(gb - B) * S);

    for (int j = tid; j < 1024; j += 256) {
        int r = j >> 3, c = j & 7;
        uint4 uq = *(const uint4*)(qb + base + (long)r * D + c * 8);
        uint4 uk = *(const uint4*)(kb + base + (long)r * D + c * 8);
        uint4 uv = *(const uint4*)(vb + base + (long)r * D + c * 8);
        *(uint4*)(Qs + r * 72 + c * 8) = uq;
        *(uint4*)(Ks + r * 72 + c * 8) = uk;
        u16 vv[8]; *(uint4*)vv = uv;
        #pragma unroll
        for (int t = 0; t < 8; t++) Vt[(c * 8 + t) * 136 + r] = vv[t];
    }
    if (tid < 128) padF[tid] = (tsrc[tid] == 0) ? 1u : 0u;
    __syncthreads();

    const int rowB = w * 32;
    f32x4 acc[2][8];
    #pragma unroll
    for (int mi = 0; mi < 2; mi++)
        #pragma unroll
        for (int ni = 0; ni < 8; ni++) { f32x4 z = {0.f, 0.f, 0.f, 0.f}; acc[mi][ni] = z; }
    #pragma unroll
    for (int ks = 0; ks < 2; ks++) {
        bf16x8 a0 = *(const bf16x8*)(Qs + (rowB + (l & 15)) * 72 + ks * 32 + (l >> 4) * 8);
        bf16x8 a1 = *(const bf16x8*)(Qs + (rowB + 16 + (l & 15)) * 72 + ks * 32 + (l >> 4) * 8);
        #pragma unroll
        for (int ni = 0; ni < 8; ni++) {
            bf16x8 bv = *(const bf16x8*)(Ks + (ni * 16 + (l & 15)) * 72 + ks * 32 + (l >> 4) * 8);
            acc[0][ni] = __builtin_amdgcn_mfma_f32_16x16x32_bf16(a0, bv, acc[0][ni], 0, 0, 0);
            acc[1][ni] = __builtin_amdgcn_mfma_f32_16x16x32_bf16(a1, bv, acc[1][ni], 0, 0, 0);
        }
    }
    float pf[8];
    #pragma unroll
    for (int ni = 0; ni < 8; ni++) pf[ni] = padF[ni * 16 + (l & 15)] ? 1.0f : 0.0f;
    #pragma unroll
    for (int mi = 0; mi < 2; mi++)
        #pragma unroll
        for (int ni = 0; ni < 8; ni++)
            #pragma unroll
            for (int r = 0; r < 4; r++) {
                float v = acc[mi][ni][r] * 0.125f;
                acc[mi][ni][r] = (pf[ni] != 0.0f) ? -1e9f : v;
            }
    #pragma unroll
    for (int mi = 0; mi < 2; mi++)
        #pragma unroll
        for (int r = 0; r < 4; r++) {
            float m = -INFINITY;
            #pragma unroll
            for (int ni = 0; ni < 8; ni++) m = fmaxf(m, acc[mi][ni][r]);
            m = fmaxf(m, __shfl_xor(m, 1)); m = fmaxf(m, __shfl_xor(m, 2));
            m = fmaxf(m, __shfl_xor(m, 4)); m = fmaxf(m, __shfl_xor(m, 8));
            float s = 0.0f;
            #pragma unroll
            for (int ni = 0; ni < 8; ni++) { float e = expf(acc[mi][ni][r] - m); acc[mi][ni][r] = e; s += e; }
            s += __shfl_xor(s, 1); s += __shfl_xor(s, 2);
            s += __shfl_xor(s, 4); s += __shfl_xor(s, 8);
            float inv = 1.0f / s;
            #pragma unroll
            for (int ni = 0; ni < 8; ni++) acc[mi][ni][r] *= inv;
        }
    float cs[8];
    #pragma unroll
    for (int ni = 0; ni < 8; ni++) {
        float s = 0.0f;
        #pragma unroll
        for (int mi = 0; mi < 2; mi++)
            #pragma unroll
            for (int r = 0; r < 4; r++) s += acc[mi][ni][r];
        s += __shfl_xor(s, 16); s += __shfl_xor(s, 32);
        cs[ni] = s;
    }
    __syncthreads();
    if (l < 16)
        #pragma unroll
        for (int ni = 0; ni < 8; ni++) colsLds[w][ni * 16 + l] = cs[ni];
    #pragma unroll
    for (int mi = 0; mi < 2; mi++)
        #pragma unroll
        for (int ni = 0; ni < 8; ni++)
            #pragma unroll
            for (int r = 0; r < 4; r++)
                Ps[(rowB + mi * 16 + (l >> 4) * 4 + r) * 136 + ni * 16 + (l & 15)] =
                    f2b(acc[mi][ni][r]);
    __syncthreads();
    if (tid < 128) {
        float s = colsLds[0][tid] + colsLds[1][tid] + colsLds[2][tid] + colsLds[3][tid];
        colsum[((long)gb * H + h) * S + tid] = s;
    }
    f32x4 o[2][4];
    #pragma unroll
    for (int mi = 0; mi < 2; mi++)
        #pragma unroll
        for (int n = 0; n < 4; n++) { f32x4 z = {0.f, 0.f, 0.f, 0.f}; o[mi][n] = z; }
    #pragma unroll
    for (int ks = 0; ks < 4; ks++) {
        bf16x8 p0 = *(const bf16x8*)(Ps + (rowB + (l & 15)) * 136 + ks * 32 + (l >> 4) * 8);
        bf16x8 p1 = *(const bf16x8*)(Ps + (rowB + 16 + (l & 15)) * 136 + ks * 32 + (l >> 4) * 8);
        #pragma unroll
        for (int n = 0; n < 4; n++) {
            bf16x8 bv = *(const bf16x8*)(Vt + (n * 16 + (l & 15)) * 136 + ks * 32 + (l >> 4) * 8);
            o[0][n] = __builtin_amdgcn_mfma_f32_16x16x32_bf16(p0, bv, o[0][n], 0, 0, 0);
            o[1][n] = __builtin_amdgcn_mfma_f32_16x16x32_bf16(p1, bv, o[1][n], 0, 0, 0);
        }
    }
    #pragma unroll
    for (int mi = 0; mi < 2; mi++)
        #pragma unroll
        for (int n = 0; n < 4; n++) {
            const int col = n * 16 + (l & 15);
            #pragma unroll
            for (int r = 0; r < 4; r++) {
                const int row = rowB + mi * 16 + (l >> 4) * 4 + r;
                qb[base + (long)row * D + col] = f2b(o[mi][n][r]);
            }
        }
}

// ---------------------------------------------------------------- creat_mask
__global__ __launch_bounds__(128)
void creat_mask_kernel(const float* __restrict__ colpart, const int* __restrict__ toks,
                       int* __restrict__ mtok, float* __restrict__ out) {
    __shared__ float colS[S];
    __shared__ int   j0s, kks;
    const int b = blockIdx.x, j = threadIdx.x;
    float c = colpart[(long)(b * AH + 0) * S + j] + colpart[(long)(b * AH + 1) * S + j];
    colS[j] = c;
    int tk = toks[b * S + j];
    __syncthreads();
    if (j == 0) {
        int j0 = S;
        for (int i = 0; i < S; i++) if (colS[i] == 0.0f) { j0 = i; break; }
        int kk = (j0 < S) ? (int)ceilf(0.2f * (float)j0) : 0;
        j0s = j0; kks = kk;
    }
    __syncthreads();
    const int j0 = j0s, kk = kks;
    float vj = (j < j0) ? colS[j] : INFINITY;
    int rank = 0;
    for (int i = 0; i < S; i++) {
        float vi = (i < j0) ? colS[i] : INFINITY;
        if (vi < vj || (vi == vj && i < j)) rank++;
    }
    int mt = (rank >= kk) ? tk : 0;
    mtok[b * S + j] = mt;
    out[OUT_TOK + b * S + j]  = (float)tk;
    out[OUT_MTOK + b * S + j] = (float)mt;
}

// ---------------------------------------------------------------- LayerNorm: y (pre-LN bf16) -> xb (bf16)
__global__ __launch_bounds__(256)
void ln_kernel(const u16* __restrict__ y, u16* __restrict__ xb) {
    const int row  = blockIdx.x * 4 + (threadIdx.x >> 6);
    const int lane = threadIdx.x & 63;
    const u16* r = y + (long)row * D;
    uint4 u = *(const uint4*)(r + lane * 8);
    u32 uu[4] = {u.x, u.y, u.z, u.w};
    float v[8];
    #pragma unroll
    for (int t = 0; t < 4; t++) {
        v[t * 2]     = b2f((u16)(uu[t] & 0xffffu));
        v[t * 2 + 1] = b2f((u16)(uu[t] >> 16));
    }
    float s = 0.0f, q = 0.0f;
    #pragma unroll
    for (int t = 0; t < 8; t++) { s += v[t]; q += v[t] * v[t]; }
    #pragma unroll
    for (int off = 32; off; off >>= 1) { s += __shfl_xor(s, off); q += __shfl_xor(q, off); }
    float m   = s * (1.0f / 512.0f);
    float var = q * (1.0f / 512.0f) - m * m;
    float inv = 1.0f / sqrtf(var + 1e-5f);
    u16 o[8];
    #pragma unroll
    for (int t = 0; t < 8; t++) o[t] = f2b((v[t] - m) * inv);
    *(uint4*)(xb + (long)row * D + lane * 8) = *(uint4*)o;
}

// ---------------------------------------------------------------- scores output (all layers, pass-0 half)
__global__ void score_all_kernel(const float* __restrict__ ascl, float* __restrict__ out) {
    int idx = blockIdx.x * 256 + threadIdx.x;     // over L*B*S = 49152
    if (idx >= L * B * S) return;
    int l   = idx / (B * S);
    int rem = idx - l * (B * S);
    int b = rem >> 7, j = rem & 127;
    const float* p = ascl + (long)l * ASCL_STRIDE + (long)b * H * S + j;
    float s = 0.0f;
    #pragma unroll
    for (int h = 0; h < H; h++) s += p[(long)h * S];
    out[OUT_SCORES + idx] = s;
}

// ---------------------------------------------------------------- pre-head reduce/pack
__global__ void reduce1_kernel(const float* __restrict__ parts, const float* __restrict__ b1,
                               float* __restrict__ o) {
    int idx = blockIdx.x * 256 + threadIdx.x;
    if (idx >= 128 * 1024) return;
    float s = 0.0f;
    for (int z = 0; z < 64; z++) s += parts[(long)z * 128 * 1024 + idx];
    s += b1[idx & 1023];
    o[idx] = fmaxf(s, 0.0f);
}

__global__ void pack_out_kernel(const float* __restrict__ ph3, float* __restrict__ out) {
    int idx = blockIdx.x * 256 + threadIdx.x;
    if (idx >= 128 * 128) return;
    int row = idx >> 7, col = idx & 127;
    long base = (row < 64) ? (OUT_OUT1 + (long)row * 128) : (OUT_OUTM + (long)(row - 64) * 128);
    out[base + col] = ph3[idx];
}

// ================================================================ launch
extern "C" void kernel_launch(void* const* d_in, const int* in_sizes, int n_in,
                              void* d_out, int out_size, void* d_ws, size_t ws_size,
                              hipStream_t stream) {
    const int*   toks = (const int*)d_in[0];
    const float* emb  = (const float*)d_in[1];
    const float* aWQ  = (const float*)d_in[2];
    const float* aWK  = (const float*)d_in[3];
    const float* tWQ  = (const float*)d_in[8];
    const float* tWK  = (const float*)d_in[9];
    const float* tWV  = (const float*)d_in[10];
    const float* tFC  = (const float*)d_in[11];
    const float* tF1  = (const float*)d_in[12];
    const float* tF2  = (const float*)d_in[13];
    const float* pW1  = (const float*)d_in[14];
    const float* pb1  = (const float*)d_in[15];
    const float* pW2  = (const float*)d_in[16];
    const float* pb2  = (const float*)d_in[17];
    const float* pW3  = (const float*)d_in[18];
    const float* pb3  = (const float*)d_in[19];
    float* out = (float*)d_out;

    float* ws   = (float*)d_ws;
    float* pe   = ws + OFF_PE;
    float* ascl = ws + OFF_ASCL;
    float* colp = ws + OFF_COLP;
    int*   mtok = (int*)(ws + OFF_MTOK);
    float* x    = ws + OFF_X;          // fp32 clean embedding (mask path only)
    u16*   xb   = (u16*)(ws + OFF_XB); // [BS2][D] bf16 canonical state
    u16*   yb   = (u16*)(ws + OFF_Y);  // [BS2][D] bf16 pre-LN scratch
    u16*   qb   = (u16*)(ws + OFF_QB);
    u16*   kb   = (u16*)(ws + OFF_KB);
    u16*   vb   = (u16*)(ws + OFF_VB);
    u16*   tb   = (u16*)(ws + OFF_TB); // [BS2][DFF] bf16
    u16*   wAll = (u16*)(ws + OFF_W);

    // phase-disjoint aliases of the TB region
    float* maq   = ws + OFF_TB;                 // mask encoder q [BS][128] fp32
    float* mak   = maq + (long)BS * 128;
    float* parts = ws + OFF_TB;                 // pre-head partials 64 x [128][1024]
    float* ph1o  = parts + 8388608;
    float* ph2o  = ph1o + 131072;
    float* ph3o  = ph2o + 65536;

    // --- setup: pos-enc, all-layer weight conversion, clean embedding
    pe_kernel<<<128, 256, 0, stream>>>(pe);
    wconv_all<<<6 * 3072, 256, 0, stream>>>(tWQ, tWK, tWV, tFC, tF1, tF2, wAll);
    embed_dual<<<2048, 256, 0, stream>>>(toks, emb, pe, x, xb);

    // --- mask-generating encoder (fp32; only the attention matrix is consumed)
    gemm64_qkv<<<dim3(BS / 64, 2, 2), 256, 0, stream>>>(
        x, aWQ, aWK, nullptr, maq, mak, nullptr, BS, AH * DK, D);
    attn_kernel<<<B * AH, 128, 0, stream>>>(maq, mak, toks, colp, AH);
    creat_mask_kernel<<<B, 128, 0, stream>>>(colp, toks, mtok, out);
    embed_dual<<<2048, 256, 0, stream>>>(mtok, emb, pe, nullptr, xb + (long)BS * D);

    // --- 6 layers, both passes batched; bf16 state xb, bf16 pre-LN scratch yb
    for (int l = 0; l < L; l++) {
        const u16* wq = wAll + (long)l * WSTRIDE;
        const u16* wk = wq + 262144;
        const u16* wv = wq + 524288;
        const u16* wo = wq + 786432;
        const u16* w1 = wq + 1048576;
        const u16* w2 = wq + 2097152;
        gemm_qkv_b<<<dim3(BS2 / 128, D / 128, 3), 256, 0, stream>>>(
            xb, wq, wk, wv, qb, kb, vb, BS2, D, D);
        attn_mfma_kernel<<<2 * B * H, 256, 0, stream>>>(
            qb, kb, vb, toks, mtok, ascl + (long)l * ASCL_STRIDE);
        gemm_resid_b<<<dim3(BS2 / 128, D / 128), 256, 0, stream>>>(qb, wo, yb, xb, BS2, D, D);
        ln_kernel<<<BS2 / 4, 256, 0, stream>>>(yb, xb);
        gemm_relu_b<<<dim3(BS2 / 128, DFF / 128), 256, 0, stream>>>(xb, w1, tb, BS2, DFF, D);
        gemm_resid_b<<<dim3(BS2 / 128, D / 128), 256, 0, stream>>>(tb, w2, yb, xb, BS2, D, DFF);
        ln_kernel<<<BS2 / 4, 256, 0, stream>>>(yb, xb);
    }
    score_all_kernel<<<192, 256, 0, stream>>>(ascl, out);

    // --- pre_head: MFMA split-K over pW1 (xb holds bf16 h ‖ hm)
    gemm_ph1<<<dim3(8, 64), 256, 0, stream>>>(xb, xb + (long)BS * D, pW1, parts, 1024);
    reduce1_kernel<<<512, 256, 0, stream>>>(parts, pb1, ph1o);
    gemm64<4><<<dim3(2, 8), 256, 0, stream>>>(ph1o, pW2, ph2o, pb2, 128, 512, 1024);
    gemm64<3><<<dim3(2, 2), 256, 0, stream>>>(ph2o, pW3, ph3o, pb3, 128, 128, 512);
    pack_out_kernel<<<64, 256, 0, stream>>>(ph3o, out);
}

// Round 13
// 1448.125 us; speedup vs baseline: 1.2495x; 1.0163x over previous
//
#include <hip/hip_runtime.h>
#include <hip/hip_bf16.h>
#include <math.h>

using u16 = unsigned short;
using u32 = unsigned int;

// Problem constants
constexpr int B   = 64;
constexpr int S   = 128;
constexpr int D   = 512;
constexpr int H   = 8;
constexpr int DK  = 64;
constexpr int L   = 6;
constexpr int DFF = 2048;
constexpr int AH  = 2;
constexpr int BS  = B * S;          // 8192
constexpr int BS2 = 2 * BS;         // 16384 (both passes batched)

// Output layout (fp32 elements)
constexpr long OUT_TOK    = 0;
constexpr long OUT_OUT1   = 8192;
constexpr long OUT_MTOK   = 16384;
constexpr long OUT_OUTM   = 24576;
constexpr long OUT_SCORES = 32768;

// Workspace layout (float units). ~226 MB of ~1 GiB ws
constexpr long OFF_PE   = 0;             // 65536
constexpr long OFF_ASCL = 65536;         // 6 layers x 2*B*H*S = 786432
constexpr long OFF_COLP = 851968;        // B*AH*S = 16384
constexpr long OFF_MTOK = 868352;        // 8192 ints
constexpr long OFF_X    = 876544;        // BS2*D fp32 (mask path uses first half)
constexpr long OFF_XB   = 9265152;       // BS2*D bf16 (canonical state)
constexpr long OFF_Y    = 13459456;      // BS2*D bf16 pre-LN scratch
constexpr long OFF_QB   = 17653760;      // BS2*D bf16
constexpr long OFF_KB   = 21848064;      // BS2*D bf16
constexpr long OFF_VB   = 26042368;      // BS2*D bf16
constexpr long OFF_TB   = 30236672;      // BS2*DFF bf16 (alias: mask q/k, pre-head parts)
constexpr long OFF_W    = 47013888;      // 6 layers x 3,145,728 bf16
constexpr long WSTRIDE  = 3145728;       // bf16 elems per layer
constexpr long ASCL_STRIDE = 131072;     // per-layer colsum floats (2*B*H*S)

typedef __attribute__((ext_vector_type(8))) short bf16x8;
typedef __attribute__((ext_vector_type(4))) float f32x4;

__device__ __forceinline__ float b2f(u16 u) {
    union { u32 i; float f; } v; v.i = ((u32)u) << 16; return v.f;
}
__device__ __forceinline__ u16 f2b(float f) {      // RNE f32 -> bf16
    union { float f; u32 i; } v; v.f = f;
    u32 r = v.i + 0x7fffu + ((v.i >> 16) & 1u);
    return (u16)(r >> 16);
}

#define GLOAD_LDS16(g, l) __builtin_amdgcn_global_load_lds(                        \
    (const __attribute__((address_space(1))) u32*)(const void*)(g),               \
    (__attribute__((address_space(3))) u32*)(void*)(l), 16, 0, 0)

// ---------------------------------------------------------------- pos enc
__global__ void pe_kernel(float* __restrict__ pe) {
    int idx = blockIdx.x * 256 + threadIdx.x;
    if (idx >= S * (D / 2)) return;
    int s = idx >> 8;
    int i = idx & 255;
    const float CPE = (float)(-9.210340371976184 / 512.0);
    float div = expf((float)(2 * i) * CPE);
    float ang = (float)s * div;
    pe[(long)s * D + 2 * i]     = sinf(ang);
    pe[(long)s * D + 2 * i + 1] = cosf(ang);
}

// ---------------------------------------------------------------- embed + pe (optional fp32 + bf16 out)
__global__ void embed_dual(const int* __restrict__ toks, const float* __restrict__ emb,
                           const float* __restrict__ pe, float* x,
                           u16* __restrict__ xb) {
    int i8 = blockIdx.x * 256 + threadIdx.x;      // over BS*D/8 = 524288
    if (i8 >= BS * D / 8) return;
    int row = i8 >> 6;
    int c8  = i8 & 63;
    int s   = row & (S - 1);
    int t   = toks[row];
    float4 e0 = *(const float4*)(emb + (long)t * D + c8 * 8);
    float4 e1 = *(const float4*)(emb + (long)t * D + c8 * 8 + 4);
    float4 p0 = *(const float4*)(pe + (long)s * D + c8 * 8);
    float4 p1 = *(const float4*)(pe + (long)s * D + c8 * 8 + 4);
    float4 o0, o1;
    o0.x = e0.x + p0.x; o0.y = e0.y + p0.y; o0.z = e0.z + p0.z; o0.w = e0.w + p0.w;
    o1.x = e1.x + p1.x; o1.y = e1.y + p1.y; o1.z = e1.z + p1.z; o1.w = e1.w + p1.w;
    if (x) {
        *(float4*)(x + (long)i8 * 8)     = o0;
        *(float4*)(x + (long)i8 * 8 + 4) = o1;
    }
    u16 u[8] = {f2b(o0.x), f2b(o0.y), f2b(o0.z), f2b(o0.w), f2b(o1.x), f2b(o1.y), f2b(o1.z), f2b(o1.w)};
    *(uint4*)(xb + (long)i8 * 8) = *(uint4*)u;
}

// ---------------------------------------------------------------- all-layer weight transpose+convert
__global__ __launch_bounds__(256)
void wconv_all(const float* __restrict__ tWQ, const float* __restrict__ tWK,
               const float* __restrict__ tWV, const float* __restrict__ tFC,
               const float* __restrict__ tF1, const float* __restrict__ tF2,
               u16* __restrict__ wAll) {
    __shared__ float t[32][33];
    const int lyr = blockIdx.x / 3072;
    const int bid = blockIdx.x % 3072;
    u16* base = wAll + (long)lyr * WSTRIDE;
    const float* src; u16* dst; int KK, NN, tk, tn;
    if (bid < 1024) {
        int which = bid >> 8, tt = bid & 255;
        src = (which == 0 ? tWQ : which == 1 ? tWK : which == 2 ? tWV : tFC) + (long)lyr * D * D;
        dst = base + (long)which * 262144;
        KK = 512; NN = 512; tk = tt >> 4; tn = tt & 15;
    } else if (bid < 2048) {
        int tt = bid - 1024;
        src = tF1 + (long)lyr * D * DFF; dst = base + 1048576;
        KK = 512; NN = 2048; tk = tt >> 6; tn = tt & 63;
    } else {
        int tt = bid - 2048;
        src = tF2 + (long)lyr * DFF * D; dst = base + 2097152;
        KK = 2048; NN = 512; tk = tt >> 4; tn = tt & 15;
    }
    int ty = threadIdx.x >> 5, tx = threadIdx.x & 31;
    #pragma unroll
    for (int i = 0; i < 4; i++)
        t[ty + i * 8][tx] = src[(long)(tk * 32 + ty + i * 8) * NN + tn * 32 + tx];
    __syncthreads();
    #pragma unroll
    for (int i = 0; i < 4; i++)
        dst[(long)(tn * 32 + ty + i * 8) * KK + tk * 32 + tx] = f2b(t[tx][ty + i * 8]);
}

// ---------------------------------------------------------------- bf16 MFMA GEMM core (128x128, 4 waves)
// BK=64 via TWO independent 128x32 panels per barrier pair.
// EPI: 0 none, 2 relu, 3 +bf16 residual X[M,N]. OUTB: bf16 output.
template<int EPI, int OUTB>
__device__ __forceinline__ void gemm_core(
        const u16* __restrict__ A, const u16* __restrict__ Wt,
        float* C, u16* Cb, const u16* __restrict__ X,
        int M, int N, int K, int m0, int n0) {
    __shared__ u16 As[2][128 * 32];
    __shared__ u16 Bs[2][128 * 32];
    const int tid = threadIdx.x;
    const int w = tid >> 6, l = tid & 63;
    const int wr = (w >> 1) * 64, wc = (w & 1) * 64;
    f32x4 acc[4][4];
    #pragma unroll
    for (int i = 0; i < 4; i++)
        #pragma unroll
        for (int j = 0; j < 4; j++) { f32x4 z = {0.f, 0.f, 0.f, 0.f}; acc[i][j] = z; }

    const int srow = w * 32 + (l >> 2);
    const int scol = (l & 3) * 8;
    const u16* gA = A + (long)(m0 + srow) * K + scol;
    const u16* gB = Wt + (long)(n0 + srow) * K + scol;

    for (int k0 = 0; k0 < K; k0 += 64) {
        #pragma unroll
        for (int p = 0; p < 2; p++) {
            GLOAD_LDS16(gA + k0 + p * 32,               As[p] + w * 1024);
            GLOAD_LDS16(gA + (long)16 * K + k0 + p * 32, As[p] + w * 1024 + 512);
            GLOAD_LDS16(gB + k0 + p * 32,               Bs[p] + w * 1024);
            GLOAD_LDS16(gB + (long)16 * K + k0 + p * 32, Bs[p] + w * 1024 + 512);
        }
        __syncthreads();
        #pragma unroll
        for (int p = 0; p < 2; p++) {
            bf16x8 aF[4], bF[4];
            #pragma unroll
            for (int mi = 0; mi < 4; mi++)
                aF[mi] = *(const bf16x8*)(As[p] + (wr + mi * 16 + (l & 15)) * 32 + (l >> 4) * 8);
            #pragma unroll
            for (int ni = 0; ni < 4; ni++)
                bF[ni] = *(const bf16x8*)(Bs[p] + (wc + ni * 16 + (l & 15)) * 32 + (l >> 4) * 8);
            #pragma unroll
            for (int mi = 0; mi < 4; mi++)
                #pragma unroll
                for (int ni = 0; ni < 4; ni++)
                    acc[mi][ni] = __builtin_amdgcn_mfma_f32_16x16x32_bf16(aF[mi], bF[ni], acc[mi][ni], 0, 0, 0);
        }
        __syncthreads();
    }

    #pragma unroll
    for (int mi = 0; mi < 4; mi++) {
        #pragma unroll
        for (int ni = 0; ni < 4; ni++) {
            const int col = n0 + wc + ni * 16 + (l & 15);
            #pragma unroll
            for (int r = 0; r < 4; r++) {
                const int row = m0 + wr + mi * 16 + (l >> 4) * 4 + r;
                const long idx = (long)row * N + col;
                float v = acc[mi][ni][r];
                if (EPI == 3) v += b2f(X[idx]);
                if (EPI == 2) v = fmaxf(v, 0.0f);
                if (OUTB) Cb[idx] = f2b(v);
                else      C[idx]  = v;
            }
        }
    }
}

// ---------------------------------------------------------------- bf16 MFMA GEMM core (256x128, 8 waves)
// Same per-wave math as gemm_core; wave pair (w>>1) selects the 64-row group.
template<int EPI>
__device__ __forceinline__ void gemm_core256(
        const u16* __restrict__ A, const u16* __restrict__ Wt, u16* __restrict__ Cb,
        int M, int N, int K, int m0, int n0) {
    __shared__ u16 As[2][256 * 32];
    __shared__ u16 Bs[2][128 * 32];
    const int tid = threadIdx.x;
    const int w = tid >> 6, l = tid & 63;         // w in 0..7
    const int wr = (w >> 1) * 64, wc = (w & 1) * 64;
    f32x4 acc[4][4];
    #pragma unroll
    for (int i = 0; i < 4; i++)
        #pragma unroll
        for (int j = 0; j < 4; j++) { f32x4 z = {0.f, 0.f, 0.f, 0.f}; acc[i][j] = z; }

    const int arow = w * 32 + (l >> 2);           // A staging: wave covers 32 rows
    const int brow = w * 16 + (l >> 2);           // B staging: wave covers 16 rows
    const int scol = (l & 3) * 8;
    const u16* gA = A + (long)(m0 + arow) * K + scol;
    const u16* gB = Wt + (long)(n0 + brow) * K + scol;

    for (int k0 = 0; k0 < K; k0 += 64) {
        #pragma unroll
        for (int p = 0; p < 2; p++) {
            GLOAD_LDS16(gA + k0 + p * 32,               As[p] + w * 1024);
            GLOAD_LDS16(gA + (long)16 * K + k0 + p * 32, As[p] + w * 1024 + 512);
            GLOAD_LDS16(gB + k0 + p * 32,               Bs[p] + w * 512);
        }
        __syncthreads();
        #pragma unroll
        for (int p = 0; p < 2; p++) {
            bf16x8 aF[4], bF[4];
            #pragma unroll
            for (int mi = 0; mi < 4; mi++)
                aF[mi] = *(const bf16x8*)(As[p] + (wr + mi * 16 + (l & 15)) * 32 + (l >> 4) * 8);
            #pragma unroll
            for (int ni = 0; ni < 4; ni++)
                bF[ni] = *(const bf16x8*)(Bs[p] + (wc + ni * 16 + (l & 15)) * 32 + (l >> 4) * 8);
            #pragma unroll
            for (int mi = 0; mi < 4; mi++)
                #pragma unroll
                for (int ni = 0; ni < 4; ni++)
                    acc[mi][ni] = __builtin_amdgcn_mfma_f32_16x16x32_bf16(aF[mi], bF[ni], acc[mi][ni], 0, 0, 0);
        }
        __syncthreads();
    }

    #pragma unroll
    for (int mi = 0; mi < 4; mi++) {
        #pragma unroll
        for (int ni = 0; ni < 4; ni++) {
            const int col = n0 + wc + ni * 16 + (l & 15);
            #pragma unroll
            for (int r = 0; r < 4; r++) {
                const int row = m0 + wr + mi * 16 + (l >> 4) * 4 + r;
                const long idx = (long)row * N + col;
                float v = acc[mi][ni][r];
                if (EPI == 2) v = fmaxf(v, 0.0f);
                Cb[idx] = f2b(v);
            }
        }
    }
}

__global__ __launch_bounds__(512)
void gemm_qkv_b(const u16* __restrict__ A, const u16* wq, const u16* wk, const u16* wv,
                u16* qb, u16* kb, u16* vb, int M, int N, int K) {
    const u16* Wt = blockIdx.z == 0 ? wq : blockIdx.z == 1 ? wk : wv;
    u16* Cb       = blockIdx.z == 0 ? qb : blockIdx.z == 1 ? kb : vb;
    gemm_core256<0>(A, Wt, Cb, M, N, K, blockIdx.x * 256, blockIdx.y * 128);
}
__global__ __launch_bounds__(512)
void gemm_relu_b(const u16* __restrict__ A, const u16* __restrict__ Wt,
                 u16* Cb, int M, int N, int K) {
    gemm_core256<2>(A, Wt, Cb, M, N, K, blockIdx.x * 256, blockIdx.y * 128);
}
__global__ __launch_bounds__(256)
void gemm_resid_b(const u16* __restrict__ A, const u16* __restrict__ Wt,
                  u16* Yb, const u16* __restrict__ X, int M, int N, int K) {
    gemm_core<3, 1>(A, Wt, nullptr, Yb, X, M, N, K, blockIdx.x * 128, blockIdx.y * 128);
}

// ---------------------------------------------------------------- fp32 GEMM (pre-head tail)
template<int EPI>
__global__ __launch_bounds__(256)
void gemm64(const float* __restrict__ A, const float* __restrict__ W,
            float* C, const float* X, int M, int N, int K) {
    __shared__ float As[32][68];
    __shared__ float Ws[32][64];
    const int m0 = blockIdx.x * 64, n0 = blockIdx.y * 64;
    const int tid  = threadIdx.x;
    const int tr   = tid >> 4, tc = tid & 15;
    const int arow = tid >> 3, acg = tid & 7;
    const int wrow = tid >> 4, wcg = tid & 15;
    float acc[4][4] = {};
    for (int k0 = 0; k0 < K; k0 += 32) {
        float4 a0 = *(const float4*)(A + (long)(m0 + arow) * K + k0 + acg * 4);
        float4 a1 = *(const float4*)(A + (long)(m0 + arow + 32) * K + k0 + acg * 4);
        float4 w0 = *(const float4*)(W + (long)(k0 + wrow) * N + n0 + wcg * 4);
        float4 w1 = *(const float4*)(W + (long)(k0 + wrow + 16) * N + n0 + wcg * 4);
        As[acg * 4 + 0][arow] = a0.x; As[acg * 4 + 1][arow] = a0.y;
        As[acg * 4 + 2][arow] = a0.z; As[acg * 4 + 3][arow] = a0.w;
        As[acg * 4 + 0][arow + 32] = a1.x; As[acg * 4 + 1][arow + 32] = a1.y;
        As[acg * 4 + 2][arow + 32] = a1.z; As[acg * 4 + 3][arow + 32] = a1.w;
        *(float4*)&Ws[wrow][wcg * 4]      = w0;
        *(float4*)&Ws[wrow + 16][wcg * 4] = w1;
        __syncthreads();
        #pragma unroll
        for (int kk = 0; kk < 32; kk++) {
            float4 av = *(const float4*)&As[kk][tr * 4];
            float4 bv = *(const float4*)&Ws[kk][tc * 4];
            acc[0][0] += av.x * bv.x; acc[0][1] += av.x * bv.y; acc[0][2] += av.x * bv.z; acc[0][3] += av.x * bv.w;
            acc[1][0] += av.y * bv.x; acc[1][1] += av.y * bv.y; acc[1][2] += av.y * bv.z; acc[1][3] += av.y * bv.w;
            acc[2][0] += av.z * bv.x; acc[2][1] += av.z * bv.y; acc[2][2] += av.z * bv.z; acc[2][3] += av.z * bv.w;
            acc[3][0] += av.w * bv.x; acc[3][1] += av.w * bv.y; acc[3][2] += av.w * bv.z; acc[3][3] += av.w * bv.w;
        }
        __syncthreads();
    }
    #pragma unroll
    for (int i = 0; i < 4; i++) {
        int row = m0 + tr * 4 + i;
        #pragma unroll
        for (int j = 0; j < 4; j++) {
            int col = n0 + tc * 4 + j;
            long idx = (long)row * N + col;
            float v = acc[i][j];
            if (EPI == 1) v += X[idx];
            if (EPI == 3 || EPI == 4) v += X[col];
            if (EPI == 2 || EPI == 4) v = fmaxf(v, 0.0f);
            C[idx] = v;
        }
    }
}

// QKV merged fp32 (mask encoder)
__global__ __launch_bounds__(256)
void gemm64_qkv(const float* __restrict__ A,
                const float* __restrict__ WQ, const float* __restrict__ WK, const float* __restrict__ WV,
                float* q, float* k, float* v, int M, int N, int K) {
    __shared__ float As[32][68];
    __shared__ float Ws[32][64];
    const float* W = (blockIdx.z == 0) ? WQ : (blockIdx.z == 1) ? WK : WV;
    float*       C = (blockIdx.z == 0) ? q  : (blockIdx.z == 1) ? k  : v;
    const int m0 = blockIdx.x * 64, n0 = blockIdx.y * 64;
    const int tid  = threadIdx.x;
    const int tr   = tid >> 4, tc = tid & 15;
    const int arow = tid >> 3, acg = tid & 7;
    const int wrow = tid >> 4, wcg = tid & 15;
    float acc[4][4] = {};
    for (int k0 = 0; k0 < K; k0 += 32) {
        float4 a0 = *(const float4*)(A + (long)(m0 + arow) * K + k0 + acg * 4);
        float4 a1 = *(const float4*)(A + (long)(m0 + arow + 32) * K + k0 + acg * 4);
        float4 w0 = *(const float4*)(W + (long)(k0 + wrow) * N + n0 + wcg * 4);
        float4 w1 = *(const float4*)(W + (long)(k0 + wrow + 16) * N + n0 + wcg * 4);
        As[acg * 4 + 0][arow] = a0.x; As[acg * 4 + 1][arow] = a0.y;
        As[acg * 4 + 2][arow] = a0.z; As[acg * 4 + 3][arow] = a0.w;
        As[acg * 4 + 0][arow + 32] = a1.x; As[acg * 4 + 1][arow + 32] = a1.y;
        As[acg * 4 + 2][arow + 32] = a1.z; As[acg * 4 + 3][arow + 32] = a1.w;
        *(float4*)&Ws[wrow][wcg * 4]      = w0;
        *(float4*)&Ws[wrow + 16][wcg * 4] = w1;
        __syncthreads();
        #pragma unroll
        for (int kk = 0; kk < 32; kk++) {
            float4 av = *(const float4*)&As[kk][tr * 4];
            float4 bv = *(const float4*)&Ws[kk][tc * 4];
            acc[0][0] += av.x * bv.x; acc[0][1] += av.x * bv.y; acc[0][2] += av.x * bv.z; acc[0][3] += av.x * bv.w;
            acc[1][0] += av.y * bv.x; acc[1][1] += av.y * bv.y; acc[1][2] += av.y * bv.z; acc[1][3] += av.y * bv.w;
            acc[2][0] += av.z * bv.x; acc[2][1] += av.z * bv.y; acc[2][2] += av.z * bv.z; acc[2][3] += av.z * bv.w;
            acc[3][0] += av.w * bv.x; acc[3][1] += av.w * bv.y; acc[3][2] += av.w * bv.z; acc[3][3] += av.w * bv.w;
        }
        __syncthreads();
    }
    #pragma unroll
    for (int i = 0; i < 4; i++)
        #pragma unroll
        for (int j = 0; j < 4; j++)
            C[(long)(m0 + tr * 4 + i) * N + n0 + tc * 4 + j] = acc[i][j];
}

// ---------------------------------------------------------------- pre-head layer-1: MFMA split-K
__global__ __launch_bounds__(256)
void gemm_ph1(const u16* __restrict__ Ah, const u16* __restrict__ Ahm,
              const float* __restrict__ W, float* __restrict__ P, int KC) {
    constexpr int N = 1024, K = 65536;
    __shared__ u16 As[128 * 32];
    __shared__ u16 Bs[128 * 32];
    const int n0 = blockIdx.x * 128;
    const int kbeg = blockIdx.y * KC;
    const int tid = threadIdx.x;
    const int w = tid >> 6, l = tid & 63;
    const int wr = w * 32;
    const int nl = tid >> 1, seg = tid & 1;
    const u16* aptr = (nl < 64 ? Ah + (long)nl * K : Ahm + (long)(nl - 64) * K) + seg * 16;
    const float* wcol = W + n0 + nl;

    f32x4 acc[2][8];
    #pragma unroll
    for (int mi = 0; mi < 2; mi++)
        #pragma unroll
        for (int ni = 0; ni < 8; ni++) { f32x4 z = {0.f, 0.f, 0.f, 0.f}; acc[mi][ni] = z; }

    for (int ks = 0; ks < KC; ks += 32) {
        const int k0 = kbeg + ks;
        uint4 a0 = *(const uint4*)(aptr + k0);
        uint4 a1 = *(const uint4*)(aptr + k0 + 8);
        float wv[16];
        #pragma unroll
        for (int j = 0; j < 16; j++)
            wv[j] = wcol[(long)(k0 + seg * 16 + j) * N];
        __syncthreads();
        *(uint4*)(As + nl * 32 + seg * 16)     = a0;
        *(uint4*)(As + nl * 32 + seg * 16 + 8) = a1;
        u32 pk[8];
        #pragma unroll
        for (int j = 0; j < 8; j++)
            pk[j] = (u32)f2b(wv[2 * j]) | ((u32)f2b(wv[2 * j + 1]) << 16);
        *(uint4*)(Bs + nl * 32 + seg * 16)     = *(uint4*)&pk[0];
        *(uint4*)(Bs + nl * 32 + seg * 16 + 8) = *(uint4*)&pk[4];
        __syncthreads();
        bf16x8 aF0 = *(const bf16x8*)(As + (wr + (l & 15)) * 32 + (l >> 4) * 8);
        bf16x8 aF1 = *(const bf16x8*)(As + (wr + 16 + (l & 15)) * 32 + (l >> 4) * 8);
        #pragma unroll
        for (int ni = 0; ni < 8; ni++) {
            bf16x8 bF = *(const bf16x8*)(Bs + (ni * 16 + (l & 15)) * 32 + (l >> 4) * 8);
            acc[0][ni] = __builtin_amdgcn_mfma_f32_16x16x32_bf16(aF0, bF, acc[0][ni], 0, 0, 0);
            acc[1][ni] = __builtin_amdgcn_mfma_f32_16x16x32_bf16(aF1, bF, acc[1][ni], 0, 0, 0);
        }
    }
    float* Pz = P + (long)blockIdx.y * 128 * N;
    #pragma unroll
    for (int mi = 0; mi < 2; mi++)
        #pragma unroll
        for (int ni = 0; ni < 8; ni++) {
            const int col = n0 + ni * 16 + (l & 15);
            #pragma unroll
            for (int r = 0; r < 4; r++)
                Pz[(long)(wr + mi * 16 + (l >> 4) * 4 + r) * N + col] = acc[mi][ni][r];
        }
}

// ---------------------------------------------------------------- fp32 attention (mask path, colsum only)
__global__ __launch_bounds__(128)
void attn_kernel(const float* __restrict__ Q, const float* __restrict__ K,
                 const int* __restrict__ toks, float* __restrict__ colsum, int Hn) {
    __shared__ float sc[S][129];
    __shared__ float KV[S][DK];
    __shared__ int   padS[S];
    const int b = blockIdx.x / Hn;
    const int h = blockIdx.x % Hn;
    const int stride = Hn * DK;
    const int tid = threadIdx.x;

    for (int idx = tid; idx < S * DK; idx += 128) {
        int r = idx >> 6, c = idx & 63;
        KV[r][c] = K[(long)(b * S + r) * stride + h * DK + c];
    }
    padS[tid] = (toks[b * S + tid] == 0) ? 1 : 0;
    float qreg[DK];
    {
        const float* qp = Q + (long)(b * S + tid) * stride + h * DK;
        #pragma unroll
        for (int i = 0; i < 16; i++) {
            float4 t4 = *(const float4*)(qp + i * 4);
            qreg[i * 4 + 0] = t4.x; qreg[i * 4 + 1] = t4.y;
            qreg[i * 4 + 2] = t4.z; qreg[i * 4 + 3] = t4.w;
        }
    }
    __syncthreads();
    for (int k = 0; k < S; k++) {
        float s = 0.0f;
        #pragma unroll
        for (int d4 = 0; d4 < 16; d4++) {
            float4 kv = *(const float4*)&KV[k][d4 * 4];
            s += qreg[d4 * 4 + 0] * kv.x + qreg[d4 * 4 + 1] * kv.y
               + qreg[d4 * 4 + 2] * kv.z + qreg[d4 * 4 + 3] * kv.w;
        }
        sc[tid][k] = padS[k] ? -1e9f : (s * 0.125f);
    }
    float mx = -INFINITY;
    for (int k = 0; k < S; k++) mx = fmaxf(mx, sc[tid][k]);
    float sum = 0.0f;
    for (int k = 0; k < S; k++) { float e = expf(sc[tid][k] - mx); sc[tid][k] = e; sum += e; }
    for (int k = 0; k < S; k++) sc[tid][k] = sc[tid][k] / sum;
    __syncthreads();
    {
        double a = 0.0;
        for (int q2 = 0; q2 < S; q2++) a += (double)sc[q2][tid];
        colsum[(long)(b * Hn + h) * S + tid] = (float)a;
    }
}

// ---------------------------------------------------------------- MFMA attention (batched passes)
__global__ __launch_bounds__(256)
void attn_mfma_kernel(u16* qb, const u16* __restrict__ kb, const u16* __restrict__ vb,
                      const int* __restrict__ toks, const int* __restrict__ mtok,
                      float* __restrict__ colsum) {
    __shared__ u16 pool[18432];          // Qs[128][72] | Ks[128][72] ; Ps[128][136] aliases
    __shared__ u16 Vt[64 * 136];
    __shared__ float colsLds[4][128];
    __shared__ u32 padF[128];
    u16* Qs = pool;
    u16* Ks = pool + 9216;
    u16* Ps = pool;

    const int gb = blockIdx.x >> 3, h = blockIdx.x & 7;
    const int tid = threadIdx.x;
    const int w = tid >> 6, l = tid & 63;
    const long base = (long)gb * S * D + h * 64;
    const int* tsrc = (gb < B) ? (toks + (long)gb * S) : (mtok + (long)(gb - B) * S);

    for (int j = tid; j < 1024; j += 256) {
        int r = j >> 3, c = j & 7;
        uint4 uq = *(const uint4*)(qb + base + (long)r * D + c * 8);
        uint4 uk = *(const uint4*)(kb + base + (long)r * D + c * 8);
        uint4 uv = *(const uint4*)(vb + base + (long)r * D + c * 8);
        *(uint4*)(Qs + r * 72 + c * 8) = uq;
        *(uint4*)(Ks + r * 72 + c * 8) = uk;
        u16 vv[8]; *(uint4*)vv = uv;
        #pragma unroll
        for (int t = 0; t < 8; t++) Vt[(c * 8 + t) * 136 + r] = vv[t];
    }
    if (tid < 128) padF[tid] = (tsrc[tid] == 0) ? 1u : 0u;
    __syncthreads();

    const int rowB = w * 32;
    f32x4 acc[2][8];
    #pragma unroll
    for (int mi = 0; mi < 2; mi++)
        #pragma unroll
        for (int ni = 0; ni < 8; ni++) { f32x4 z = {0.f, 0.f, 0.f, 0.f}; acc[mi][ni] = z; }
    #pragma unroll
    for (int ks = 0; ks < 2; ks++) {
        bf16x8 a0 = *(const bf16x8*)(Qs + (rowB + (l & 15)) * 72 + ks * 32 + (l >> 4) * 8);
        bf16x8 a1 = *(const bf16x8*)(Qs + (rowB + 16 + (l & 15)) * 72 + ks * 32 + (l >> 4) * 8);
        #pragma unroll
        for (int ni = 0; ni < 8; ni++) {
            bf16x8 bv = *(const bf16x8*)(Ks + (ni * 16 + (l & 15)) * 72 + ks * 32 + (l >> 4) * 8);
            acc[0][ni] = __builtin_amdgcn_mfma_f32_16x16x32_bf16(a0, bv, acc[0][ni], 0, 0, 0);
            acc[1][ni] = __builtin_amdgcn_mfma_f32_16x16x32_bf16(a1, bv, acc[1][ni], 0, 0, 0);
        }
    }
    float pf[8];
    #pragma unroll
    for (int ni = 0; ni < 8; ni++) pf[ni] = padF[ni * 16 + (l & 15)] ? 1.0f : 0.0f;
    #pragma unroll
    for (int mi = 0; mi < 2; mi++)
        #pragma unroll
        for (int ni = 0; ni < 8; ni++)
            #pragma unroll
            for (int r = 0; r < 4; r++) {
                float v = acc[mi][ni][r] * 0.125f;
                acc[mi][ni][r] = (pf[ni] != 0.0f) ? -1e9f : v;
            }
    #pragma unroll
    for (int mi = 0; mi < 2; mi++)
        #pragma unroll
        for (int r = 0; r < 4; r++) {
            float m = -INFINITY;
            #pragma unroll
            for (int ni = 0; ni < 8; ni++) m = fmaxf(m, acc[mi][ni][r]);
            m = fmaxf(m, __shfl_xor(m, 1)); m = fmaxf(m, __shfl_xor(m, 2));
            m = fmaxf(m, __shfl_xor(m, 4)); m = fmaxf(m, __shfl_xor(m, 8));
            float s = 0.0f;
            #pragma unroll
            for (int ni = 0; ni < 8; ni++) { float e = expf(acc[mi][ni][r] - m); acc[mi][ni][r] = e; s += e; }
            s += __shfl_xor(s, 1); s += __shfl_xor(s, 2);
            s += __shfl_xor(s, 4); s += __shfl_xor(s, 8);
            float inv = 1.0f / s;
            #pragma unroll
            for (int ni = 0; ni < 8; ni++) acc[mi][ni][r] *= inv;
        }
    float cs[8];
    #pragma unroll
    for (int ni = 0; ni < 8; ni++) {
        float s = 0.0f;
        #pragma unroll
        for (int mi = 0; mi < 2; mi++)
            #pragma unroll
            for (int r = 0; r < 4; r++) s += acc[mi][ni][r];
        s += __shfl_xor(s, 16); s += __shfl_xor(s, 32);
        cs[ni] = s;
    }
    __syncthreads();
    if (l < 16)
        #pragma unroll
        for (int ni = 0; ni < 8; ni++) colsLds[w][ni * 16 + l] = cs[ni];
    #pragma unroll
    for (int mi = 0; mi < 2; mi++)
        #pragma unroll
        for (int ni = 0; ni < 8; ni++)
            #pragma unroll
            for (int r = 0; r < 4; r++)
                Ps[(rowB + mi * 16 + (l >> 4) * 4 + r) * 136 + ni * 16 + (l & 15)] =
                    f2b(acc[mi][ni][r]);
    __syncthreads();
    if (tid < 128) {
        float s = colsLds[0][tid] + colsLds[1][tid] + colsLds[2][tid] + colsLds[3][tid];
        colsum[((long)gb * H + h) * S + tid] = s;
    }
    f32x4 o[2][4];
    #pragma unroll
    for (int mi = 0; mi < 2; mi++)
        #pragma unroll
        for (int n = 0; n < 4; n++) { f32x4 z = {0.f, 0.f, 0.f, 0.f}; o[mi][n] = z; }
    #pragma unroll
    for (int ks = 0; ks < 4; ks++) {
        bf16x8 p0 = *(const bf16x8*)(Ps + (rowB + (l & 15)) * 136 + ks * 32 + (l >> 4) * 8);
        bf16x8 p1 = *(const bf16x8*)(Ps + (rowB + 16 + (l & 15)) * 136 + ks * 32 + (l >> 4) * 8);
        #pragma unroll
        for (int n = 0; n < 4; n++) {
            bf16x8 bv = *(const bf16x8*)(Vt + (n * 16 + (l & 15)) * 136 + ks * 32 + (l >> 4) * 8);
            o[0][n] = __builtin_amdgcn_mfma_f32_16x16x32_bf16(p0, bv, o[0][n], 0, 0, 0);
            o[1][n] = __builtin_amdgcn_mfma_f32_16x16x32_bf16(p1, bv, o[1][n], 0, 0, 0);
        }
    }
    #pragma unroll
    for (int mi = 0; mi < 2; mi++)
        #pragma unroll
        for (int n = 0; n < 4; n++) {
            const int col = n * 16 + (l & 15);
            #pragma unroll
            for (int r = 0; r < 4; r++) {
                const int row = rowB + mi * 16 + (l >> 4) * 4 + r;
                qb[base + (long)row * D + col] = f2b(o[mi][n][r]);
            }
        }
}

// ---------------------------------------------------------------- creat_mask
__global__ __launch_bounds__(128)
void creat_mask_kernel(const float* __restrict__ colpart, const int* __restrict__ toks,
                       int* __restrict__ mtok, float* __restrict__ out) {
    __shared__ float colS[S];
    __shared__ int   j0s, kks;
    const int b = blockIdx.x, j = threadIdx.x;
    float c = colpart[(long)(b * AH + 0) * S + j] + colpart[(long)(b * AH + 1) * S + j];
    colS[j] = c;
    int tk = toks[b * S + j];
    __syncthreads();
    if (j == 0) {
        int j0 = S;
        for (int i = 0; i < S; i++) if (colS[i] == 0.0f) { j0 = i; break; }
        int kk = (j0 < S) ? (int)ceilf(0.2f * (float)j0) : 0;
        j0s = j0; kks = kk;
    }
    __syncthreads();
    const int j0 = j0s, kk = kks;
    float vj = (j < j0) ? colS[j] : INFINITY;
    int rank = 0;
    for (int i = 0; i < S; i++) {
        float vi = (i < j0) ? colS[i] : INFINITY;
        if (vi < vj || (vi == vj && i < j)) rank++;
    }
    int mt = (rank >= kk) ? tk : 0;
    mtok[b * S + j] = mt;
    out[OUT_TOK + b * S + j]  = (float)tk;
    out[OUT_MTOK + b * S + j] = (float)mt;
}

// ---------------------------------------------------------------- LayerNorm: y (pre-LN bf16) -> xb (bf16)
__global__ __launch_bounds__(256)
void ln_kernel(const u16* __restrict__ y, u16* __restrict__ xb) {
    const int row  = blockIdx.x * 4 + (threadIdx.x >> 6);
    const int lane = threadIdx.x & 63;
    const u16* r = y + (long)row * D;
    uint4 u = *(const uint4*)(r + lane * 8);
    u32 uu[4] = {u.x, u.y, u.z, u.w};
    float v[8];
    #pragma unroll
    for (int t = 0; t < 4; t++) {
        v[t * 2]     = b2f((u16)(uu[t] & 0xffffu));
        v[t * 2 + 1] = b2f((u16)(uu[t] >> 16));
    }
    float s = 0.0f, q = 0.0f;
    #pragma unroll
    for (int t = 0; t < 8; t++) { s += v[t]; q += v[t] * v[t]; }
    #pragma unroll
    for (int off = 32; off; off >>= 1) { s += __shfl_xor(s, off); q += __shfl_xor(q, off); }
    float m   = s * (1.0f / 512.0f);
    float var = q * (1.0f / 512.0f) - m * m;
    float inv = 1.0f / sqrtf(var + 1e-5f);
    u16 o[8];
    #pragma unroll
    for (int t = 0; t < 8; t++) o[t] = f2b((v[t] - m) * inv);
    *(uint4*)(xb + (long)row * D + lane * 8) = *(uint4*)o;
}

// ---------------------------------------------------------------- scores output (all layers, pass-0 half)
__global__ void score_all_kernel(const float* __restrict__ ascl, float* __restrict__ out) {
    int idx = blockIdx.x * 256 + threadIdx.x;     // over L*B*S = 49152
    if (idx >= L * B * S) return;
    int l   = idx / (B * S);
    int rem = idx - l * (B * S);
    int b = rem >> 7, j = rem & 127;
    const float* p = ascl + (long)l * ASCL_STRIDE + (long)b * H * S + j;
    float s = 0.0f;
    #pragma unroll
    for (int h = 0; h < H; h++) s += p[(long)h * S];
    out[OUT_SCORES + idx] = s;
}

// ---------------------------------------------------------------- pre-head reduce/pack
__global__ void reduce1_kernel(const float* __restrict__ parts, const float* __restrict__ b1,
                               float* __restrict__ o) {
    int idx = blockIdx.x * 256 + threadIdx.x;
    if (idx >= 128 * 1024) return;
    float s = 0.0f;
    for (int z = 0; z < 64; z++) s += parts[(long)z * 128 * 1024 + idx];
    s += b1[idx & 1023];
    o[idx] = fmaxf(s, 0.0f);
}

__global__ void pack_out_kernel(const float* __restrict__ ph3, float* __restrict__ out) {
    int idx = blockIdx.x * 256 + threadIdx.x;
    if (idx >= 128 * 128) return;
    int row = idx >> 7, col = idx & 127;
    long base = (row < 64) ? (OUT_OUT1 + (long)row * 128) : (OUT_OUTM + (long)(row - 64) * 128);
    out[base + col] = ph3[idx];
}

// ================================================================ launch
extern "C" void kernel_launch(void* const* d_in, const int* in_sizes, int n_in,
                              void* d_out, int out_size, void* d_ws, size_t ws_size,
                              hipStream_t stream) {
    const int*   toks = (const int*)d_in[0];
    const float* emb  = (const float*)d_in[1];
    const float* aWQ  = (const float*)d_in[2];
    const float* aWK  = (const float*)d_in[3];
    const float* tWQ  = (const float*)d_in[8];
    const float* tWK  = (const float*)d_in[9];
    const float* tWV  = (const float*)d_in[10];
    const float* tFC  = (const float*)d_in[11];
    const float* tF1  = (const float*)d_in[12];
    const float* tF2  = (const float*)d_in[13];
    const float* pW1  = (const float*)d_in[14];
    const float* pb1  = (const float*)d_in[15];
    const float* pW2  = (const float*)d_in[16];
    const float* pb2  = (const float*)d_in[17];
    const float* pW3  = (const float*)d_in[18];
    const float* pb3  = (const float*)d_in[19];
    float* out = (float*)d_out;

    float* ws   = (float*)d_ws;
    float* pe   = ws + OFF_PE;
    float* ascl = ws + OFF_ASCL;
    float* colp = ws + OFF_COLP;
    int*   mtok = (int*)(ws + OFF_MTOK);
    float* x    = ws + OFF_X;          // fp32 clean embedding (mask path only)
    u16*   xb   = (u16*)(ws + OFF_XB); // [BS2][D] bf16 canonical state
    u16*   yb   = (u16*)(ws + OFF_Y);  // [BS2][D] bf16 pre-LN scratch
    u16*   qb   = (u16*)(ws + OFF_QB);
    u16*   kb   = (u16*)(ws + OFF_KB);
    u16*   vb   = (u16*)(ws + OFF_VB);
    u16*   tb   = (u16*)(ws + OFF_TB); // [BS2][DFF] bf16
    u16*   wAll = (u16*)(ws + OFF_W);

    // phase-disjoint aliases of the TB region
    float* maq   = ws + OFF_TB;                 // mask encoder q [BS][128] fp32
    float* mak   = maq + (long)BS * 128;
    float* parts = ws + OFF_TB;                 // pre-head partials 64 x [128][1024]
    float* ph1o  = parts + 8388608;
    float* ph2o  = ph1o + 131072;
    float* ph3o  = ph2o + 65536;

    // --- setup: pos-enc, all-layer weight conversion, clean embedding
    pe_kernel<<<128, 256, 0, stream>>>(pe);
    wconv_all<<<6 * 3072, 256, 0, stream>>>(tWQ, tWK, tWV, tFC, tF1, tF2, wAll);
    embed_dual<<<2048, 256, 0, stream>>>(toks, emb, pe, x, xb);

    // --- mask-generating encoder (fp32; only the attention matrix is consumed)
    gemm64_qkv<<<dim3(BS / 64, 2, 2), 256, 0, stream>>>(
        x, aWQ, aWK, nullptr, maq, mak, nullptr, BS, AH * DK, D);
    attn_kernel<<<B * AH, 128, 0, stream>>>(maq, mak, toks, colp, AH);
    creat_mask_kernel<<<B, 128, 0, stream>>>(colp, toks, mtok, out);
    embed_dual<<<2048, 256, 0, stream>>>(mtok, emb, pe, nullptr, xb + (long)BS * D);

    // --- 6 layers, both passes batched; bf16 state xb, bf16 pre-LN scratch yb
    for (int l = 0; l < L; l++) {
        const u16* wq = wAll + (long)l * WSTRIDE;
        const u16* wk = wq + 262144;
        const u16* wv = wq + 524288;
        const u16* wo = wq + 786432;
        const u16* w1 = wq + 1048576;
        const u16* w2 = wq + 2097152;
        gemm_qkv_b<<<dim3(BS2 / 256, D / 128, 3), 512, 0, stream>>>(
            xb, wq, wk, wv, qb, kb, vb, BS2, D, D);
        attn_mfma_kernel<<<2 * B * H, 256, 0, stream>>>(
            qb, kb, vb, toks, mtok, ascl + (long)l * ASCL_STRIDE);
        gemm_resid_b<<<dim3(BS2 / 128, D / 128), 256, 0, stream>>>(qb, wo, yb, xb, BS2, D, D);
        ln_kernel<<<BS2 / 4, 256, 0, stream>>>(yb, xb);
        gemm_relu_b<<<dim3(BS2 / 256, DFF / 128), 512, 0, stream>>>(xb, w1, tb, BS2, DFF, D);
        gemm_resid_b<<<dim3(BS2 / 128, D / 128), 256, 0, stream>>>(tb, w2, yb, xb, BS2, D, DFF);
        ln_kernel<<<BS2 / 4, 256, 0, stream>>>(yb, xb);
    }
    score_all_kernel<<<192, 256, 0, stream>>>(ascl, out);

    // --- pre_head: MFMA split-K over pW1 (xb holds bf16 h ‖ hm)
    gemm_ph1<<<dim3(8, 64), 256, 0, stream>>>(xb, xb + (long)BS * D, pW1, parts, 1024);
    reduce1_kernel<<<512, 256, 0, stream>>>(parts, pb1, ph1o);
    gemm64<4><<<dim3(2, 8), 256, 0, stream>>>(ph1o, pW2, ph2o, pb2, 128, 512, 1024);
    gemm64<3><<<dim3(2, 2), 256, 0, stream>>>(ph2o, pW3, ph3o, pb3, 128, 128, 512);
    pack_out_kernel<<<64, 256, 0, stream>>>(ph3o, out);
}